// Round 8
// baseline (10612.981 us; speedup 1.0000x reference)
//
#include <hip/hip_runtime.h>
#include <hip/hip_bf16.h>
#include <hip/hip_fp16.h>

#define EPSN 1e-5f

typedef __hip_bfloat16 bf16;
typedef __half f16;
typedef __attribute__((ext_vector_type(8))) short bf16x8;
typedef __attribute__((ext_vector_type(4))) float f32x4;

__device__ __forceinline__ float b2f(bf16 v) { return __bfloat162float(v); }
__device__ __forceinline__ bf16 f2b(float v) { return __float2bfloat16(v); }
__device__ __forceinline__ unsigned short f2bu(float v) {
  bf16 h = __float2bfloat16(v);
  return *reinterpret_cast<unsigned short*>(&h);
}
__device__ __forceinline__ float bu2f(unsigned short u) {
  unsigned int b = ((unsigned int)u) << 16;
  return __uint_as_float(b);
}
__device__ __forceinline__ unsigned short f2hu(float v) {
  f16 h = __float2half(v);
  return *reinterpret_cast<unsigned short*>(&h);
}
__device__ __forceinline__ float hu2f(unsigned short u) {
  f16 h = *reinterpret_cast<f16*>(&u);
  return __half2float(h);
}
__device__ __forceinline__ void stv(bf16* p, size_t i, float v) { p[i] = f2b(v); }
__device__ __forceinline__ void stv(float* p, size_t i, float v) { p[i] = v; }
__device__ __forceinline__ void stv(f16* p, size_t i, float v) {
  p[i] = __float2half(v);
}

// vec4 load/store helpers (fp32/bf16/fp16 storage, fp32 compute)
__device__ __forceinline__ float4 ld4(const float* p) { return *(const float4*)p; }
__device__ __forceinline__ float4 ld4(const bf16* p) {
  ushort4 u = *(const ushort4*)p;
  float4 r;
  r.x = bu2f(u.x);
  r.y = bu2f(u.y);
  r.z = bu2f(u.z);
  r.w = bu2f(u.w);
  return r;
}
__device__ __forceinline__ float4 ld4(const f16* p) {
  ushort4 u = *(const ushort4*)p;
  float4 r;
  r.x = hu2f(u.x);
  r.y = hu2f(u.y);
  r.z = hu2f(u.z);
  r.w = hu2f(u.w);
  return r;
}
__device__ __forceinline__ void st4(float* p, float4 v) { *(float4*)p = v; }
__device__ __forceinline__ void st4(bf16* p, float4 v) {
  uint2 o;
  o.x = (unsigned)f2bu(v.x) | ((unsigned)f2bu(v.y) << 16);
  o.y = (unsigned)f2bu(v.z) | ((unsigned)f2bu(v.w) << 16);
  *(uint2*)p = o;
}
__device__ __forceinline__ void st4(f16* p, float4 v) {
  ushort4 o = {f2hu(v.x), f2hu(v.y), f2hu(v.z), f2hu(v.w)};
  *(ushort4*)p = o;
}

// ---------------- zero the stats scratch (atomicAdd target) -----------------
__global__ void zero_stats_kernel(float* __restrict__ stats) {
  for (int k = threadIdx.x; k < 2048; k += 256) stats[k] = 0.f;
}

// ------- weight convert: [Co][Ci][3][3] fp32 -> [tap][co][ci] bf16 hi+lo ----
__global__ __launch_bounds__(256) void convert_w_kernel(
    const float* __restrict__ rw1, const float* __restrict__ rw2,
    unsigned short* __restrict__ wb) {
  int i = blockIdx.x * 256 + threadIdx.x;  // < 8*9*65536 = 4718592
  if (i >= 4718592) return;
  int conv = i / 589824;
  int rem = i % 589824;
  int tap = rem / 65536;
  int cc = rem % 65536;  // co*256+ci
  const float* src = ((conv & 1) ? rw2 : rw1) + (size_t)(conv >> 1) * 589824;
  float v = src[(size_t)cc * 9 + tap];
  bf16 h = __float2bfloat16(v);
  float fh = __bfloat162float(h);
  wb[i] = *reinterpret_cast<unsigned short*>(&h);
  bf16 l = __float2bfloat16(v - fh);
  wb[4718592 + i] = *reinterpret_cast<unsigned short*>(&l);
}

// ---------------- 3x3 s1 p1 conv via MFMA (bf16x3), Ci=Co=256, H=W=128 ------
__device__ __forceinline__ int swz3(int idx) {
  return (idx & 3) ^ ((idx >> 2) & 1);
}

__global__ __launch_bounds__(256) void conv3x3s1_mfma(
    const float* __restrict__ x, const unsigned short* __restrict__ wh,
    const unsigned short* __restrict__ wl, const float* __restrict__ bias,
    float* __restrict__ y) {
  const int H = 128, W = 128;
  int r = blockIdx.x;    // output row
  int cog = blockIdx.y;  // 0..1 (128 co each)
  int n = blockIdx.z;
  int tid = threadIdx.x;
  int wv = tid >> 6, lane = tid & 63;
  int wco = (wv >> 1) * 64, wpx = (wv & 1) * 64;
  int l15 = lane & 15, l4 = lane >> 4;

  __shared__ __align__(16) unsigned short Xh[3 * 130 * 32];
  __shared__ __align__(16) unsigned short Xl[3 * 130 * 32];
  __shared__ __align__(16) unsigned short Ah[128 * 32];
  __shared__ __align__(16) unsigned short Al[128 * 32];

  f32x4 acc[4][4];
#pragma unroll
  for (int m = 0; m < 4; ++m)
#pragma unroll
    for (int nf = 0; nf < 4; ++nf) acc[m][nf] = (f32x4){0.f, 0.f, 0.f, 0.f};

  const float* xn0 = x + (size_t)n * 256 * H * W;

  for (int cb = 0; cb < 8; ++cb) {
    int ci0 = cb * 32;
    {
      const float* xn = xn0 + (size_t)ci0 * H * W;
      for (int t = tid; t < 1560; t += 256) {
        int q = t & 3;
        int cr = t >> 2;     // 0..389
        int col = cr % 130;  // 0..129
        int row = cr / 130;  // 0..2
        int gr = r + row - 1;
        int gc = col - 1;
        bool ok = (gr >= 0) && (gr < H) && (gc >= 0) && (gc < W);
        uint4 ph = {0, 0, 0, 0};
        uint4 pl = {0, 0, 0, 0};
        if (ok) {
          const float* xp =
              xn + (size_t)(q * 8) * (H * W) + (size_t)gr * W + gc;
          unsigned short vh[8], vl[8];
#pragma unroll
          for (int e = 0; e < 8; ++e) {
            float v = xp[(size_t)e * H * W];
            bf16 hb = __float2bfloat16(v);
            float fh = __bfloat162float(hb);
            bf16 lb = __float2bfloat16(v - fh);
            vh[e] = *reinterpret_cast<unsigned short*>(&hb);
            vl[e] = *reinterpret_cast<unsigned short*>(&lb);
          }
          ph.x = (unsigned)vh[0] | ((unsigned)vh[1] << 16);
          ph.y = (unsigned)vh[2] | ((unsigned)vh[3] << 16);
          ph.z = (unsigned)vh[4] | ((unsigned)vh[5] << 16);
          ph.w = (unsigned)vh[6] | ((unsigned)vh[7] << 16);
          pl.x = (unsigned)vl[0] | ((unsigned)vl[1] << 16);
          pl.y = (unsigned)vl[2] | ((unsigned)vl[3] << 16);
          pl.z = (unsigned)vl[4] | ((unsigned)vl[5] << 16);
          pl.w = (unsigned)vl[6] | ((unsigned)vl[7] << 16);
        }
        int slot = (cr * 4 + (q ^ swz3(col))) * 8;
        *(uint4*)(&Xh[slot]) = ph;
        *(uint4*)(&Xl[slot]) = pl;
      }
    }
    for (int tap = 0; tap < 9; ++tap) {
      for (int t = tid; t < 1024; t += 256) {
        int half = t >> 9;
        int rem = t & 511;
        int q = rem & 3;
        int co = rem >> 2;
        const unsigned short* wsrc =
            (half ? wl : wh) +
            ((size_t)tap * 256 + cog * 128 + co) * 256 + ci0 + q * 8;
        uint4 pk = *(const uint4*)wsrc;
        int slot = (co * 4 + (q ^ swz3(co))) * 8;
        *(uint4*)((half ? Al : Ah) + slot) = pk;
      }
      __syncthreads();
      int ky = tap / 3;
      int kx = tap - ky * 3;
      bf16x8 ahf[4], alf[4], bhf[4], blf[4];
#pragma unroll
      for (int m = 0; m < 4; ++m) {
        int co = wco + m * 16 + l15;
        int slot = (co * 4 + (l4 ^ swz3(co))) * 8;
        ahf[m] = *(const bf16x8*)(&Ah[slot]);
        alf[m] = *(const bf16x8*)(&Al[slot]);
      }
#pragma unroll
      for (int nf = 0; nf < 4; ++nf) {
        int col = wpx + nf * 16 + l15 + kx;  // lds col = px + kx
        int slot = ((ky * 130 + col) * 4 + (l4 ^ swz3(col))) * 8;
        bhf[nf] = *(const bf16x8*)(&Xh[slot]);
        blf[nf] = *(const bf16x8*)(&Xl[slot]);
      }
#pragma unroll
      for (int m = 0; m < 4; ++m)
#pragma unroll
        for (int nf = 0; nf < 4; ++nf) {
          acc[m][nf] = __builtin_amdgcn_mfma_f32_16x16x32_bf16(
              ahf[m], bhf[nf], acc[m][nf], 0, 0, 0);
          acc[m][nf] = __builtin_amdgcn_mfma_f32_16x16x32_bf16(
              ahf[m], blf[nf], acc[m][nf], 0, 0, 0);
          acc[m][nf] = __builtin_amdgcn_mfma_f32_16x16x32_bf16(
              alf[m], bhf[nf], acc[m][nf], 0, 0, 0);
        }
      __syncthreads();
    }
  }
#pragma unroll
  for (int m = 0; m < 4; ++m) {
    int cob = cog * 128 + wco + m * 16 + l4 * 4;
#pragma unroll
    for (int reg = 0; reg < 4; ++reg) {
      float bv = bias[cob + reg];
      float* yr =
          y + (((size_t)(n * 256 + cob + reg) * H) + r) * W + wpx + l15;
#pragma unroll
      for (int nf = 0; nf < 4; ++nf) yr[nf * 16] = acc[m][nf][reg] + bv;
    }
  }
}

// ---------------- e1: 7x7 conv p3, CI=3, LDS-tiled (1 ci slice at a time) ---
// 8co x 8px(interleaved), raw f16 out + stats. Block: 4 rows x 512 cols.
// grid (128, 8, 4). LDS: 20.8K (Xs) + 4.7K (wsh) + 0.25K = 25.8 KB.
__global__ __launch_bounds__(256) void conv7_e1(
    const float* __restrict__ x, const float* __restrict__ w,
    const float* __restrict__ bias, float* __restrict__ stats,
    f16* __restrict__ y) {
  const int H = 512, W = 512;
  __shared__ float Xs[5200];         // [10][520] one ci, zero-padded halo
  __shared__ float wsh[8 * 3 * 49];  // 8 co slab
  __shared__ float sred[4][8], qred[4][8];
  int cog = blockIdx.y;  // 8 groups x 8 co
  int n = blockIdx.z;
  int tid = threadIdx.x;
  int r0 = blockIdx.x * 4;
  int tr = tid >> 6;
  int lane = tid & 63;
  for (int t = tid; t < 1176; t += 256) wsh[t] = w[cog * 1176 + t];
  const float* xb = x + (size_t)n * 3 * H * W;
  float acc[8][8];
#pragma unroll
  for (int j = 0; j < 8; ++j) {
#pragma unroll
    for (int p = 0; p < 8; ++p) acc[j][p] = 0.f;
  }
  for (int ci = 0; ci < 3; ++ci) {
    __syncthreads();  // protect Xs from prev readers; orders wsh on 1st iter
    for (int t = tid; t < 5200; t += 256) {
      int row = t / 520;
      int col = t - row * 520;
      int gr = r0 - 3 + row;
      int gc = col - 3;
      float v = 0.f;
      if (gr >= 0 && gr < H && gc >= 0 && gc < W)
        v = xb[((size_t)ci * H + gr) * W + gc];
      Xs[t] = v;
    }
    __syncthreads();
    for (int i = 0; i < 7; ++i) {
      const float* xr = &Xs[(tr + i) * 520 + lane];
      float v[8][7];
#pragma unroll
      for (int p = 0; p < 8; ++p)
#pragma unroll
        for (int k = 0; k < 7; ++k) v[p][k] = xr[p * 64 + k];
#pragma unroll
      for (int j = 0; j < 8; ++j) {
        const float* wr = &wsh[(j * 3 + ci) * 49 + i * 7];
        float w0 = wr[0], w1 = wr[1], w2 = wr[2], w3 = wr[3], w4 = wr[4],
              w5 = wr[5], w6 = wr[6];
#pragma unroll
        for (int p = 0; p < 8; ++p)
          acc[j][p] += v[p][0] * w0 + v[p][1] * w1 + v[p][2] * w2 +
                       v[p][3] * w3 + v[p][4] * w4 + v[p][5] * w5 +
                       v[p][6] * w6;
      }
    }
  }
  int r = r0 + tr;
#pragma unroll
  for (int j = 0; j < 8; ++j) {
    int co = cog * 8 + j;
    float bv = bias[co];
    f16* yr = y + ((size_t)(n * 64 + co) * H + r) * W + lane;
    float s = 0.f, q = 0.f;
#pragma unroll
    for (int p = 0; p < 8; ++p) {
      float o = acc[j][p] + bv;
      yr[p * 64] = __float2half(o);
      s += o;
      q += o * o;
    }
#pragma unroll
    for (int off = 32; off > 0; off >>= 1) {
      s += __shfl_down(s, off, 64);
      q += __shfl_down(q, off, 64);
    }
    if (lane == 0) {
      sred[tr][j] = s;
      qred[tr][j] = q;
    }
  }
  __syncthreads();
  if (tid < 8) {
    float S = sred[0][tid] + sred[1][tid] + sred[2][tid] + sred[3][tid];
    float Q = qred[0][tid] + qred[1][tid] + qred[2][tid] + qred[3][tid];
    atomicAdd(&stats[n * 64 + cog * 8 + tid], S);
    atomicAdd(&stats[1024 + n * 64 + cog * 8 + tid], Q);
  }
}

// ---------------- head: 7x7 conv p3, CI=64 (bf16 in), LDS-tiled + tanh ------
// 2-row blocks for occupancy: grid (256,1,4) = 4 blocks/CU.
// ci-chunked (2/chunk); f16 weights in LDS. LDS: 16.6K (Xs) + 18.8K = 35.4 KB.
__global__ __launch_bounds__(256) void conv7_head(
    const bf16* __restrict__ xin, const float* __restrict__ w,
    const float* __restrict__ bias, float* __restrict__ y) {
  const int H = 512, W = 512;
  __shared__ unsigned short Xs[8320];   // [2][8][520] bf16 bits
  __shared__ unsigned short wsh[9408];  // [3][64][49] f16 bits
  int n = blockIdx.z;
  int tid = threadIdx.x;
  int r0 = blockIdx.x * 2;
  int tr = tid >> 7;        // 0..1 output row
  int lane = tid & 127;     // 0..127 column base
  for (int t = tid; t < 9408; t += 256) wsh[t] = f2hu(w[t]);
  const unsigned short* xb =
      (const unsigned short*)xin + (size_t)n * 64 * H * W;
  float acc[3][4];
#pragma unroll
  for (int j = 0; j < 3; ++j) {
    float b = bias[j];
#pragma unroll
    for (int p = 0; p < 4; ++p) acc[j][p] = b;
  }
  for (int cc0 = 0; cc0 < 64; cc0 += 2) {
    __syncthreads();  // protect Xs from prev chunk's readers (+wsh 1st it)
    for (int t = tid; t < 8320; t += 256) {
      int ci = t / 4160;
      int rem = t - ci * 4160;
      int row = rem / 520;
      int col = rem - row * 520;
      int gr = r0 - 3 + row;
      int gc = col - 3;
      unsigned short v = 0;
      if (gr >= 0 && gr < H && gc >= 0 && gc < W)
        v = xb[((size_t)(cc0 + ci) * H + gr) * W + gc];
      Xs[t] = v;
    }
    __syncthreads();
    for (int ci = 0; ci < 2; ++ci)
      for (int i = 0; i < 7; ++i) {
        const unsigned short* xr = &Xs[(ci * 8 + tr + i) * 520 + lane];
        float v[4][7];
#pragma unroll
        for (int p = 0; p < 4; ++p)
#pragma unroll
          for (int k = 0; k < 7; ++k) v[p][k] = bu2f(xr[p * 128 + k]);
#pragma unroll
        for (int j = 0; j < 3; ++j) {
          const unsigned short* wr = &wsh[(j * 64 + cc0 + ci) * 49 + i * 7];
          float w0 = hu2f(wr[0]), w1 = hu2f(wr[1]), w2 = hu2f(wr[2]),
                w3 = hu2f(wr[3]), w4 = hu2f(wr[4]), w5 = hu2f(wr[5]),
                w6 = hu2f(wr[6]);
#pragma unroll
          for (int p = 0; p < 4; ++p)
            acc[j][p] += v[p][0] * w0 + v[p][1] * w1 + v[p][2] * w2 +
                         v[p][3] * w3 + v[p][4] * w4 + v[p][5] * w5 +
                         v[p][6] * w6;
        }
      }
  }
  int r = r0 + tr;
#pragma unroll
  for (int j = 0; j < 3; ++j) {
    float* yr = y + ((size_t)(n * 3 + j) * H + r) * W + lane;
#pragma unroll
    for (int p = 0; p < 4; ++p) yr[p * 128] = tanhf(acc[j][p]);
  }
}

// ---------------- 3x3 s2 p1 conv, tiled 4 px x 8 co ------------------------
// NORM: input v = relu(x*sc[n,ci] + sh[n,ci]) fused from stats (AdaLIN coefs)
template <typename Tin, typename Tout, bool NORM>
__global__ __launch_bounds__(256) void conv3x3s2_tile(
    const Tin* __restrict__ x, const float* __restrict__ w,
    const float* __restrict__ bias, const float* __restrict__ stats,
    Tout* __restrict__ y, int Ci, int Hi, int Wi) {
  int Ho = Hi >> 1, Wo = Wi >> 1;
  int cog = blockIdx.y;
  int Co = gridDim.y * 8;
  int n = blockIdx.z;
  int CG = Wo >> 2;
  int rpb = 256 / CG;
  int tid = threadIdx.x;
  int r = blockIdx.x * rpb + tid / CG;
  int c0 = (tid % CG) * 4;
  const Tin* xb = x + (size_t)n * Ci * Hi * Wi;
  int ir0 = 2 * r - 1;
  float mr0 = (ir0 >= 0) ? 1.f : 0.f;
  int cr0 = max(ir0, 0);
  int icl = 2 * c0 - 1;
  float mcl = (icl >= 0) ? 1.f : 0.f;
  int ccl = max(icl, 0);
  float acc[8][4];
#pragma unroll
  for (int j = 0; j < 8; ++j) {
    float b = bias[cog * 8 + j];
#pragma unroll
    for (int p = 0; p < 4; ++p) acc[j][p] = b;
  }
  for (int ci = 0; ci < Ci; ++ci) {
    const Tin* xc = xb + (size_t)ci * Hi * Wi;
    float sc = 1.f, sh = 0.f;
    if (NORM) {
      sc = stats[2048 + n * Ci + ci];
      sh = stats[3072 + n * Ci + ci];
    }
    float v[3][9];
#pragma unroll
    for (int i = 0; i < 3; ++i) {
      int rr = (i == 0) ? cr0 : (2 * r - 1 + i);
      float mi = (i == 0) ? mr0 : 1.f;
      const Tin* xr = xc + (size_t)rr * Wi;
      float t[9];
      t[0] = (float)xr[ccl];
      float4 a = ld4(xr + 2 * c0);
      float4 b4 = ld4(xr + 2 * c0 + 4);
      t[1] = a.x;
      t[2] = a.y;
      t[3] = a.z;
      t[4] = a.w;
      t[5] = b4.x;
      t[6] = b4.y;
      t[7] = b4.z;
      t[8] = b4.w;
      if (NORM) {
#pragma unroll
        for (int k = 0; k < 9; ++k) t[k] = fmaxf(fmaf(t[k], sc, sh), 0.f);
      }
      v[i][0] = t[0] * (mcl * mi);
#pragma unroll
      for (int k = 1; k < 9; ++k) v[i][k] = t[k] * mi;
    }
#pragma unroll
    for (int j = 0; j < 8; ++j) {
      const float* wc = w + ((size_t)(cog * 8 + j) * Ci + ci) * 9;
#pragma unroll
      for (int p = 0; p < 4; ++p) {
        acc[j][p] += v[0][2 * p] * wc[0] + v[0][2 * p + 1] * wc[1] +
                     v[0][2 * p + 2] * wc[2] + v[1][2 * p] * wc[3] +
                     v[1][2 * p + 1] * wc[4] + v[1][2 * p + 2] * wc[5] +
                     v[2][2 * p] * wc[6] + v[2][2 * p + 1] * wc[7] +
                     v[2][2 * p + 2] * wc[8];
      }
    }
  }
#pragma unroll
  for (int j = 0; j < 8; ++j) {
    float4 o = {acc[j][0], acc[j][1], acc[j][2], acc[j][3]};
    st4(y + ((size_t)(n * Co + cog * 8 + j) * Ho + r) * Wo + c0, o);
  }
}

// ---------------- 1x1 conv, tiled 4 px x 4 co, fp32 -------------------------
__global__ __launch_bounds__(256) void conv1x1_tile(
    const float* __restrict__ x, const float* __restrict__ w,
    const float* __restrict__ bias, float* __restrict__ y, int Ci, int HW) {
  int cog = blockIdx.y;
  int Co = gridDim.y * 4;
  int n = blockIdx.z;
  int p0 = (blockIdx.x * 256 + threadIdx.x) * 4;
  const float* xb = x + (size_t)n * Ci * HW + p0;
  float acc[4][4];
#pragma unroll
  for (int j = 0; j < 4; ++j) {
    float b = bias[cog * 4 + j];
#pragma unroll
    for (int p = 0; p < 4; ++p) acc[j][p] = b;
  }
  for (int ci = 0; ci < Ci; ++ci) {
    float4 xv = *(const float4*)(xb + (size_t)ci * HW);
#pragma unroll
    for (int j = 0; j < 4; ++j) {
      float wv = w[(size_t)(cog * 4 + j) * Ci + ci];
      acc[j][0] += xv.x * wv;
      acc[j][1] += xv.y * wv;
      acc[j][2] += xv.z * wv;
      acc[j][3] += xv.w * wv;
    }
  }
#pragma unroll
  for (int j = 0; j < 4; ++j) {
    float4 o = {acc[j][0], acc[j][1], acc[j][2], acc[j][3]};
    *(float4*)(y + (size_t)(n * Co + cog * 4 + j) * HW + p0) = o;
  }
}

// ---------------- ConvTranspose2d k3 s2 p1 op1, tiled 2x2 quad x 8 co -------
template <typename Tin, typename Tout>
__global__ __launch_bounds__(256) void convt3x3_tile(
    const Tin* __restrict__ x, const float* __restrict__ w,
    const float* __restrict__ bias, Tout* __restrict__ y, int Ci, int Hi,
    int Wi) {
  int Ho = Hi * 2, Wo = Wi * 2;
  int cog = blockIdx.y;
  int Co = gridDim.y * 8;
  int n = blockIdx.z;
  int q = blockIdx.x * 256 + threadIdx.x;
  int yq = q / Wi, xq = q % Wi;
  const Tin* xb = x + (size_t)n * Ci * Hi * Wi;
  float mx = (xq + 1 < Wi) ? 1.f : 0.f;
  int x1 = min(xq + 1, Wi - 1);
  float my = (yq + 1 < Hi) ? 1.f : 0.f;
  int y1 = min(yq + 1, Hi - 1);
  float mxy = mx * my;
  float acc[8][4];
#pragma unroll
  for (int j = 0; j < 8; ++j) {
    float b = bias[cog * 8 + j];
#pragma unroll
    for (int p = 0; p < 4; ++p) acc[j][p] = b;
  }
  for (int ci = 0; ci < Ci; ++ci) {
    const Tin* xc = xb + (size_t)ci * Hi * Wi;
    float a = (float)xc[(size_t)yq * Wi + xq];
    float bv = (float)xc[(size_t)yq * Wi + x1] * mx;
    float c = (float)xc[(size_t)y1 * Wi + xq] * my;
    float d = (float)xc[(size_t)y1 * Wi + x1] * mxy;
#pragma unroll
    for (int j = 0; j < 8; ++j) {
      const float* wc = w + ((size_t)ci * Co + cog * 8 + j) * 9;
      acc[j][0] += a * wc[4];
      acc[j][1] += bv * wc[3] + a * wc[5];
      acc[j][2] += c * wc[1] + a * wc[7];
      acc[j][3] += d * wc[0] + c * wc[2] + bv * wc[6] + a * wc[8];
    }
  }
#pragma unroll
  for (int j = 0; j < 8; ++j) {
    size_t base = ((size_t)(n * Co + cog * 8 + j) * Ho + 2 * yq) * Wo + 2 * xq;
    stv(y, base, acc[j][0]);
    stv(y, base + 1, acc[j][1]);
    stv(y, base + Wo, acc[j][2]);
    stv(y, base + Wo + 1, acc[j][3]);
  }
}

// ---------------- per-(n,c) sum / sumsq reduction ---------------------------
template <typename Tin>
__global__ __launch_bounds__(256) void reduce_nc_kernel(
    const Tin* __restrict__ x, float* __restrict__ stats, int HW) {
  int b = blockIdx.x;
  const Tin* p = x + (size_t)b * HW;
  float s = 0.f, q = 0.f;
  for (int i = threadIdx.x; i < HW; i += 256) {
    float v = (float)p[i];
    s += v;
    q += v * v;
  }
  __shared__ float ss[256], qq[256];
  ss[threadIdx.x] = s;
  qq[threadIdx.x] = q;
  __syncthreads();
  for (int off = 128; off > 0; off >>= 1) {
    if (threadIdx.x < off) {
      ss[threadIdx.x] += ss[threadIdx.x + off];
      qq[threadIdx.x] += qq[threadIdx.x + off];
    }
    __syncthreads();
  }
  if (threadIdx.x == 0) {
    stats[b] = ss[0];
    stats[1024 + b] = qq[0];
  }
}

// ---------------- AdaLIN coefficients ---------------------------------------
__global__ void adalin_coef_kernel(float* __restrict__ stats,
                                   const float* __restrict__ rho,
                                   const float* __restrict__ gam,
                                   const float* __restrict__ bet, int N, int C,
                                   float invHW) {
  int i = blockIdx.x * blockDim.x + threadIdx.x;
  if (i >= N * C) return;
  int c = i % C;
  const float* sums = stats;
  const float* sqs = stats + 1024;
  float im = sums[i] * invHW;
  float iv = sqs[i] * invHW - im * im;
  float lsum = 0.f, lsq = 0.f;
  for (int n = 0; n < N; ++n) {
    lsum += sums[n * C + c];
    lsq += sqs[n * C + c];
  }
  float lm = lsum * invHW / N;
  float lv = lsq * invHW / N - lm * lm;
  float r = rho[c];
  float mean = r * im + (1.f - r) * lm;
  float var = fmaxf(r * iv + (1.f - r) * lv, 0.f);
  float sc = gam[c] / sqrtf(var + EPSN);
  stats[2048 + i] = sc;
  stats[3072 + i] = bet[c] - mean * sc;
}

// ---------------- InstanceNorm coefficients ---------------------------------
__global__ void inorm_coef_kernel(float* __restrict__ stats, int NC,
                                  float invHW) {
  int i = blockIdx.x * blockDim.x + threadIdx.x;
  if (i >= NC) return;
  float im = stats[i] * invHW;
  float iv = fmaxf(stats[1024 + i] * invHW - im * im, 0.f);
  float sc = 1.f / sqrtf(iv + EPSN);
  stats[2048 + i] = sc;
  stats[3072 + i] = -im * sc;
}

// ---------------- x = (relu?)(x*scale[nc] + shift[nc])  (in-place) ----------
template <typename T>
__global__ __launch_bounds__(256) void scale_shift_kernel(
    T* __restrict__ x, const float* __restrict__ stats, int HW, size_t total,
    int relu) {
  size_t i = (size_t)blockIdx.x * 256 + threadIdx.x;
  if (i >= total) return;
  int nc = (int)(i / (size_t)HW);
  float v = (float)x[i] * stats[2048 + nc] + stats[3072 + nc];
  if (relu) v = fmaxf(v, 0.f);
  stv(x, i, v);
}

// ---------------- dst = relu(dst + a)  (fp32) -------------------------------
__global__ __launch_bounds__(256) void add_relu_kernel(
    float* __restrict__ dst, const float* __restrict__ a, size_t total) {
  size_t i = (size_t)blockIdx.x * 256 + threadIdx.x;
  if (i >= total) return;
  dst[i] = fmaxf(dst[i] + a[i], 0.f);
}

// ---------------- windowed attention (all fp32) -----------------------------
__global__ __launch_bounds__(256) void win_attn_kernel(
    const float* __restrict__ f, const float* __restrict__ g,
    const float* __restrict__ h, float* __restrict__ out) {
  const int H = 128;
  int j = blockIdx.x;
  int i = blockIdx.y;
  int b = blockIdx.z;
  __shared__ float fs[32 * 64];
  __shared__ float gs[32 * 64];
  __shared__ float att[16 * 64];
  int t = threadIdx.x;
  for (int idx = t; idx < 32 * 64; idx += 256) {
    int c = idx >> 6, k = idx & 63;
    int hr = i * 4 + (k >> 3), wc = j * 4 + (k & 7);
    float fv = 0.f, gv = 0.f;
    if (hr < H && wc < H) {
      size_t o = ((size_t)(b * 32 + c) * H + hr) * H + wc;
      fv = f[o];
      gv = g[o];
    }
    fs[idx] = fv;
    gs[idx] = gv;
  }
  __syncthreads();
  for (int idx = t; idx < 1024; idx += 256) {
    int q = idx >> 6, k = idx & 63;
    int qi = (q >> 2) * 8 + (q & 3);
    int hr = i * 4 + (k >> 3), wc = j * 4 + (k & 7);
    float s;
    if (hr < H && wc < H) {
      s = 0.f;
      for (int c = 0; c < 32; ++c) s += fs[c * 64 + qi] * gs[c * 64 + k];
    } else {
      s = -1e30f;
    }
    att[idx] = s;
  }
  __syncthreads();
  if (t < 16) {
    float m = -1e30f;
    for (int k = 0; k < 64; ++k) m = fmaxf(m, att[t * 64 + k]);
    float d = 0.f;
    for (int k = 0; k < 64; ++k) {
      float e = expf(att[t * 64 + k] - m);
      att[t * 64 + k] = e;
      d += e;
    }
    float inv = 1.f / d;
    for (int k = 0; k < 64; ++k) att[t * 64 + k] *= inv;
  }
  __syncthreads();
  int c = t;
  float accs[16];
  for (int q = 0; q < 16; ++q) accs[q] = 0.f;
  const float* hb = h + (size_t)(b * 256 + c) * H * H;
  for (int k = 0; k < 64; ++k) {
    int hr = i * 4 + (k >> 3), wc = j * 4 + (k & 7);
    if (hr >= H || wc >= H) continue;
    float hv = hb[hr * H + wc];
    for (int q = 0; q < 16; ++q) accs[q] += hv * att[q * 64 + k];
  }
  for (int q = 0; q < 16; ++q) {
    int oh = i * 4 + (q >> 2), ow = j * 4 + (q & 3);
    out[((size_t)(b * 256 + c) * H + oh) * H + ow] = accs[q];
  }
}

// ============================================================================
extern "C" void kernel_launch(void* const* d_in, const int* in_sizes, int n_in,
                              void* d_out, int out_size, void* d_ws,
                              size_t ws_size, hipStream_t stream) {
  const float* x = (const float*)d_in[0];
  const float* w_e1 = (const float*)d_in[1];
  const float* b_e1 = (const float*)d_in[2];
  const float* rho1 = (const float*)d_in[3];
  const float* gam1 = (const float*)d_in[4];
  const float* bet1 = (const float*)d_in[5];
  const float* w_e2 = (const float*)d_in[6];
  const float* b_e2 = (const float*)d_in[7];
  const float* rho2 = (const float*)d_in[8];
  const float* gam2 = (const float*)d_in[9];
  const float* bet2 = (const float*)d_in[10];
  const float* w_e3 = (const float*)d_in[11];
  const float* b_e3 = (const float*)d_in[12];
  const float* rho3 = (const float*)d_in[13];
  const float* gam3 = (const float*)d_in[14];
  const float* bet3 = (const float*)d_in[15];
  const float* rw1 = (const float*)d_in[16];
  const float* rb1 = (const float*)d_in[17];
  const float* rw2 = (const float*)d_in[18];
  const float* rb2 = (const float*)d_in[19];
  const float* w_f = (const float*)d_in[20];
  const float* b_f = (const float*)d_in[21];
  const float* w_g = (const float*)d_in[22];
  const float* b_g = (const float*)d_in[23];
  const float* w_h = (const float*)d_in[24];
  const float* b_h = (const float*)d_in[25];
  const float* w_d1 = (const float*)d_in[26];
  const float* b_d1 = (const float*)d_in[27];
  const float* rho4 = (const float*)d_in[28];
  const float* gam4 = (const float*)d_in[29];
  const float* bet4 = (const float*)d_in[30];
  const float* w_d2 = (const float*)d_in[31];
  const float* b_d2 = (const float*)d_in[32];
  const float* rho5 = (const float*)d_in[33];
  const float* gam5 = (const float*)d_in[34];
  const float* bet5 = (const float*)d_in[35];
  const float* w_d3 = (const float*)d_in[36];
  const float* b_d3 = (const float*)d_in[37];

  // ws layout (192 MiB):
  // E1H f16 raw e1 [0,128MiB) (dead after e2)
  // B2H f16 raw e2 [128,192) (dead after e3; later Bb2 bf16 d1 out)
  // Cc fp32 [0,64), D fp32 [64,128), E fp32 [128,192) (residual stage)
  // F1/F2 fp32 [64,80) (attention f/g); A2 bf16 [0,128) (d2 out)
  char* wsb = (char*)d_ws;
  f16* E1H = (f16*)wsb;
  float* Cc = (float*)wsb;
  float* D = (float*)(wsb + 67108864);
  float* E = (float*)(wsb + 134217728);
  float* F1 = (float*)(wsb + 67108864);
  float* F2 = (float*)(wsb + 75497472);
  f16* B2H = (f16*)(wsb + 134217728);
  bf16* Bb2 = (bf16*)(wsb + 134217728);
  bf16* A2 = (bf16*)wsb;

  float* out_img = (float*)d_out;
  float* out_attn = out_img + 3145728;
  // 16 KiB stats scratch at head of img region; fully overwritten by head conv
  float* stats = (float*)d_out;
  // bf16 hi+lo residual weights scratch in the (not yet written) out_attn
  // region; fully consumed before win_attn_kernel writes out_attn.
  unsigned short* wbres = (unsigned short*)((char*)d_out + 12582912);

  dim3 blk(256);

  // ---- convert residual weights to bf16 hi+lo [tap][co][ci] (once) ----
  convert_w_kernel<<<18432, blk, 0, stream>>>(rw1, rw2, wbres);

  // ---- e1: 7x7 conv (LDS-tiled) -> raw f16 + stats ----
  zero_stats_kernel<<<1, 256, 0, stream>>>(stats);
  conv7_e1<<<dim3(128, 8, 4), blk, 0, stream>>>(x, w_e1, b_e1, stats, E1H);
  adalin_coef_kernel<<<1, 256, 0, stream>>>(stats, rho1, gam1, bet1, 4, 64,
                                            1.f / 262144.f);
  // ---- e2: 3x3 s2 conv with fused e1-norm+relu -> raw f16 ----
  conv3x3s2_tile<f16, f16, true><<<dim3(64, 16, 4), blk, 0, stream>>>(
      E1H, w_e2, b_e2, stats, B2H, 64, 512, 512);
  reduce_nc_kernel<f16><<<512, blk, 0, stream>>>(B2H, stats, 65536);
  adalin_coef_kernel<<<2, 256, 0, stream>>>(stats, rho2, gam2, bet2, 4, 128,
                                            1.f / 65536.f);
  // ---- e3: 3x3 s2 conv with fused e2-norm+relu -> fp32, then AdaLIN ----
  conv3x3s2_tile<f16, float, true><<<dim3(16, 32, 4), blk, 0, stream>>>(
      B2H, w_e3, b_e3, stats, Cc, 128, 256, 256);
  reduce_nc_kernel<float><<<1024, blk, 0, stream>>>(Cc, stats, 16384);
  adalin_coef_kernel<<<4, 256, 0, stream>>>(stats, rho3, gam3, bet3, 4, 256,
                                            1.f / 16384.f);
  scale_shift_kernel<float><<<65536, blk, 0, stream>>>(Cc, stats, 16384,
                                                       (size_t)16777216, 1);
  // ---- 4 residual blocks (bf16x3 MFMA convs) ----
  for (int r = 0; r < 4; ++r) {
    const float* rb1p = rb1 + (size_t)r * 256;
    const float* rb2p = rb2 + (size_t)r * 256;
    const unsigned short* w1h = wbres + (size_t)(r * 2) * 589824;
    const unsigned short* w1l = w1h + 4718592;
    const unsigned short* w2h = wbres + (size_t)(r * 2 + 1) * 589824;
    const unsigned short* w2l = w2h + 4718592;
    conv3x3s1_mfma<<<dim3(128, 2, 4), blk, 0, stream>>>(Cc, w1h, w1l, rb1p, D);
    reduce_nc_kernel<float><<<1024, blk, 0, stream>>>(D, stats, 16384);
    inorm_coef_kernel<<<4, 256, 0, stream>>>(stats, 1024, 1.f / 16384.f);
    scale_shift_kernel<float><<<65536, blk, 0, stream>>>(D, stats, 16384,
                                                         (size_t)16777216, 1);
    conv3x3s1_mfma<<<dim3(128, 2, 4), blk, 0, stream>>>(D, w2h, w2l, rb2p, E);
    reduce_nc_kernel<float><<<1024, blk, 0, stream>>>(E, stats, 16384);
    inorm_coef_kernel<<<4, 256, 0, stream>>>(stats, 1024, 1.f / 16384.f);
    scale_shift_kernel<float><<<65536, blk, 0, stream>>>(E, stats, 16384,
                                                         (size_t)16777216, 0);
    add_relu_kernel<<<65536, blk, 0, stream>>>(Cc, E, (size_t)16777216);
  }
  // ---- attention: 1x1 convs f/g/h + windowed attention ----
  conv1x1_tile<<<dim3(16, 8, 4), blk, 0, stream>>>(Cc, w_f, b_f, F1, 256,
                                                   16384);
  conv1x1_tile<<<dim3(16, 8, 4), blk, 0, stream>>>(Cc, w_g, b_g, F2, 256,
                                                   16384);
  conv1x1_tile<<<dim3(16, 64, 4), blk, 0, stream>>>(Cc, w_h, b_h, E, 256,
                                                    16384);
  win_attn_kernel<<<dim3(32, 32, 4), blk, 0, stream>>>(F1, F2, E, out_attn);
  // ---- d1: convT 256->128, AdaLIN, relu (bf16 out) ----
  convt3x3_tile<float, bf16><<<dim3(64, 16, 4), blk, 0, stream>>>(
      Cc, w_d1, b_d1, Bb2, 256, 128, 128);
  reduce_nc_kernel<bf16><<<512, blk, 0, stream>>>(Bb2, stats, 65536);
  adalin_coef_kernel<<<2, 256, 0, stream>>>(stats, rho4, gam4, bet4, 4, 128,
                                            1.f / 65536.f);
  scale_shift_kernel<bf16><<<131072, blk, 0, stream>>>(Bb2, stats, 65536,
                                                       (size_t)33554432, 1);
  // ---- d2: convT 128->64, AdaLIN, relu (bf16) ----
  convt3x3_tile<bf16, bf16><<<dim3(256, 8, 4), blk, 0, stream>>>(
      Bb2, w_d2, b_d2, A2, 128, 256, 256);
  reduce_nc_kernel<bf16><<<256, blk, 0, stream>>>(A2, stats, 262144);
  adalin_coef_kernel<<<1, 256, 0, stream>>>(stats, rho5, gam5, bet5, 4, 64,
                                            1.f / 262144.f);
  scale_shift_kernel<bf16><<<262144, blk, 0, stream>>>(A2, stats, 262144,
                                                       (size_t)67108864, 1);
  // ---- head: 7x7 conv (LDS-tiled, 2-row blocks) + tanh -> fp32 img ----
  conv7_head<<<dim3(256, 1, 4), blk, 0, stream>>>(A2, w_d3, b_d3, out_img);
}

// Round 9
// 10083.450 us; speedup vs baseline: 1.0525x; 1.0525x over previous
//
#include <hip/hip_runtime.h>
#include <hip/hip_bf16.h>
#include <hip/hip_fp16.h>

#define EPSN 1e-5f

typedef __hip_bfloat16 bf16;
typedef __half f16;
typedef __attribute__((ext_vector_type(8))) short bf16x8;
typedef __attribute__((ext_vector_type(4))) float f32x4;

__device__ __forceinline__ float b2f(bf16 v) { return __bfloat162float(v); }
__device__ __forceinline__ bf16 f2b(float v) { return __float2bfloat16(v); }
__device__ __forceinline__ unsigned short f2bu(float v) {
  bf16 h = __float2bfloat16(v);
  return *reinterpret_cast<unsigned short*>(&h);
}
__device__ __forceinline__ float bu2f(unsigned short u) {
  unsigned int b = ((unsigned int)u) << 16;
  return __uint_as_float(b);
}
__device__ __forceinline__ unsigned short f2hu(float v) {
  f16 h = __float2half(v);
  return *reinterpret_cast<unsigned short*>(&h);
}
__device__ __forceinline__ float hu2f(unsigned short u) {
  f16 h = *reinterpret_cast<f16*>(&u);
  return __half2float(h);
}
__device__ __forceinline__ void stv(bf16* p, size_t i, float v) { p[i] = f2b(v); }
__device__ __forceinline__ void stv(float* p, size_t i, float v) { p[i] = v; }
__device__ __forceinline__ void stv(f16* p, size_t i, float v) {
  p[i] = __float2half(v);
}

// vec4 load/store helpers (fp32/bf16/fp16 storage, fp32 compute)
__device__ __forceinline__ float4 ld4(const float* p) { return *(const float4*)p; }
__device__ __forceinline__ float4 ld4(const bf16* p) {
  ushort4 u = *(const ushort4*)p;
  float4 r;
  r.x = bu2f(u.x);
  r.y = bu2f(u.y);
  r.z = bu2f(u.z);
  r.w = bu2f(u.w);
  return r;
}
__device__ __forceinline__ float4 ld4(const f16* p) {
  ushort4 u = *(const ushort4*)p;
  float4 r;
  r.x = hu2f(u.x);
  r.y = hu2f(u.y);
  r.z = hu2f(u.z);
  r.w = hu2f(u.w);
  return r;
}
__device__ __forceinline__ void st4(float* p, float4 v) { *(float4*)p = v; }
__device__ __forceinline__ void st4(bf16* p, float4 v) {
  uint2 o;
  o.x = (unsigned)f2bu(v.x) | ((unsigned)f2bu(v.y) << 16);
  o.y = (unsigned)f2bu(v.z) | ((unsigned)f2bu(v.w) << 16);
  *(uint2*)p = o;
}
__device__ __forceinline__ void st4(f16* p, float4 v) {
  ushort4 o = {f2hu(v.x), f2hu(v.y), f2hu(v.z), f2hu(v.w)};
  *(ushort4*)p = o;
}

// ---------------- zero the stats scratch (atomicAdd target) -----------------
__global__ void zero_stats_kernel(float* __restrict__ stats) {
  for (int k = threadIdx.x; k < 2048; k += 256) stats[k] = 0.f;
}

// ------- weight convert: [Co][Ci][3][3] fp32 -> [tap][co][ci] bf16 hi+lo ----
__global__ __launch_bounds__(256) void convert_w_kernel(
    const float* __restrict__ rw1, const float* __restrict__ rw2,
    unsigned short* __restrict__ wb) {
  int i = blockIdx.x * 256 + threadIdx.x;  // < 8*9*65536 = 4718592
  if (i >= 4718592) return;
  int conv = i / 589824;
  int rem = i % 589824;
  int tap = rem / 65536;
  int cc = rem % 65536;  // co*256+ci
  const float* src = ((conv & 1) ? rw2 : rw1) + (size_t)(conv >> 1) * 589824;
  float v = src[(size_t)cc * 9 + tap];
  bf16 h = __float2bfloat16(v);
  float fh = __bfloat162float(h);
  wb[i] = *reinterpret_cast<unsigned short*>(&h);
  bf16 l = __float2bfloat16(v - fh);
  wb[4718592 + i] = *reinterpret_cast<unsigned short*>(&l);
}

// ---------------- 3x3 s1 p1 conv via MFMA (bf16x3), Ci=Co=256, H=W=128 ------
__device__ __forceinline__ int swz3(int idx) {
  return (idx & 3) ^ ((idx >> 2) & 1);
}

__global__ __launch_bounds__(256) void conv3x3s1_mfma(
    const float* __restrict__ x, const unsigned short* __restrict__ wh,
    const unsigned short* __restrict__ wl, const float* __restrict__ bias,
    float* __restrict__ y) {
  const int H = 128, W = 128;
  int r = blockIdx.x;    // output row
  int cog = blockIdx.y;  // 0..1 (128 co each)
  int n = blockIdx.z;
  int tid = threadIdx.x;
  int wv = tid >> 6, lane = tid & 63;
  int wco = (wv >> 1) * 64, wpx = (wv & 1) * 64;
  int l15 = lane & 15, l4 = lane >> 4;

  __shared__ __align__(16) unsigned short Xh[3 * 130 * 32];
  __shared__ __align__(16) unsigned short Xl[3 * 130 * 32];
  __shared__ __align__(16) unsigned short Ah[128 * 32];
  __shared__ __align__(16) unsigned short Al[128 * 32];

  f32x4 acc[4][4];
#pragma unroll
  for (int m = 0; m < 4; ++m)
#pragma unroll
    for (int nf = 0; nf < 4; ++nf) acc[m][nf] = (f32x4){0.f, 0.f, 0.f, 0.f};

  const float* xn0 = x + (size_t)n * 256 * H * W;

  for (int cb = 0; cb < 8; ++cb) {
    int ci0 = cb * 32;
    {
      const float* xn = xn0 + (size_t)ci0 * H * W;
      for (int t = tid; t < 1560; t += 256) {
        int q = t & 3;
        int cr = t >> 2;     // 0..389
        int col = cr % 130;  // 0..129
        int row = cr / 130;  // 0..2
        int gr = r + row - 1;
        int gc = col - 1;
        bool ok = (gr >= 0) && (gr < H) && (gc >= 0) && (gc < W);
        uint4 ph = {0, 0, 0, 0};
        uint4 pl = {0, 0, 0, 0};
        if (ok) {
          const float* xp =
              xn + (size_t)(q * 8) * (H * W) + (size_t)gr * W + gc;
          unsigned short vh[8], vl[8];
#pragma unroll
          for (int e = 0; e < 8; ++e) {
            float v = xp[(size_t)e * H * W];
            bf16 hb = __float2bfloat16(v);
            float fh = __bfloat162float(hb);
            bf16 lb = __float2bfloat16(v - fh);
            vh[e] = *reinterpret_cast<unsigned short*>(&hb);
            vl[e] = *reinterpret_cast<unsigned short*>(&lb);
          }
          ph.x = (unsigned)vh[0] | ((unsigned)vh[1] << 16);
          ph.y = (unsigned)vh[2] | ((unsigned)vh[3] << 16);
          ph.z = (unsigned)vh[4] | ((unsigned)vh[5] << 16);
          ph.w = (unsigned)vh[6] | ((unsigned)vh[7] << 16);
          pl.x = (unsigned)vl[0] | ((unsigned)vl[1] << 16);
          pl.y = (unsigned)vl[2] | ((unsigned)vl[3] << 16);
          pl.z = (unsigned)vl[4] | ((unsigned)vl[5] << 16);
          pl.w = (unsigned)vl[6] | ((unsigned)vl[7] << 16);
        }
        int slot = (cr * 4 + (q ^ swz3(col))) * 8;
        *(uint4*)(&Xh[slot]) = ph;
        *(uint4*)(&Xl[slot]) = pl;
      }
    }
    for (int tap = 0; tap < 9; ++tap) {
      for (int t = tid; t < 1024; t += 256) {
        int half = t >> 9;
        int rem = t & 511;
        int q = rem & 3;
        int co = rem >> 2;
        const unsigned short* wsrc =
            (half ? wl : wh) +
            ((size_t)tap * 256 + cog * 128 + co) * 256 + ci0 + q * 8;
        uint4 pk = *(const uint4*)wsrc;
        int slot = (co * 4 + (q ^ swz3(co))) * 8;
        *(uint4*)((half ? Al : Ah) + slot) = pk;
      }
      __syncthreads();
      int ky = tap / 3;
      int kx = tap - ky * 3;
      bf16x8 ahf[4], alf[4], bhf[4], blf[4];
#pragma unroll
      for (int m = 0; m < 4; ++m) {
        int co = wco + m * 16 + l15;
        int slot = (co * 4 + (l4 ^ swz3(co))) * 8;
        ahf[m] = *(const bf16x8*)(&Ah[slot]);
        alf[m] = *(const bf16x8*)(&Al[slot]);
      }
#pragma unroll
      for (int nf = 0; nf < 4; ++nf) {
        int col = wpx + nf * 16 + l15 + kx;  // lds col = px + kx
        int slot = ((ky * 130 + col) * 4 + (l4 ^ swz3(col))) * 8;
        bhf[nf] = *(const bf16x8*)(&Xh[slot]);
        blf[nf] = *(const bf16x8*)(&Xl[slot]);
      }
#pragma unroll
      for (int m = 0; m < 4; ++m)
#pragma unroll
        for (int nf = 0; nf < 4; ++nf) {
          acc[m][nf] = __builtin_amdgcn_mfma_f32_16x16x32_bf16(
              ahf[m], bhf[nf], acc[m][nf], 0, 0, 0);
          acc[m][nf] = __builtin_amdgcn_mfma_f32_16x16x32_bf16(
              ahf[m], blf[nf], acc[m][nf], 0, 0, 0);
          acc[m][nf] = __builtin_amdgcn_mfma_f32_16x16x32_bf16(
              alf[m], bhf[nf], acc[m][nf], 0, 0, 0);
        }
      __syncthreads();
    }
  }
#pragma unroll
  for (int m = 0; m < 4; ++m) {
    int cob = cog * 128 + wco + m * 16 + l4 * 4;
#pragma unroll
    for (int reg = 0; reg < 4; ++reg) {
      float bv = bias[cob + reg];
      float* yr =
          y + (((size_t)(n * 256 + cob + reg) * H) + r) * W + wpx + l15;
#pragma unroll
      for (int nf = 0; nf < 4; ++nf) yr[nf * 16] = acc[m][nf][reg] + bv;
    }
  }
}

// ---------------- e1: 7x7 conv p3, CI=3, LDS-tiled (1 ci slice at a time) ---
// 8co x 8px(interleaved), raw f16 out + stats. Block: 4 rows x 512 cols.
// grid (128, 8, 4). LDS: 20.8K (Xs) + 4.7K (wsh) + 0.25K = 25.8 KB.
__global__ __launch_bounds__(256) void conv7_e1(
    const float* __restrict__ x, const float* __restrict__ w,
    const float* __restrict__ bias, float* __restrict__ stats,
    f16* __restrict__ y) {
  const int H = 512, W = 512;
  __shared__ float Xs[5200];         // [10][520] one ci, zero-padded halo
  __shared__ float wsh[8 * 3 * 49];  // 8 co slab
  __shared__ float sred[4][8], qred[4][8];
  int cog = blockIdx.y;  // 8 groups x 8 co
  int n = blockIdx.z;
  int tid = threadIdx.x;
  int r0 = blockIdx.x * 4;
  int tr = tid >> 6;
  int lane = tid & 63;
  for (int t = tid; t < 1176; t += 256) wsh[t] = w[cog * 1176 + t];
  const float* xb = x + (size_t)n * 3 * H * W;
  float acc[8][8];
#pragma unroll
  for (int j = 0; j < 8; ++j) {
#pragma unroll
    for (int p = 0; p < 8; ++p) acc[j][p] = 0.f;
  }
  for (int ci = 0; ci < 3; ++ci) {
    __syncthreads();  // protect Xs from prev readers; orders wsh on 1st iter
    for (int t = tid; t < 5200; t += 256) {
      int row = t / 520;
      int col = t - row * 520;
      int gr = r0 - 3 + row;
      int gc = col - 3;
      float v = 0.f;
      if (gr >= 0 && gr < H && gc >= 0 && gc < W)
        v = xb[((size_t)ci * H + gr) * W + gc];
      Xs[t] = v;
    }
    __syncthreads();
    for (int i = 0; i < 7; ++i) {
      const float* xr = &Xs[(tr + i) * 520 + lane];
      float v[8][7];
#pragma unroll
      for (int p = 0; p < 8; ++p)
#pragma unroll
        for (int k = 0; k < 7; ++k) v[p][k] = xr[p * 64 + k];
#pragma unroll
      for (int j = 0; j < 8; ++j) {
        const float* wr = &wsh[(j * 3 + ci) * 49 + i * 7];
        float w0 = wr[0], w1 = wr[1], w2 = wr[2], w3 = wr[3], w4 = wr[4],
              w5 = wr[5], w6 = wr[6];
#pragma unroll
        for (int p = 0; p < 8; ++p)
          acc[j][p] += v[p][0] * w0 + v[p][1] * w1 + v[p][2] * w2 +
                       v[p][3] * w3 + v[p][4] * w4 + v[p][5] * w5 +
                       v[p][6] * w6;
      }
    }
  }
  int r = r0 + tr;
#pragma unroll
  for (int j = 0; j < 8; ++j) {
    int co = cog * 8 + j;
    float bv = bias[co];
    f16* yr = y + ((size_t)(n * 64 + co) * H + r) * W + lane;
    float s = 0.f, q = 0.f;
#pragma unroll
    for (int p = 0; p < 8; ++p) {
      float o = acc[j][p] + bv;
      yr[p * 64] = __float2half(o);
      s += o;
      q += o * o;
    }
#pragma unroll
    for (int off = 32; off > 0; off >>= 1) {
      s += __shfl_down(s, off, 64);
      q += __shfl_down(q, off, 64);
    }
    if (lane == 0) {
      sred[tr][j] = s;
      qred[tr][j] = q;
    }
  }
  __syncthreads();
  if (tid < 8) {
    float S = sred[0][tid] + sred[1][tid] + sred[2][tid] + sred[3][tid];
    float Q = qred[0][tid] + qred[1][tid] + qred[2][tid] + qred[3][tid];
    atomicAdd(&stats[n * 64 + cog * 8 + tid], S);
    atomicAdd(&stats[1024 + n * 64 + cog * 8 + tid], Q);
  }
}

// ---------------- head: 7x7 conv p3, CI=64 (bf16 in), LDS-tiled + tanh ------
// WIDTH-split blocks: 4 rows x 256 cols, grid (128, 2, 4) = 4 blocks/CU.
// Same inner structure as the 64-VGPR R7 variant (tr=tid>>6, stride-64 cols).
// LDS: [2][10][264] Xs (10.6K) + wsh (18.8K) = 29.4 KB.
__global__ __launch_bounds__(256) void conv7_head(
    const bf16* __restrict__ xin, const float* __restrict__ w,
    const float* __restrict__ bias, float* __restrict__ y) {
  const int H = 512, W = 512;
  __shared__ unsigned short Xs[5280];   // [2][10][264] bf16 bits
  __shared__ unsigned short wsh[9408];  // [3][64][49] f16 bits
  int n = blockIdx.z;
  int cbase = blockIdx.y * 256;
  int tid = threadIdx.x;
  int r0 = blockIdx.x * 4;
  int tr = tid >> 6;
  int lane = tid & 63;
  for (int t = tid; t < 9408; t += 256) wsh[t] = f2hu(w[t]);
  const unsigned short* xb =
      (const unsigned short*)xin + (size_t)n * 64 * H * W;
  float acc[3][4];
#pragma unroll
  for (int j = 0; j < 3; ++j) {
    float b = bias[j];
#pragma unroll
    for (int p = 0; p < 4; ++p) acc[j][p] = b;
  }
  for (int cc0 = 0; cc0 < 64; cc0 += 2) {
    __syncthreads();  // protect Xs from prev chunk's readers (+wsh 1st it)
    for (int t = tid; t < 5280; t += 256) {
      int ci = t / 2640;
      int rem = t - ci * 2640;
      int row = rem / 264;
      int col = rem - row * 264;
      int gr = r0 - 3 + row;
      int gc = cbase - 3 + col;
      unsigned short v = 0;
      if (gr >= 0 && gr < H && gc >= 0 && gc < W)
        v = xb[((size_t)(cc0 + ci) * H + gr) * W + gc];
      Xs[t] = v;
    }
    __syncthreads();
    for (int ci = 0; ci < 2; ++ci)
      for (int i = 0; i < 7; ++i) {
        const unsigned short* xr = &Xs[(ci * 10 + tr + i) * 264 + lane];
        float v[4][7];
#pragma unroll
        for (int p = 0; p < 4; ++p)
#pragma unroll
          for (int k = 0; k < 7; ++k) v[p][k] = bu2f(xr[p * 64 + k]);
#pragma unroll
        for (int j = 0; j < 3; ++j) {
          const unsigned short* wr = &wsh[(j * 64 + cc0 + ci) * 49 + i * 7];
          float w0 = hu2f(wr[0]), w1 = hu2f(wr[1]), w2 = hu2f(wr[2]),
                w3 = hu2f(wr[3]), w4 = hu2f(wr[4]), w5 = hu2f(wr[5]),
                w6 = hu2f(wr[6]);
#pragma unroll
          for (int p = 0; p < 4; ++p)
            acc[j][p] += v[p][0] * w0 + v[p][1] * w1 + v[p][2] * w2 +
                         v[p][3] * w3 + v[p][4] * w4 + v[p][5] * w5 +
                         v[p][6] * w6;
        }
      }
  }
  int r = r0 + tr;
#pragma unroll
  for (int j = 0; j < 3; ++j) {
    float* yr = y + ((size_t)(n * 3 + j) * H + r) * W + cbase + lane;
#pragma unroll
    for (int p = 0; p < 4; ++p) yr[p * 64] = tanhf(acc[j][p]);
  }
}

// ---------------- 3x3 s2 p1 conv, tiled 4 px x 8 co ------------------------
// NORM: input v = relu(x*sc[n,ci] + sh[n,ci]) fused from stats (AdaLIN coefs)
template <typename Tin, typename Tout, bool NORM>
__global__ __launch_bounds__(256) void conv3x3s2_tile(
    const Tin* __restrict__ x, const float* __restrict__ w,
    const float* __restrict__ bias, const float* __restrict__ stats,
    Tout* __restrict__ y, int Ci, int Hi, int Wi) {
  int Ho = Hi >> 1, Wo = Wi >> 1;
  int cog = blockIdx.y;
  int Co = gridDim.y * 8;
  int n = blockIdx.z;
  int CG = Wo >> 2;
  int rpb = 256 / CG;
  int tid = threadIdx.x;
  int r = blockIdx.x * rpb + tid / CG;
  int c0 = (tid % CG) * 4;
  const Tin* xb = x + (size_t)n * Ci * Hi * Wi;
  int ir0 = 2 * r - 1;
  float mr0 = (ir0 >= 0) ? 1.f : 0.f;
  int cr0 = max(ir0, 0);
  int icl = 2 * c0 - 1;
  float mcl = (icl >= 0) ? 1.f : 0.f;
  int ccl = max(icl, 0);
  float acc[8][4];
#pragma unroll
  for (int j = 0; j < 8; ++j) {
    float b = bias[cog * 8 + j];
#pragma unroll
    for (int p = 0; p < 4; ++p) acc[j][p] = b;
  }
  for (int ci = 0; ci < Ci; ++ci) {
    const Tin* xc = xb + (size_t)ci * Hi * Wi;
    float sc = 1.f, sh = 0.f;
    if (NORM) {
      sc = stats[2048 + n * Ci + ci];
      sh = stats[3072 + n * Ci + ci];
    }
    float v[3][9];
#pragma unroll
    for (int i = 0; i < 3; ++i) {
      int rr = (i == 0) ? cr0 : (2 * r - 1 + i);
      float mi = (i == 0) ? mr0 : 1.f;
      const Tin* xr = xc + (size_t)rr * Wi;
      float t[9];
      t[0] = (float)xr[ccl];
      float4 a = ld4(xr + 2 * c0);
      float4 b4 = ld4(xr + 2 * c0 + 4);
      t[1] = a.x;
      t[2] = a.y;
      t[3] = a.z;
      t[4] = a.w;
      t[5] = b4.x;
      t[6] = b4.y;
      t[7] = b4.z;
      t[8] = b4.w;
      if (NORM) {
#pragma unroll
        for (int k = 0; k < 9; ++k) t[k] = fmaxf(fmaf(t[k], sc, sh), 0.f);
      }
      v[i][0] = t[0] * (mcl * mi);
#pragma unroll
      for (int k = 1; k < 9; ++k) v[i][k] = t[k] * mi;
    }
#pragma unroll
    for (int j = 0; j < 8; ++j) {
      const float* wc = w + ((size_t)(cog * 8 + j) * Ci + ci) * 9;
#pragma unroll
      for (int p = 0; p < 4; ++p) {
        acc[j][p] += v[0][2 * p] * wc[0] + v[0][2 * p + 1] * wc[1] +
                     v[0][2 * p + 2] * wc[2] + v[1][2 * p] * wc[3] +
                     v[1][2 * p + 1] * wc[4] + v[1][2 * p + 2] * wc[5] +
                     v[2][2 * p] * wc[6] + v[2][2 * p + 1] * wc[7] +
                     v[2][2 * p + 2] * wc[8];
      }
    }
  }
#pragma unroll
  for (int j = 0; j < 8; ++j) {
    float4 o = {acc[j][0], acc[j][1], acc[j][2], acc[j][3]};
    st4(y + ((size_t)(n * Co + cog * 8 + j) * Ho + r) * Wo + c0, o);
  }
}

// ---------------- 1x1 conv, tiled 4 px x 4 co, fp32 -------------------------
__global__ __launch_bounds__(256) void conv1x1_tile(
    const float* __restrict__ x, const float* __restrict__ w,
    const float* __restrict__ bias, float* __restrict__ y, int Ci, int HW) {
  int cog = blockIdx.y;
  int Co = gridDim.y * 4;
  int n = blockIdx.z;
  int p0 = (blockIdx.x * 256 + threadIdx.x) * 4;
  const float* xb = x + (size_t)n * Ci * HW + p0;
  float acc[4][4];
#pragma unroll
  for (int j = 0; j < 4; ++j) {
    float b = bias[cog * 4 + j];
#pragma unroll
    for (int p = 0; p < 4; ++p) acc[j][p] = b;
  }
  for (int ci = 0; ci < Ci; ++ci) {
    float4 xv = *(const float4*)(xb + (size_t)ci * HW);
#pragma unroll
    for (int j = 0; j < 4; ++j) {
      float wv = w[(size_t)(cog * 4 + j) * Ci + ci];
      acc[j][0] += xv.x * wv;
      acc[j][1] += xv.y * wv;
      acc[j][2] += xv.z * wv;
      acc[j][3] += xv.w * wv;
    }
  }
#pragma unroll
  for (int j = 0; j < 4; ++j) {
    float4 o = {acc[j][0], acc[j][1], acc[j][2], acc[j][3]};
    *(float4*)(y + (size_t)(n * Co + cog * 4 + j) * HW + p0) = o;
  }
}

// ---------------- ConvTranspose2d k3 s2 p1 op1, tiled 2x2 quad x 8 co -------
template <typename Tin, typename Tout>
__global__ __launch_bounds__(256) void convt3x3_tile(
    const Tin* __restrict__ x, const float* __restrict__ w,
    const float* __restrict__ bias, Tout* __restrict__ y, int Ci, int Hi,
    int Wi) {
  int Ho = Hi * 2, Wo = Wi * 2;
  int cog = blockIdx.y;
  int Co = gridDim.y * 8;
  int n = blockIdx.z;
  int q = blockIdx.x * 256 + threadIdx.x;
  int yq = q / Wi, xq = q % Wi;
  const Tin* xb = x + (size_t)n * Ci * Hi * Wi;
  float mx = (xq + 1 < Wi) ? 1.f : 0.f;
  int x1 = min(xq + 1, Wi - 1);
  float my = (yq + 1 < Hi) ? 1.f : 0.f;
  int y1 = min(yq + 1, Hi - 1);
  float mxy = mx * my;
  float acc[8][4];
#pragma unroll
  for (int j = 0; j < 8; ++j) {
    float b = bias[cog * 8 + j];
#pragma unroll
    for (int p = 0; p < 4; ++p) acc[j][p] = b;
  }
  for (int ci = 0; ci < Ci; ++ci) {
    const Tin* xc = xb + (size_t)ci * Hi * Wi;
    float a = (float)xc[(size_t)yq * Wi + xq];
    float bv = (float)xc[(size_t)yq * Wi + x1] * mx;
    float c = (float)xc[(size_t)y1 * Wi + xq] * my;
    float d = (float)xc[(size_t)y1 * Wi + x1] * mxy;
#pragma unroll
    for (int j = 0; j < 8; ++j) {
      const float* wc = w + ((size_t)ci * Co + cog * 8 + j) * 9;
      acc[j][0] += a * wc[4];
      acc[j][1] += bv * wc[3] + a * wc[5];
      acc[j][2] += c * wc[1] + a * wc[7];
      acc[j][3] += d * wc[0] + c * wc[2] + bv * wc[6] + a * wc[8];
    }
  }
#pragma unroll
  for (int j = 0; j < 8; ++j) {
    size_t base = ((size_t)(n * Co + cog * 8 + j) * Ho + 2 * yq) * Wo + 2 * xq;
    stv(y, base, acc[j][0]);
    stv(y, base + 1, acc[j][1]);
    stv(y, base + Wo, acc[j][2]);
    stv(y, base + Wo + 1, acc[j][3]);
  }
}

// ---------------- per-(n,c) sum / sumsq reduction ---------------------------
template <typename Tin>
__global__ __launch_bounds__(256) void reduce_nc_kernel(
    const Tin* __restrict__ x, float* __restrict__ stats, int HW) {
  int b = blockIdx.x;
  const Tin* p = x + (size_t)b * HW;
  float s = 0.f, q = 0.f;
  for (int i = threadIdx.x; i < HW; i += 256) {
    float v = (float)p[i];
    s += v;
    q += v * v;
  }
  __shared__ float ss[256], qq[256];
  ss[threadIdx.x] = s;
  qq[threadIdx.x] = q;
  __syncthreads();
  for (int off = 128; off > 0; off >>= 1) {
    if (threadIdx.x < off) {
      ss[threadIdx.x] += ss[threadIdx.x + off];
      qq[threadIdx.x] += qq[threadIdx.x + off];
    }
    __syncthreads();
  }
  if (threadIdx.x == 0) {
    stats[b] = ss[0];
    stats[1024 + b] = qq[0];
  }
}

// ---------------- AdaLIN coefficients ---------------------------------------
__global__ void adalin_coef_kernel(float* __restrict__ stats,
                                   const float* __restrict__ rho,
                                   const float* __restrict__ gam,
                                   const float* __restrict__ bet, int N, int C,
                                   float invHW) {
  int i = blockIdx.x * blockDim.x + threadIdx.x;
  if (i >= N * C) return;
  int c = i % C;
  const float* sums = stats;
  const float* sqs = stats + 1024;
  float im = sums[i] * invHW;
  float iv = sqs[i] * invHW - im * im;
  float lsum = 0.f, lsq = 0.f;
  for (int n = 0; n < N; ++n) {
    lsum += sums[n * C + c];
    lsq += sqs[n * C + c];
  }
  float lm = lsum * invHW / N;
  float lv = lsq * invHW / N - lm * lm;
  float r = rho[c];
  float mean = r * im + (1.f - r) * lm;
  float var = fmaxf(r * iv + (1.f - r) * lv, 0.f);
  float sc = gam[c] / sqrtf(var + EPSN);
  stats[2048 + i] = sc;
  stats[3072 + i] = bet[c] - mean * sc;
}

// ---------------- InstanceNorm coefficients ---------------------------------
__global__ void inorm_coef_kernel(float* __restrict__ stats, int NC,
                                  float invHW) {
  int i = blockIdx.x * blockDim.x + threadIdx.x;
  if (i >= NC) return;
  float im = stats[i] * invHW;
  float iv = fmaxf(stats[1024 + i] * invHW - im * im, 0.f);
  float sc = 1.f / sqrtf(iv + EPSN);
  stats[2048 + i] = sc;
  stats[3072 + i] = -im * sc;
}

// ---------------- x = (relu?)(x*scale[nc] + shift[nc])  (in-place) ----------
template <typename T>
__global__ __launch_bounds__(256) void scale_shift_kernel(
    T* __restrict__ x, const float* __restrict__ stats, int HW, size_t total,
    int relu) {
  size_t i = (size_t)blockIdx.x * 256 + threadIdx.x;
  if (i >= total) return;
  int nc = (int)(i / (size_t)HW);
  float v = (float)x[i] * stats[2048 + nc] + stats[3072 + nc];
  if (relu) v = fmaxf(v, 0.f);
  stv(x, i, v);
}

// ---------------- dst = relu(dst + a)  (fp32) -------------------------------
__global__ __launch_bounds__(256) void add_relu_kernel(
    float* __restrict__ dst, const float* __restrict__ a, size_t total) {
  size_t i = (size_t)blockIdx.x * 256 + threadIdx.x;
  if (i >= total) return;
  dst[i] = fmaxf(dst[i] + a[i], 0.f);
}

// ---------------- windowed attention (all fp32) -----------------------------
__global__ __launch_bounds__(256) void win_attn_kernel(
    const float* __restrict__ f, const float* __restrict__ g,
    const float* __restrict__ h, float* __restrict__ out) {
  const int H = 128;
  int j = blockIdx.x;
  int i = blockIdx.y;
  int b = blockIdx.z;
  __shared__ float fs[32 * 64];
  __shared__ float gs[32 * 64];
  __shared__ float att[16 * 64];
  int t = threadIdx.x;
  for (int idx = t; idx < 32 * 64; idx += 256) {
    int c = idx >> 6, k = idx & 63;
    int hr = i * 4 + (k >> 3), wc = j * 4 + (k & 7);
    float fv = 0.f, gv = 0.f;
    if (hr < H && wc < H) {
      size_t o = ((size_t)(b * 32 + c) * H + hr) * H + wc;
      fv = f[o];
      gv = g[o];
    }
    fs[idx] = fv;
    gs[idx] = gv;
  }
  __syncthreads();
  for (int idx = t; idx < 1024; idx += 256) {
    int q = idx >> 6, k = idx & 63;
    int qi = (q >> 2) * 8 + (q & 3);
    int hr = i * 4 + (k >> 3), wc = j * 4 + (k & 7);
    float s;
    if (hr < H && wc < H) {
      s = 0.f;
      for (int c = 0; c < 32; ++c) s += fs[c * 64 + qi] * gs[c * 64 + k];
    } else {
      s = -1e30f;
    }
    att[idx] = s;
  }
  __syncthreads();
  if (t < 16) {
    float m = -1e30f;
    for (int k = 0; k < 64; ++k) m = fmaxf(m, att[t * 64 + k]);
    float d = 0.f;
    for (int k = 0; k < 64; ++k) {
      float e = expf(att[t * 64 + k] - m);
      att[t * 64 + k] = e;
      d += e;
    }
    float inv = 1.f / d;
    for (int k = 0; k < 64; ++k) att[t * 64 + k] *= inv;
  }
  __syncthreads();
  int c = t;
  float accs[16];
  for (int q = 0; q < 16; ++q) accs[q] = 0.f;
  const float* hb = h + (size_t)(b * 256 + c) * H * H;
  for (int k = 0; k < 64; ++k) {
    int hr = i * 4 + (k >> 3), wc = j * 4 + (k & 7);
    if (hr >= H || wc >= H) continue;
    float hv = hb[hr * H + wc];
    for (int q = 0; q < 16; ++q) accs[q] += hv * att[q * 64 + k];
  }
  for (int q = 0; q < 16; ++q) {
    int oh = i * 4 + (q >> 2), ow = j * 4 + (q & 3);
    out[((size_t)(b * 256 + c) * H + oh) * H + ow] = accs[q];
  }
}

// ============================================================================
extern "C" void kernel_launch(void* const* d_in, const int* in_sizes, int n_in,
                              void* d_out, int out_size, void* d_ws,
                              size_t ws_size, hipStream_t stream) {
  const float* x = (const float*)d_in[0];
  const float* w_e1 = (const float*)d_in[1];
  const float* b_e1 = (const float*)d_in[2];
  const float* rho1 = (const float*)d_in[3];
  const float* gam1 = (const float*)d_in[4];
  const float* bet1 = (const float*)d_in[5];
  const float* w_e2 = (const float*)d_in[6];
  const float* b_e2 = (const float*)d_in[7];
  const float* rho2 = (const float*)d_in[8];
  const float* gam2 = (const float*)d_in[9];
  const float* bet2 = (const float*)d_in[10];
  const float* w_e3 = (const float*)d_in[11];
  const float* b_e3 = (const float*)d_in[12];
  const float* rho3 = (const float*)d_in[13];
  const float* gam3 = (const float*)d_in[14];
  const float* bet3 = (const float*)d_in[15];
  const float* rw1 = (const float*)d_in[16];
  const float* rb1 = (const float*)d_in[17];
  const float* rw2 = (const float*)d_in[18];
  const float* rb2 = (const float*)d_in[19];
  const float* w_f = (const float*)d_in[20];
  const float* b_f = (const float*)d_in[21];
  const float* w_g = (const float*)d_in[22];
  const float* b_g = (const float*)d_in[23];
  const float* w_h = (const float*)d_in[24];
  const float* b_h = (const float*)d_in[25];
  const float* w_d1 = (const float*)d_in[26];
  const float* b_d1 = (const float*)d_in[27];
  const float* rho4 = (const float*)d_in[28];
  const float* gam4 = (const float*)d_in[29];
  const float* bet4 = (const float*)d_in[30];
  const float* w_d2 = (const float*)d_in[31];
  const float* b_d2 = (const float*)d_in[32];
  const float* rho5 = (const float*)d_in[33];
  const float* gam5 = (const float*)d_in[34];
  const float* bet5 = (const float*)d_in[35];
  const float* w_d3 = (const float*)d_in[36];
  const float* b_d3 = (const float*)d_in[37];

  // ws layout (192 MiB):
  // E1H f16 raw e1 [0,128MiB) (dead after e2)
  // B2H f16 raw e2 [128,192) (dead after e3; later Bb2 bf16 d1 out)
  // Cc fp32 [0,64), D fp32 [64,128), E fp32 [128,192) (residual stage)
  // F1/F2 fp32 [64,80) (attention f/g); A2 bf16 [0,128) (d2 out)
  char* wsb = (char*)d_ws;
  f16* E1H = (f16*)wsb;
  float* Cc = (float*)wsb;
  float* D = (float*)(wsb + 67108864);
  float* E = (float*)(wsb + 134217728);
  float* F1 = (float*)(wsb + 67108864);
  float* F2 = (float*)(wsb + 75497472);
  f16* B2H = (f16*)(wsb + 134217728);
  bf16* Bb2 = (bf16*)(wsb + 134217728);
  bf16* A2 = (bf16*)wsb;

  float* out_img = (float*)d_out;
  float* out_attn = out_img + 3145728;
  // 16 KiB stats scratch at head of img region; fully overwritten by head conv
  float* stats = (float*)d_out;
  // bf16 hi+lo residual weights scratch in the (not yet written) out_attn
  // region; fully consumed before win_attn_kernel writes out_attn.
  unsigned short* wbres = (unsigned short*)((char*)d_out + 12582912);

  dim3 blk(256);

  // ---- convert residual weights to bf16 hi+lo [tap][co][ci] (once) ----
  convert_w_kernel<<<18432, blk, 0, stream>>>(rw1, rw2, wbres);

  // ---- e1: 7x7 conv (LDS-tiled) -> raw f16 + stats ----
  zero_stats_kernel<<<1, 256, 0, stream>>>(stats);
  conv7_e1<<<dim3(128, 8, 4), blk, 0, stream>>>(x, w_e1, b_e1, stats, E1H);
  adalin_coef_kernel<<<1, 256, 0, stream>>>(stats, rho1, gam1, bet1, 4, 64,
                                            1.f / 262144.f);
  // ---- e2: 3x3 s2 conv with fused e1-norm+relu -> raw f16 ----
  conv3x3s2_tile<f16, f16, true><<<dim3(64, 16, 4), blk, 0, stream>>>(
      E1H, w_e2, b_e2, stats, B2H, 64, 512, 512);
  reduce_nc_kernel<f16><<<512, blk, 0, stream>>>(B2H, stats, 65536);
  adalin_coef_kernel<<<2, 256, 0, stream>>>(stats, rho2, gam2, bet2, 4, 128,
                                            1.f / 65536.f);
  // ---- e3: 3x3 s2 conv with fused e2-norm+relu -> fp32, then AdaLIN ----
  conv3x3s2_tile<f16, float, true><<<dim3(16, 32, 4), blk, 0, stream>>>(
      B2H, w_e3, b_e3, stats, Cc, 128, 256, 256);
  reduce_nc_kernel<float><<<1024, blk, 0, stream>>>(Cc, stats, 16384);
  adalin_coef_kernel<<<4, 256, 0, stream>>>(stats, rho3, gam3, bet3, 4, 256,
                                            1.f / 16384.f);
  scale_shift_kernel<float><<<65536, blk, 0, stream>>>(Cc, stats, 16384,
                                                       (size_t)16777216, 1);
  // ---- 4 residual blocks (bf16x3 MFMA convs) ----
  for (int r = 0; r < 4; ++r) {
    const float* rb1p = rb1 + (size_t)r * 256;
    const float* rb2p = rb2 + (size_t)r * 256;
    const unsigned short* w1h = wbres + (size_t)(r * 2) * 589824;
    const unsigned short* w1l = w1h + 4718592;
    const unsigned short* w2h = wbres + (size_t)(r * 2 + 1) * 589824;
    const unsigned short* w2l = w2h + 4718592;
    conv3x3s1_mfma<<<dim3(128, 2, 4), blk, 0, stream>>>(Cc, w1h, w1l, rb1p, D);
    reduce_nc_kernel<float><<<1024, blk, 0, stream>>>(D, stats, 16384);
    inorm_coef_kernel<<<4, 256, 0, stream>>>(stats, 1024, 1.f / 16384.f);
    scale_shift_kernel<float><<<65536, blk, 0, stream>>>(D, stats, 16384,
                                                         (size_t)16777216, 1);
    conv3x3s1_mfma<<<dim3(128, 2, 4), blk, 0, stream>>>(D, w2h, w2l, rb2p, E);
    reduce_nc_kernel<float><<<1024, blk, 0, stream>>>(E, stats, 16384);
    inorm_coef_kernel<<<4, 256, 0, stream>>>(stats, 1024, 1.f / 16384.f);
    scale_shift_kernel<float><<<65536, blk, 0, stream>>>(E, stats, 16384,
                                                         (size_t)16777216, 0);
    add_relu_kernel<<<65536, blk, 0, stream>>>(Cc, E, (size_t)16777216);
  }
  // ---- attention: 1x1 convs f/g/h + windowed attention ----
  conv1x1_tile<<<dim3(16, 8, 4), blk, 0, stream>>>(Cc, w_f, b_f, F1, 256,
                                                   16384);
  conv1x1_tile<<<dim3(16, 8, 4), blk, 0, stream>>>(Cc, w_g, b_g, F2, 256,
                                                   16384);
  conv1x1_tile<<<dim3(16, 64, 4), blk, 0, stream>>>(Cc, w_h, b_h, E, 256,
                                                    16384);
  win_attn_kernel<<<dim3(32, 32, 4), blk, 0, stream>>>(F1, F2, E, out_attn);
  // ---- d1: convT 256->128, AdaLIN, relu (bf16 out) ----
  convt3x3_tile<float, bf16><<<dim3(64, 16, 4), blk, 0, stream>>>(
      Cc, w_d1, b_d1, Bb2, 256, 128, 128);
  reduce_nc_kernel<bf16><<<512, blk, 0, stream>>>(Bb2, stats, 65536);
  adalin_coef_kernel<<<2, 256, 0, stream>>>(stats, rho4, gam4, bet4, 4, 128,
                                            1.f / 65536.f);
  scale_shift_kernel<bf16><<<131072, blk, 0, stream>>>(Bb2, stats, 65536,
                                                       (size_t)33554432, 1);
  // ---- d2: convT 128->64, AdaLIN, relu (bf16) ----
  convt3x3_tile<bf16, bf16><<<dim3(256, 8, 4), blk, 0, stream>>>(
      Bb2, w_d2, b_d2, A2, 128, 256, 256);
  reduce_nc_kernel<bf16><<<256, blk, 0, stream>>>(A2, stats, 262144);
  adalin_coef_kernel<<<1, 256, 0, stream>>>(stats, rho5, gam5, bet5, 4, 64,
                                            1.f / 262144.f);
  scale_shift_kernel<bf16><<<262144, blk, 0, stream>>>(A2, stats, 262144,
                                                       (size_t)67108864, 1);
  // ---- head: 7x7 conv (LDS-tiled, width-split blocks) + tanh -> fp32 img ----
  conv7_head<<<dim3(128, 2, 4), blk, 0, stream>>>(A2, w_d3, b_d3, out_img);
}

// Round 10
// 7728.519 us; speedup vs baseline: 1.3732x; 1.3047x over previous
//
#include <hip/hip_runtime.h>
#include <hip/hip_bf16.h>
#include <hip/hip_fp16.h>

#define EPSN 1e-5f

typedef __hip_bfloat16 bf16;
typedef __half f16;
typedef __attribute__((ext_vector_type(8))) short bf16x8;
typedef __attribute__((ext_vector_type(4))) float f32x4;

__device__ __forceinline__ float b2f(bf16 v) { return __bfloat162float(v); }
__device__ __forceinline__ bf16 f2b(float v) { return __float2bfloat16(v); }
__device__ __forceinline__ unsigned short f2bu(float v) {
  bf16 h = __float2bfloat16(v);
  return *reinterpret_cast<unsigned short*>(&h);
}
__device__ __forceinline__ float bu2f(unsigned short u) {
  unsigned int b = ((unsigned int)u) << 16;
  return __uint_as_float(b);
}
__device__ __forceinline__ unsigned short f2hu(float v) {
  f16 h = __float2half(v);
  return *reinterpret_cast<unsigned short*>(&h);
}
__device__ __forceinline__ float hu2f(unsigned short u) {
  f16 h = *reinterpret_cast<f16*>(&u);
  return __half2float(h);
}
__device__ __forceinline__ void stv(bf16* p, size_t i, float v) { p[i] = f2b(v); }
__device__ __forceinline__ void stv(float* p, size_t i, float v) { p[i] = v; }
__device__ __forceinline__ void stv(f16* p, size_t i, float v) {
  p[i] = __float2half(v);
}

// vec4 load/store helpers (fp32/bf16/fp16 storage, fp32 compute)
__device__ __forceinline__ float4 ld4(const float* p) { return *(const float4*)p; }
__device__ __forceinline__ float4 ld4(const bf16* p) {
  ushort4 u = *(const ushort4*)p;
  float4 r;
  r.x = bu2f(u.x);
  r.y = bu2f(u.y);
  r.z = bu2f(u.z);
  r.w = bu2f(u.w);
  return r;
}
__device__ __forceinline__ float4 ld4(const f16* p) {
  ushort4 u = *(const ushort4*)p;
  float4 r;
  r.x = hu2f(u.x);
  r.y = hu2f(u.y);
  r.z = hu2f(u.z);
  r.w = hu2f(u.w);
  return r;
}
__device__ __forceinline__ void st4(float* p, float4 v) { *(float4*)p = v; }
__device__ __forceinline__ void st4(bf16* p, float4 v) {
  uint2 o;
  o.x = (unsigned)f2bu(v.x) | ((unsigned)f2bu(v.y) << 16);
  o.y = (unsigned)f2bu(v.z) | ((unsigned)f2bu(v.w) << 16);
  *(uint2*)p = o;
}
__device__ __forceinline__ void st4(f16* p, float4 v) {
  ushort4 o = {f2hu(v.x), f2hu(v.y), f2hu(v.z), f2hu(v.w)};
  *(ushort4*)p = o;
}

// ---------------- zero the stats scratch (atomicAdd target) -----------------
__global__ void zero_stats_kernel(float* __restrict__ stats) {
  for (int k = threadIdx.x; k < 2048; k += 256) stats[k] = 0.f;
}

// ------- weight convert: [Co][Ci][3][3] fp32 -> [tap][co][ci] bf16 hi+lo ----
__global__ __launch_bounds__(256) void convert_w_kernel(
    const float* __restrict__ rw1, const float* __restrict__ rw2,
    unsigned short* __restrict__ wb) {
  int i = blockIdx.x * 256 + threadIdx.x;  // < 8*9*65536 = 4718592
  if (i >= 4718592) return;
  int conv = i / 589824;
  int rem = i % 589824;
  int tap = rem / 65536;
  int cc = rem % 65536;  // co*256+ci
  const float* src = ((conv & 1) ? rw2 : rw1) + (size_t)(conv >> 1) * 589824;
  float v = src[(size_t)cc * 9 + tap];
  bf16 h = __float2bfloat16(v);
  float fh = __bfloat162float(h);
  wb[i] = *reinterpret_cast<unsigned short*>(&h);
  bf16 l = __float2bfloat16(v - fh);
  wb[4718592 + i] = *reinterpret_cast<unsigned short*>(&l);
}

// ---------------- 3x3 s1 p1 conv via MFMA (bf16x3), Ci=Co=256, H=W=128 ------
__device__ __forceinline__ int swz3(int idx) {
  return (idx & 3) ^ ((idx >> 2) & 1);
}

__global__ __launch_bounds__(256) void conv3x3s1_mfma(
    const float* __restrict__ x, const unsigned short* __restrict__ wh,
    const unsigned short* __restrict__ wl, const float* __restrict__ bias,
    float* __restrict__ y) {
  const int H = 128, W = 128;
  int r = blockIdx.x;    // output row
  int cog = blockIdx.y;  // 0..1 (128 co each)
  int n = blockIdx.z;
  int tid = threadIdx.x;
  int wv = tid >> 6, lane = tid & 63;
  int wco = (wv >> 1) * 64, wpx = (wv & 1) * 64;
  int l15 = lane & 15, l4 = lane >> 4;

  __shared__ __align__(16) unsigned short Xh[3 * 130 * 32];
  __shared__ __align__(16) unsigned short Xl[3 * 130 * 32];
  __shared__ __align__(16) unsigned short Ah[128 * 32];
  __shared__ __align__(16) unsigned short Al[128 * 32];

  f32x4 acc[4][4];
#pragma unroll
  for (int m = 0; m < 4; ++m)
#pragma unroll
    for (int nf = 0; nf < 4; ++nf) acc[m][nf] = (f32x4){0.f, 0.f, 0.f, 0.f};

  const float* xn0 = x + (size_t)n * 256 * H * W;

  for (int cb = 0; cb < 8; ++cb) {
    int ci0 = cb * 32;
    {
      const float* xn = xn0 + (size_t)ci0 * H * W;
      for (int t = tid; t < 1560; t += 256) {
        int q = t & 3;
        int cr = t >> 2;     // 0..389
        int col = cr % 130;  // 0..129
        int row = cr / 130;  // 0..2
        int gr = r + row - 1;
        int gc = col - 1;
        bool ok = (gr >= 0) && (gr < H) && (gc >= 0) && (gc < W);
        uint4 ph = {0, 0, 0, 0};
        uint4 pl = {0, 0, 0, 0};
        if (ok) {
          const float* xp =
              xn + (size_t)(q * 8) * (H * W) + (size_t)gr * W + gc;
          unsigned short vh[8], vl[8];
#pragma unroll
          for (int e = 0; e < 8; ++e) {
            float v = xp[(size_t)e * H * W];
            bf16 hb = __float2bfloat16(v);
            float fh = __bfloat162float(hb);
            bf16 lb = __float2bfloat16(v - fh);
            vh[e] = *reinterpret_cast<unsigned short*>(&hb);
            vl[e] = *reinterpret_cast<unsigned short*>(&lb);
          }
          ph.x = (unsigned)vh[0] | ((unsigned)vh[1] << 16);
          ph.y = (unsigned)vh[2] | ((unsigned)vh[3] << 16);
          ph.z = (unsigned)vh[4] | ((unsigned)vh[5] << 16);
          ph.w = (unsigned)vh[6] | ((unsigned)vh[7] << 16);
          pl.x = (unsigned)vl[0] | ((unsigned)vl[1] << 16);
          pl.y = (unsigned)vl[2] | ((unsigned)vl[3] << 16);
          pl.z = (unsigned)vl[4] | ((unsigned)vl[5] << 16);
          pl.w = (unsigned)vl[6] | ((unsigned)vl[7] << 16);
        }
        int slot = (cr * 4 + (q ^ swz3(col))) * 8;
        *(uint4*)(&Xh[slot]) = ph;
        *(uint4*)(&Xl[slot]) = pl;
      }
    }
    for (int tap = 0; tap < 9; ++tap) {
      for (int t = tid; t < 1024; t += 256) {
        int half = t >> 9;
        int rem = t & 511;
        int q = rem & 3;
        int co = rem >> 2;
        const unsigned short* wsrc =
            (half ? wl : wh) +
            ((size_t)tap * 256 + cog * 128 + co) * 256 + ci0 + q * 8;
        uint4 pk = *(const uint4*)wsrc;
        int slot = (co * 4 + (q ^ swz3(co))) * 8;
        *(uint4*)((half ? Al : Ah) + slot) = pk;
      }
      __syncthreads();
      int ky = tap / 3;
      int kx = tap - ky * 3;
      bf16x8 ahf[4], alf[4], bhf[4], blf[4];
#pragma unroll
      for (int m = 0; m < 4; ++m) {
        int co = wco + m * 16 + l15;
        int slot = (co * 4 + (l4 ^ swz3(co))) * 8;
        ahf[m] = *(const bf16x8*)(&Ah[slot]);
        alf[m] = *(const bf16x8*)(&Al[slot]);
      }
#pragma unroll
      for (int nf = 0; nf < 4; ++nf) {
        int col = wpx + nf * 16 + l15 + kx;  // lds col = px + kx
        int slot = ((ky * 130 + col) * 4 + (l4 ^ swz3(col))) * 8;
        bhf[nf] = *(const bf16x8*)(&Xh[slot]);
        blf[nf] = *(const bf16x8*)(&Xl[slot]);
      }
#pragma unroll
      for (int m = 0; m < 4; ++m)
#pragma unroll
        for (int nf = 0; nf < 4; ++nf) {
          acc[m][nf] = __builtin_amdgcn_mfma_f32_16x16x32_bf16(
              ahf[m], bhf[nf], acc[m][nf], 0, 0, 0);
          acc[m][nf] = __builtin_amdgcn_mfma_f32_16x16x32_bf16(
              ahf[m], blf[nf], acc[m][nf], 0, 0, 0);
          acc[m][nf] = __builtin_amdgcn_mfma_f32_16x16x32_bf16(
              alf[m], bhf[nf], acc[m][nf], 0, 0, 0);
        }
      __syncthreads();
    }
  }
#pragma unroll
  for (int m = 0; m < 4; ++m) {
    int cob = cog * 128 + wco + m * 16 + l4 * 4;
#pragma unroll
    for (int reg = 0; reg < 4; ++reg) {
      float bv = bias[cob + reg];
      float* yr =
          y + (((size_t)(n * 256 + cob + reg) * H) + r) * W + wpx + l15;
#pragma unroll
      for (int nf = 0; nf < 4; ++nf) yr[nf * 16] = acc[m][nf][reg] + bv;
    }
  }
}

// ---------------- e1: 7x7 conv p3, CI=3, LDS-tiled (1 ci slice at a time) ---
// 8co x 8px(interleaved), raw f16 out + stats. Block: 4 rows x 512 cols.
// grid (128, 8, 4). LDS: 20.8K (Xs) + 4.7K (wsh) + 0.25K = 25.8 KB.
__global__ __launch_bounds__(256) void conv7_e1(
    const float* __restrict__ x, const float* __restrict__ w,
    const float* __restrict__ bias, float* __restrict__ stats,
    f16* __restrict__ y) {
  const int H = 512, W = 512;
  __shared__ float Xs[5200];         // [10][520] one ci, zero-padded halo
  __shared__ float wsh[8 * 3 * 49];  // 8 co slab
  __shared__ float sred[4][8], qred[4][8];
  int cog = blockIdx.y;  // 8 groups x 8 co
  int n = blockIdx.z;
  int tid = threadIdx.x;
  int r0 = blockIdx.x * 4;
  int tr = tid >> 6;
  int lane = tid & 63;
  for (int t = tid; t < 1176; t += 256) wsh[t] = w[cog * 1176 + t];
  const float* xb = x + (size_t)n * 3 * H * W;
  float acc[8][8];
#pragma unroll
  for (int j = 0; j < 8; ++j) {
#pragma unroll
    for (int p = 0; p < 8; ++p) acc[j][p] = 0.f;
  }
  for (int ci = 0; ci < 3; ++ci) {
    __syncthreads();  // protect Xs from prev readers; orders wsh on 1st iter
    for (int t = tid; t < 5200; t += 256) {
      int row = t / 520;
      int col = t - row * 520;
      int gr = r0 - 3 + row;
      int gc = col - 3;
      float v = 0.f;
      if (gr >= 0 && gr < H && gc >= 0 && gc < W)
        v = xb[((size_t)ci * H + gr) * W + gc];
      Xs[t] = v;
    }
    __syncthreads();
    for (int i = 0; i < 7; ++i) {
      const float* xr = &Xs[(tr + i) * 520 + lane];
      float v[8][7];
#pragma unroll
      for (int p = 0; p < 8; ++p)
#pragma unroll
        for (int k = 0; k < 7; ++k) v[p][k] = xr[p * 64 + k];
#pragma unroll
      for (int j = 0; j < 8; ++j) {
        const float* wr = &wsh[(j * 3 + ci) * 49 + i * 7];
        float w0 = wr[0], w1 = wr[1], w2 = wr[2], w3 = wr[3], w4 = wr[4],
              w5 = wr[5], w6 = wr[6];
#pragma unroll
        for (int p = 0; p < 8; ++p)
          acc[j][p] += v[p][0] * w0 + v[p][1] * w1 + v[p][2] * w2 +
                       v[p][3] * w3 + v[p][4] * w4 + v[p][5] * w5 +
                       v[p][6] * w6;
      }
    }
  }
  int r = r0 + tr;
#pragma unroll
  for (int j = 0; j < 8; ++j) {
    int co = cog * 8 + j;
    float bv = bias[co];
    f16* yr = y + ((size_t)(n * 64 + co) * H + r) * W + lane;
    float s = 0.f, q = 0.f;
#pragma unroll
    for (int p = 0; p < 8; ++p) {
      float o = acc[j][p] + bv;
      yr[p * 64] = __float2half(o);
      s += o;
      q += o * o;
    }
#pragma unroll
    for (int off = 32; off > 0; off >>= 1) {
      s += __shfl_down(s, off, 64);
      q += __shfl_down(q, off, 64);
    }
    if (lane == 0) {
      sred[tr][j] = s;
      qred[tr][j] = q;
    }
  }
  __syncthreads();
  if (tid < 8) {
    float S = sred[0][tid] + sred[1][tid] + sred[2][tid] + sred[3][tid];
    float Q = qred[0][tid] + qred[1][tid] + qred[2][tid] + qred[3][tid];
    atomicAdd(&stats[n * 64 + cog * 8 + tid], S);
    atomicAdd(&stats[1024 + n * 64 + cog * 8 + tid], Q);
  }
}

// ---------------- head: 7x7 conv via MFMA bf16, Ci=64, Co=3 (M padded 16) ---
// Block: 4 waves = 4 output rows x 256 cols; grid (128, 2, 4).
// K = 64ci*49taps, as 8 ci-chunks x 7 ky x 2 kf (kx0-3 / kx4-7, kx7 zero-wgt).
// Xs NHWC [10 row][264 col][8 ci] bf16 (42.2KB) + wlds [7ky][16co][64k]
// (14.3KB, k = kx*8+ci) = 56.5KB -> 2 blocks/CU. Fragment mapping identical to
// conv3x3s1_mfma (A lane l15=co row, B lane l15=px col, D row=l4*4+reg).
__global__ __launch_bounds__(256) void conv7_head_mfma(
    const bf16* __restrict__ xin, const float* __restrict__ w,
    const float* __restrict__ bias, float* __restrict__ y) {
  const int H = 512, W = 512;
  __shared__ __align__(16) unsigned short Xs[10 * 264 * 8];
  __shared__ __align__(16) unsigned short wlds[7 * 16 * 64];
  int n = blockIdx.z;
  int cbase = blockIdx.y * 256;
  int r0 = blockIdx.x * 4;
  int tid = threadIdx.x;
  int wv = tid >> 6;  // wave = output row
  int lane = tid & 63;
  int l15 = lane & 15, l4 = lane >> 4;
  const unsigned short* xb =
      (const unsigned short*)xin + (size_t)n * 64 * H * W;
  f32x4 acc[16];
#pragma unroll
  for (int nf = 0; nf < 16; ++nf) acc[nf] = (f32x4){0.f, 0.f, 0.f, 0.f};
  for (int ch = 0; ch < 8; ++ch) {
    __syncthreads();  // protect Xs/wlds from previous chunk's readers
    // stage input: 10 rows x 264 cols x 8 ci (bit-copy, zero-padded)
    for (int t = tid; t < 2640; t += 256) {
      int row = t / 264;
      int col = t - row * 264;
      int gr = r0 - 3 + row;
      int gc = cbase - 3 + col;
      uint4 pk = {0, 0, 0, 0};
      if (gr >= 0 && gr < H && gc >= 0 && gc < W) {
        const unsigned short* xp =
            xb + ((size_t)(ch * 8) * H + gr) * W + gc;
        unsigned short v[8];
#pragma unroll
        for (int e = 0; e < 8; ++e) v[e] = xp[(size_t)e * H * W];
        pk.x = (unsigned)v[0] | ((unsigned)v[1] << 16);
        pk.y = (unsigned)v[2] | ((unsigned)v[3] << 16);
        pk.z = (unsigned)v[4] | ((unsigned)v[5] << 16);
        pk.w = (unsigned)v[6] | ((unsigned)v[7] << 16);
      }
      *(uint4*)(&Xs[t * 8]) = pk;
    }
    // stage weights: wlds[ky][co16][k64], k = kx*8 + cie; co>=3 or kx==7 -> 0
    for (int t = tid; t < 7168; t += 256) {
      int k64 = t & 63;
      int co = (t >> 6) & 15;
      int ky = t >> 10;
      int kx = k64 >> 3;
      int cie = k64 & 7;
      unsigned short val = 0;
      if (co < 3 && kx < 7)
        val = f2bu(w[((size_t)(co * 64 + ch * 8 + cie) * 7 + ky) * 7 + kx]);
      wlds[t] = val;
    }
    __syncthreads();
#pragma unroll 1
    for (int ky = 0; ky < 7; ++ky) {
      bf16x8 af0 = *(const bf16x8*)(&wlds[(ky * 16 + l15) * 64 + l4 * 8]);
      bf16x8 af1 =
          *(const bf16x8*)(&wlds[(ky * 16 + l15) * 64 + 32 + l4 * 8]);
      int xrow = wv + ky;
#pragma unroll
      for (int nf = 0; nf < 16; ++nf) {
        int col0 = nf * 16 + l15 + l4;  // kf=0: kx = l4
        bf16x8 b0 = *(const bf16x8*)(&Xs[(xrow * 264 + col0) * 8]);
        acc[nf] =
            __builtin_amdgcn_mfma_f32_16x16x32_bf16(af0, b0, acc[nf], 0, 0, 0);
        bf16x8 b1 = *(const bf16x8*)(&Xs[(xrow * 264 + col0 + 4) * 8]);
        acc[nf] =
            __builtin_amdgcn_mfma_f32_16x16x32_bf16(af1, b1, acc[nf], 0, 0, 0);
      }
    }
  }
  // epilogue: D rows 0-2 (l4==0, reg 0-2) are co 0-2; + bias, tanh, store
  if (l4 == 0) {
    int r = r0 + wv;
#pragma unroll
    for (int nf = 0; nf < 16; ++nf) {
#pragma unroll
      for (int reg = 0; reg < 3; ++reg) {
        float o = tanhf(acc[nf][reg] + bias[reg]);
        y[((size_t)(n * 3 + reg) * H + r) * W + cbase + nf * 16 + l15] = o;
      }
    }
  }
}

// ---------------- 3x3 s2 p1 conv, tiled 4 px x 8 co ------------------------
// NORM: input v = relu(x*sc[n,ci] + sh[n,ci]) fused from stats (AdaLIN coefs)
template <typename Tin, typename Tout, bool NORM>
__global__ __launch_bounds__(256) void conv3x3s2_tile(
    const Tin* __restrict__ x, const float* __restrict__ w,
    const float* __restrict__ bias, const float* __restrict__ stats,
    Tout* __restrict__ y, int Ci, int Hi, int Wi) {
  int Ho = Hi >> 1, Wo = Wi >> 1;
  int cog = blockIdx.y;
  int Co = gridDim.y * 8;
  int n = blockIdx.z;
  int CG = Wo >> 2;
  int rpb = 256 / CG;
  int tid = threadIdx.x;
  int r = blockIdx.x * rpb + tid / CG;
  int c0 = (tid % CG) * 4;
  const Tin* xb = x + (size_t)n * Ci * Hi * Wi;
  int ir0 = 2 * r - 1;
  float mr0 = (ir0 >= 0) ? 1.f : 0.f;
  int cr0 = max(ir0, 0);
  int icl = 2 * c0 - 1;
  float mcl = (icl >= 0) ? 1.f : 0.f;
  int ccl = max(icl, 0);
  float acc[8][4];
#pragma unroll
  for (int j = 0; j < 8; ++j) {
    float b = bias[cog * 8 + j];
#pragma unroll
    for (int p = 0; p < 4; ++p) acc[j][p] = b;
  }
  for (int ci = 0; ci < Ci; ++ci) {
    const Tin* xc = xb + (size_t)ci * Hi * Wi;
    float sc = 1.f, sh = 0.f;
    if (NORM) {
      sc = stats[2048 + n * Ci + ci];
      sh = stats[3072 + n * Ci + ci];
    }
    float v[3][9];
#pragma unroll
    for (int i = 0; i < 3; ++i) {
      int rr = (i == 0) ? cr0 : (2 * r - 1 + i);
      float mi = (i == 0) ? mr0 : 1.f;
      const Tin* xr = xc + (size_t)rr * Wi;
      float t[9];
      t[0] = (float)xr[ccl];
      float4 a = ld4(xr + 2 * c0);
      float4 b4 = ld4(xr + 2 * c0 + 4);
      t[1] = a.x;
      t[2] = a.y;
      t[3] = a.z;
      t[4] = a.w;
      t[5] = b4.x;
      t[6] = b4.y;
      t[7] = b4.z;
      t[8] = b4.w;
      if (NORM) {
#pragma unroll
        for (int k = 0; k < 9; ++k) t[k] = fmaxf(fmaf(t[k], sc, sh), 0.f);
      }
      v[i][0] = t[0] * (mcl * mi);
#pragma unroll
      for (int k = 1; k < 9; ++k) v[i][k] = t[k] * mi;
    }
#pragma unroll
    for (int j = 0; j < 8; ++j) {
      const float* wc = w + ((size_t)(cog * 8 + j) * Ci + ci) * 9;
#pragma unroll
      for (int p = 0; p < 4; ++p) {
        acc[j][p] += v[0][2 * p] * wc[0] + v[0][2 * p + 1] * wc[1] +
                     v[0][2 * p + 2] * wc[2] + v[1][2 * p] * wc[3] +
                     v[1][2 * p + 1] * wc[4] + v[1][2 * p + 2] * wc[5] +
                     v[2][2 * p] * wc[6] + v[2][2 * p + 1] * wc[7] +
                     v[2][2 * p + 2] * wc[8];
      }
    }
  }
#pragma unroll
  for (int j = 0; j < 8; ++j) {
    float4 o = {acc[j][0], acc[j][1], acc[j][2], acc[j][3]};
    st4(y + ((size_t)(n * Co + cog * 8 + j) * Ho + r) * Wo + c0, o);
  }
}

// ---------------- 1x1 conv, tiled 4 px x 4 co, fp32 -------------------------
__global__ __launch_bounds__(256) void conv1x1_tile(
    const float* __restrict__ x, const float* __restrict__ w,
    const float* __restrict__ bias, float* __restrict__ y, int Ci, int HW) {
  int cog = blockIdx.y;
  int Co = gridDim.y * 4;
  int n = blockIdx.z;
  int p0 = (blockIdx.x * 256 + threadIdx.x) * 4;
  const float* xb = x + (size_t)n * Ci * HW + p0;
  float acc[4][4];
#pragma unroll
  for (int j = 0; j < 4; ++j) {
    float b = bias[cog * 4 + j];
#pragma unroll
    for (int p = 0; p < 4; ++p) acc[j][p] = b;
  }
  for (int ci = 0; ci < Ci; ++ci) {
    float4 xv = *(const float4*)(xb + (size_t)ci * HW);
#pragma unroll
    for (int j = 0; j < 4; ++j) {
      float wv = w[(size_t)(cog * 4 + j) * Ci + ci];
      acc[j][0] += xv.x * wv;
      acc[j][1] += xv.y * wv;
      acc[j][2] += xv.z * wv;
      acc[j][3] += xv.w * wv;
    }
  }
#pragma unroll
  for (int j = 0; j < 4; ++j) {
    float4 o = {acc[j][0], acc[j][1], acc[j][2], acc[j][3]};
    *(float4*)(y + (size_t)(n * Co + cog * 4 + j) * HW + p0) = o;
  }
}

// ---------------- ConvTranspose2d k3 s2 p1 op1, tiled 2x2 quad x 8 co -------
template <typename Tin, typename Tout>
__global__ __launch_bounds__(256) void convt3x3_tile(
    const Tin* __restrict__ x, const float* __restrict__ w,
    const float* __restrict__ bias, Tout* __restrict__ y, int Ci, int Hi,
    int Wi) {
  int Ho = Hi * 2, Wo = Wi * 2;
  int cog = blockIdx.y;
  int Co = gridDim.y * 8;
  int n = blockIdx.z;
  int q = blockIdx.x * 256 + threadIdx.x;
  int yq = q / Wi, xq = q % Wi;
  const Tin* xb = x + (size_t)n * Ci * Hi * Wi;
  float mx = (xq + 1 < Wi) ? 1.f : 0.f;
  int x1 = min(xq + 1, Wi - 1);
  float my = (yq + 1 < Hi) ? 1.f : 0.f;
  int y1 = min(yq + 1, Hi - 1);
  float mxy = mx * my;
  float acc[8][4];
#pragma unroll
  for (int j = 0; j < 8; ++j) {
    float b = bias[cog * 8 + j];
#pragma unroll
    for (int p = 0; p < 4; ++p) acc[j][p] = b;
  }
  for (int ci = 0; ci < Ci; ++ci) {
    const Tin* xc = xb + (size_t)ci * Hi * Wi;
    float a = (float)xc[(size_t)yq * Wi + xq];
    float bv = (float)xc[(size_t)yq * Wi + x1] * mx;
    float c = (float)xc[(size_t)y1 * Wi + xq] * my;
    float d = (float)xc[(size_t)y1 * Wi + x1] * mxy;
#pragma unroll
    for (int j = 0; j < 8; ++j) {
      const float* wc = w + ((size_t)ci * Co + cog * 8 + j) * 9;
      acc[j][0] += a * wc[4];
      acc[j][1] += bv * wc[3] + a * wc[5];
      acc[j][2] += c * wc[1] + a * wc[7];
      acc[j][3] += d * wc[0] + c * wc[2] + bv * wc[6] + a * wc[8];
    }
  }
#pragma unroll
  for (int j = 0; j < 8; ++j) {
    size_t base = ((size_t)(n * Co + cog * 8 + j) * Ho + 2 * yq) * Wo + 2 * xq;
    stv(y, base, acc[j][0]);
    stv(y, base + 1, acc[j][1]);
    stv(y, base + Wo, acc[j][2]);
    stv(y, base + Wo + 1, acc[j][3]);
  }
}

// ---------------- per-(n,c) sum / sumsq reduction ---------------------------
template <typename Tin>
__global__ __launch_bounds__(256) void reduce_nc_kernel(
    const Tin* __restrict__ x, float* __restrict__ stats, int HW) {
  int b = blockIdx.x;
  const Tin* p = x + (size_t)b * HW;
  float s = 0.f, q = 0.f;
  for (int i = threadIdx.x; i < HW; i += 256) {
    float v = (float)p[i];
    s += v;
    q += v * v;
  }
  __shared__ float ss[256], qq[256];
  ss[threadIdx.x] = s;
  qq[threadIdx.x] = q;
  __syncthreads();
  for (int off = 128; off > 0; off >>= 1) {
    if (threadIdx.x < off) {
      ss[threadIdx.x] += ss[threadIdx.x + off];
      qq[threadIdx.x] += qq[threadIdx.x + off];
    }
    __syncthreads();
  }
  if (threadIdx.x == 0) {
    stats[b] = ss[0];
    stats[1024 + b] = qq[0];
  }
}

// ---------------- AdaLIN coefficients ---------------------------------------
__global__ void adalin_coef_kernel(float* __restrict__ stats,
                                   const float* __restrict__ rho,
                                   const float* __restrict__ gam,
                                   const float* __restrict__ bet, int N, int C,
                                   float invHW) {
  int i = blockIdx.x * blockDim.x + threadIdx.x;
  if (i >= N * C) return;
  int c = i % C;
  const float* sums = stats;
  const float* sqs = stats + 1024;
  float im = sums[i] * invHW;
  float iv = sqs[i] * invHW - im * im;
  float lsum = 0.f, lsq = 0.f;
  for (int n = 0; n < N; ++n) {
    lsum += sums[n * C + c];
    lsq += sqs[n * C + c];
  }
  float lm = lsum * invHW / N;
  float lv = lsq * invHW / N - lm * lm;
  float r = rho[c];
  float mean = r * im + (1.f - r) * lm;
  float var = fmaxf(r * iv + (1.f - r) * lv, 0.f);
  float sc = gam[c] / sqrtf(var + EPSN);
  stats[2048 + i] = sc;
  stats[3072 + i] = bet[c] - mean * sc;
}

// ---------------- InstanceNorm coefficients ---------------------------------
__global__ void inorm_coef_kernel(float* __restrict__ stats, int NC,
                                  float invHW) {
  int i = blockIdx.x * blockDim.x + threadIdx.x;
  if (i >= NC) return;
  float im = stats[i] * invHW;
  float iv = fmaxf(stats[1024 + i] * invHW - im * im, 0.f);
  float sc = 1.f / sqrtf(iv + EPSN);
  stats[2048 + i] = sc;
  stats[3072 + i] = -im * sc;
}

// ---------------- x = (relu?)(x*scale[nc] + shift[nc])  (in-place) ----------
template <typename T>
__global__ __launch_bounds__(256) void scale_shift_kernel(
    T* __restrict__ x, const float* __restrict__ stats, int HW, size_t total,
    int relu) {
  size_t i = (size_t)blockIdx.x * 256 + threadIdx.x;
  if (i >= total) return;
  int nc = (int)(i / (size_t)HW);
  float v = (float)x[i] * stats[2048 + nc] + stats[3072 + nc];
  if (relu) v = fmaxf(v, 0.f);
  stv(x, i, v);
}

// ---------------- dst = relu(dst + a)  (fp32) -------------------------------
__global__ __launch_bounds__(256) void add_relu_kernel(
    float* __restrict__ dst, const float* __restrict__ a, size_t total) {
  size_t i = (size_t)blockIdx.x * 256 + threadIdx.x;
  if (i >= total) return;
  dst[i] = fmaxf(dst[i] + a[i], 0.f);
}

// ---------------- windowed attention (all fp32) -----------------------------
__global__ __launch_bounds__(256) void win_attn_kernel(
    const float* __restrict__ f, const float* __restrict__ g,
    const float* __restrict__ h, float* __restrict__ out) {
  const int H = 128;
  int j = blockIdx.x;
  int i = blockIdx.y;
  int b = blockIdx.z;
  __shared__ float fs[32 * 64];
  __shared__ float gs[32 * 64];
  __shared__ float att[16 * 64];
  int t = threadIdx.x;
  for (int idx = t; idx < 32 * 64; idx += 256) {
    int c = idx >> 6, k = idx & 63;
    int hr = i * 4 + (k >> 3), wc = j * 4 + (k & 7);
    float fv = 0.f, gv = 0.f;
    if (hr < H && wc < H) {
      size_t o = ((size_t)(b * 32 + c) * H + hr) * H + wc;
      fv = f[o];
      gv = g[o];
    }
    fs[idx] = fv;
    gs[idx] = gv;
  }
  __syncthreads();
  for (int idx = t; idx < 1024; idx += 256) {
    int q = idx >> 6, k = idx & 63;
    int qi = (q >> 2) * 8 + (q & 3);
    int hr = i * 4 + (k >> 3), wc = j * 4 + (k & 7);
    float s;
    if (hr < H && wc < H) {
      s = 0.f;
      for (int c = 0; c < 32; ++c) s += fs[c * 64 + qi] * gs[c * 64 + k];
    } else {
      s = -1e30f;
    }
    att[idx] = s;
  }
  __syncthreads();
  if (t < 16) {
    float m = -1e30f;
    for (int k = 0; k < 64; ++k) m = fmaxf(m, att[t * 64 + k]);
    float d = 0.f;
    for (int k = 0; k < 64; ++k) {
      float e = expf(att[t * 64 + k] - m);
      att[t * 64 + k] = e;
      d += e;
    }
    float inv = 1.f / d;
    for (int k = 0; k < 64; ++k) att[t * 64 + k] *= inv;
  }
  __syncthreads();
  int c = t;
  float accs[16];
  for (int q = 0; q < 16; ++q) accs[q] = 0.f;
  const float* hb = h + (size_t)(b * 256 + c) * H * H;
  for (int k = 0; k < 64; ++k) {
    int hr = i * 4 + (k >> 3), wc = j * 4 + (k & 7);
    if (hr >= H || wc >= H) continue;
    float hv = hb[hr * H + wc];
    for (int q = 0; q < 16; ++q) accs[q] += hv * att[q * 64 + k];
  }
  for (int q = 0; q < 16; ++q) {
    int oh = i * 4 + (q >> 2), ow = j * 4 + (q & 3);
    out[((size_t)(b * 256 + c) * H + oh) * H + ow] = accs[q];
  }
}

// ============================================================================
extern "C" void kernel_launch(void* const* d_in, const int* in_sizes, int n_in,
                              void* d_out, int out_size, void* d_ws,
                              size_t ws_size, hipStream_t stream) {
  const float* x = (const float*)d_in[0];
  const float* w_e1 = (const float*)d_in[1];
  const float* b_e1 = (const float*)d_in[2];
  const float* rho1 = (const float*)d_in[3];
  const float* gam1 = (const float*)d_in[4];
  const float* bet1 = (const float*)d_in[5];
  const float* w_e2 = (const float*)d_in[6];
  const float* b_e2 = (const float*)d_in[7];
  const float* rho2 = (const float*)d_in[8];
  const float* gam2 = (const float*)d_in[9];
  const float* bet2 = (const float*)d_in[10];
  const float* w_e3 = (const float*)d_in[11];
  const float* b_e3 = (const float*)d_in[12];
  const float* rho3 = (const float*)d_in[13];
  const float* gam3 = (const float*)d_in[14];
  const float* bet3 = (const float*)d_in[15];
  const float* rw1 = (const float*)d_in[16];
  const float* rb1 = (const float*)d_in[17];
  const float* rw2 = (const float*)d_in[18];
  const float* rb2 = (const float*)d_in[19];
  const float* w_f = (const float*)d_in[20];
  const float* b_f = (const float*)d_in[21];
  const float* w_g = (const float*)d_in[22];
  const float* b_g = (const float*)d_in[23];
  const float* w_h = (const float*)d_in[24];
  const float* b_h = (const float*)d_in[25];
  const float* w_d1 = (const float*)d_in[26];
  const float* b_d1 = (const float*)d_in[27];
  const float* rho4 = (const float*)d_in[28];
  const float* gam4 = (const float*)d_in[29];
  const float* bet4 = (const float*)d_in[30];
  const float* w_d2 = (const float*)d_in[31];
  const float* b_d2 = (const float*)d_in[32];
  const float* rho5 = (const float*)d_in[33];
  const float* gam5 = (const float*)d_in[34];
  const float* bet5 = (const float*)d_in[35];
  const float* w_d3 = (const float*)d_in[36];
  const float* b_d3 = (const float*)d_in[37];

  // ws layout (192 MiB):
  // E1H f16 raw e1 [0,128MiB) (dead after e2)
  // B2H f16 raw e2 [128,192) (dead after e3; later Bb2 bf16 d1 out)
  // Cc fp32 [0,64), D fp32 [64,128), E fp32 [128,192) (residual stage)
  // F1/F2 fp32 [64,80) (attention f/g); A2 bf16 [0,128) (d2 out)
  char* wsb = (char*)d_ws;
  f16* E1H = (f16*)wsb;
  float* Cc = (float*)wsb;
  float* D = (float*)(wsb + 67108864);
  float* E = (float*)(wsb + 134217728);
  float* F1 = (float*)(wsb + 67108864);
  float* F2 = (float*)(wsb + 75497472);
  f16* B2H = (f16*)(wsb + 134217728);
  bf16* Bb2 = (bf16*)(wsb + 134217728);
  bf16* A2 = (bf16*)wsb;

  float* out_img = (float*)d_out;
  float* out_attn = out_img + 3145728;
  // 16 KiB stats scratch at head of img region; fully overwritten by head conv
  float* stats = (float*)d_out;
  // bf16 hi+lo residual weights scratch in the (not yet written) out_attn
  // region; fully consumed before win_attn_kernel writes out_attn.
  unsigned short* wbres = (unsigned short*)((char*)d_out + 12582912);

  dim3 blk(256);

  // ---- convert residual weights to bf16 hi+lo [tap][co][ci] (once) ----
  convert_w_kernel<<<18432, blk, 0, stream>>>(rw1, rw2, wbres);

  // ---- e1: 7x7 conv (LDS-tiled) -> raw f16 + stats ----
  zero_stats_kernel<<<1, 256, 0, stream>>>(stats);
  conv7_e1<<<dim3(128, 8, 4), blk, 0, stream>>>(x, w_e1, b_e1, stats, E1H);
  adalin_coef_kernel<<<1, 256, 0, stream>>>(stats, rho1, gam1, bet1, 4, 64,
                                            1.f / 262144.f);
  // ---- e2: 3x3 s2 conv with fused e1-norm+relu -> raw f16 ----
  conv3x3s2_tile<f16, f16, true><<<dim3(64, 16, 4), blk, 0, stream>>>(
      E1H, w_e2, b_e2, stats, B2H, 64, 512, 512);
  reduce_nc_kernel<f16><<<512, blk, 0, stream>>>(B2H, stats, 65536);
  adalin_coef_kernel<<<2, 256, 0, stream>>>(stats, rho2, gam2, bet2, 4, 128,
                                            1.f / 65536.f);
  // ---- e3: 3x3 s2 conv with fused e2-norm+relu -> fp32, then AdaLIN ----
  conv3x3s2_tile<f16, float, true><<<dim3(16, 32, 4), blk, 0, stream>>>(
      B2H, w_e3, b_e3, stats, Cc, 128, 256, 256);
  reduce_nc_kernel<float><<<1024, blk, 0, stream>>>(Cc, stats, 16384);
  adalin_coef_kernel<<<4, 256, 0, stream>>>(stats, rho3, gam3, bet3, 4, 256,
                                            1.f / 16384.f);
  scale_shift_kernel<float><<<65536, blk, 0, stream>>>(Cc, stats, 16384,
                                                       (size_t)16777216, 1);
  // ---- 4 residual blocks (bf16x3 MFMA convs) ----
  for (int r = 0; r < 4; ++r) {
    const float* rb1p = rb1 + (size_t)r * 256;
    const float* rb2p = rb2 + (size_t)r * 256;
    const unsigned short* w1h = wbres + (size_t)(r * 2) * 589824;
    const unsigned short* w1l = w1h + 4718592;
    const unsigned short* w2h = wbres + (size_t)(r * 2 + 1) * 589824;
    const unsigned short* w2l = w2h + 4718592;
    conv3x3s1_mfma<<<dim3(128, 2, 4), blk, 0, stream>>>(Cc, w1h, w1l, rb1p, D);
    reduce_nc_kernel<float><<<1024, blk, 0, stream>>>(D, stats, 16384);
    inorm_coef_kernel<<<4, 256, 0, stream>>>(stats, 1024, 1.f / 16384.f);
    scale_shift_kernel<float><<<65536, blk, 0, stream>>>(D, stats, 16384,
                                                         (size_t)16777216, 1);
    conv3x3s1_mfma<<<dim3(128, 2, 4), blk, 0, stream>>>(D, w2h, w2l, rb2p, E);
    reduce_nc_kernel<float><<<1024, blk, 0, stream>>>(E, stats, 16384);
    inorm_coef_kernel<<<4, 256, 0, stream>>>(stats, 1024, 1.f / 16384.f);
    scale_shift_kernel<float><<<65536, blk, 0, stream>>>(E, stats, 16384,
                                                         (size_t)16777216, 0);
    add_relu_kernel<<<65536, blk, 0, stream>>>(Cc, E, (size_t)16777216);
  }
  // ---- attention: 1x1 convs f/g/h + windowed attention ----
  conv1x1_tile<<<dim3(16, 8, 4), blk, 0, stream>>>(Cc, w_f, b_f, F1, 256,
                                                   16384);
  conv1x1_tile<<<dim3(16, 8, 4), blk, 0, stream>>>(Cc, w_g, b_g, F2, 256,
                                                   16384);
  conv1x1_tile<<<dim3(16, 64, 4), blk, 0, stream>>>(Cc, w_h, b_h, E, 256,
                                                    16384);
  win_attn_kernel<<<dim3(32, 32, 4), blk, 0, stream>>>(F1, F2, E, out_attn);
  // ---- d1: convT 256->128, AdaLIN, relu (bf16 out) ----
  convt3x3_tile<float, bf16><<<dim3(64, 16, 4), blk, 0, stream>>>(
      Cc, w_d1, b_d1, Bb2, 256, 128, 128);
  reduce_nc_kernel<bf16><<<512, blk, 0, stream>>>(Bb2, stats, 65536);
  adalin_coef_kernel<<<2, 256, 0, stream>>>(stats, rho4, gam4, bet4, 4, 128,
                                            1.f / 65536.f);
  scale_shift_kernel<bf16><<<131072, blk, 0, stream>>>(Bb2, stats, 65536,
                                                       (size_t)33554432, 1);
  // ---- d2: convT 128->64, AdaLIN, relu (bf16) ----
  convt3x3_tile<bf16, bf16><<<dim3(256, 8, 4), blk, 0, stream>>>(
      Bb2, w_d2, b_d2, A2, 128, 256, 256);
  reduce_nc_kernel<bf16><<<256, blk, 0, stream>>>(A2, stats, 262144);
  adalin_coef_kernel<<<1, 256, 0, stream>>>(stats, rho5, gam5, bet5, 4, 64,
                                            1.f / 262144.f);
  scale_shift_kernel<bf16><<<262144, blk, 0, stream>>>(A2, stats, 262144,
                                                       (size_t)67108864, 1);
  // ---- head: 7x7 conv via MFMA + tanh -> fp32 img ----
  conv7_head_mfma<<<dim3(128, 2, 4), blk, 0, stream>>>(A2, w_d3, b_d3,
                                                       out_img);
}

// Round 11
// 6715.830 us; speedup vs baseline: 1.5803x; 1.1508x over previous
//
#include <hip/hip_runtime.h>
#include <hip/hip_bf16.h>
#include <hip/hip_fp16.h>

#define EPSN 1e-5f

typedef __hip_bfloat16 bf16;
typedef __half f16;
typedef __attribute__((ext_vector_type(8))) short bf16x8;
typedef __attribute__((ext_vector_type(4))) float f32x4;

__device__ __forceinline__ float b2f(bf16 v) { return __bfloat162float(v); }
__device__ __forceinline__ bf16 f2b(float v) { return __float2bfloat16(v); }
__device__ __forceinline__ unsigned short f2bu(float v) {
  bf16 h = __float2bfloat16(v);
  return *reinterpret_cast<unsigned short*>(&h);
}
__device__ __forceinline__ float bu2f(unsigned short u) {
  unsigned int b = ((unsigned int)u) << 16;
  return __uint_as_float(b);
}
__device__ __forceinline__ unsigned short f2hu(float v) {
  f16 h = __float2half(v);
  return *reinterpret_cast<unsigned short*>(&h);
}
__device__ __forceinline__ float hu2f(unsigned short u) {
  f16 h = *reinterpret_cast<f16*>(&u);
  return __half2float(h);
}
__device__ __forceinline__ void stv(bf16* p, size_t i, float v) { p[i] = f2b(v); }
__device__ __forceinline__ void stv(float* p, size_t i, float v) { p[i] = v; }
__device__ __forceinline__ void stv(f16* p, size_t i, float v) {
  p[i] = __float2half(v);
}

// bf16-bits helper for staging (fp32 -> bf16 bits, or bf16 bit-copy)
__device__ __forceinline__ unsigned short xbits(float v) { return f2bu(v); }
__device__ __forceinline__ unsigned short xbits(bf16 v) {
  return *reinterpret_cast<unsigned short*>(&v);
}

// vec4 load/store helpers (fp32/bf16/fp16 storage, fp32 compute)
__device__ __forceinline__ float4 ld4(const float* p) { return *(const float4*)p; }
__device__ __forceinline__ float4 ld4(const bf16* p) {
  ushort4 u = *(const ushort4*)p;
  float4 r;
  r.x = bu2f(u.x);
  r.y = bu2f(u.y);
  r.z = bu2f(u.z);
  r.w = bu2f(u.w);
  return r;
}
__device__ __forceinline__ float4 ld4(const f16* p) {
  ushort4 u = *(const ushort4*)p;
  float4 r;
  r.x = hu2f(u.x);
  r.y = hu2f(u.y);
  r.z = hu2f(u.z);
  r.w = hu2f(u.w);
  return r;
}
__device__ __forceinline__ void st4(float* p, float4 v) { *(float4*)p = v; }
__device__ __forceinline__ void st4(bf16* p, float4 v) {
  uint2 o;
  o.x = (unsigned)f2bu(v.x) | ((unsigned)f2bu(v.y) << 16);
  o.y = (unsigned)f2bu(v.z) | ((unsigned)f2bu(v.w) << 16);
  *(uint2*)p = o;
}
__device__ __forceinline__ void st4(f16* p, float4 v) {
  ushort4 o = {f2hu(v.x), f2hu(v.y), f2hu(v.z), f2hu(v.w)};
  *(ushort4*)p = o;
}

// ---------------- zero the stats scratch (atomicAdd target) -----------------
__global__ void zero_stats_kernel(float* __restrict__ stats) {
  for (int k = threadIdx.x; k < 2048; k += 256) stats[k] = 0.f;
}

// ------- weight convert: [Co][Ci][3][3] fp32 -> [tap][co][ci] bf16 hi+lo ----
__global__ __launch_bounds__(256) void convert_w_kernel(
    const float* __restrict__ rw1, const float* __restrict__ rw2,
    unsigned short* __restrict__ wb) {
  int i = blockIdx.x * 256 + threadIdx.x;  // < 8*9*65536 = 4718592
  if (i >= 4718592) return;
  int conv = i / 589824;
  int rem = i % 589824;
  int tap = rem / 65536;
  int cc = rem % 65536;  // co*256+ci
  const float* src = ((conv & 1) ? rw2 : rw1) + (size_t)(conv >> 1) * 589824;
  float v = src[(size_t)cc * 9 + tap];
  bf16 h = __float2bfloat16(v);
  float fh = __bfloat162float(h);
  wb[i] = *reinterpret_cast<unsigned short*>(&h);
  bf16 l = __float2bfloat16(v - fh);
  wb[4718592 + i] = *reinterpret_cast<unsigned short*>(&l);
}

// ------- convT weight convert: [Ci][Co][3][3] fp32 -> [tap][co][ci] bf16 ----
__global__ __launch_bounds__(256) void convert_wd_kernel(
    const float* __restrict__ w, unsigned short* __restrict__ out, int Ci,
    int Co) {
  int i = blockIdx.x * 256 + threadIdx.x;
  int total = 9 * Co * Ci;
  if (i >= total) return;
  int tap = i / (Co * Ci);
  int rem = i % (Co * Ci);
  int co = rem / Ci;
  int ci = rem % Ci;
  out[i] = f2bu(w[((size_t)ci * Co + co) * 9 + tap]);
}

// ---------------- 3x3 s1 p1 conv via MFMA (bf16x3), Ci=Co=256, H=W=128 ------
__device__ __forceinline__ int swz3(int idx) {
  return (idx & 3) ^ ((idx >> 2) & 1);
}

__global__ __launch_bounds__(256) void conv3x3s1_mfma(
    const float* __restrict__ x, const unsigned short* __restrict__ wh,
    const unsigned short* __restrict__ wl, const float* __restrict__ bias,
    float* __restrict__ y) {
  const int H = 128, W = 128;
  int r = blockIdx.x;    // output row
  int cog = blockIdx.y;  // 0..1 (128 co each)
  int n = blockIdx.z;
  int tid = threadIdx.x;
  int wv = tid >> 6, lane = tid & 63;
  int wco = (wv >> 1) * 64, wpx = (wv & 1) * 64;
  int l15 = lane & 15, l4 = lane >> 4;

  __shared__ __align__(16) unsigned short Xh[3 * 130 * 32];
  __shared__ __align__(16) unsigned short Xl[3 * 130 * 32];
  __shared__ __align__(16) unsigned short Ah[128 * 32];
  __shared__ __align__(16) unsigned short Al[128 * 32];

  f32x4 acc[4][4];
#pragma unroll
  for (int m = 0; m < 4; ++m)
#pragma unroll
    for (int nf = 0; nf < 4; ++nf) acc[m][nf] = (f32x4){0.f, 0.f, 0.f, 0.f};

  const float* xn0 = x + (size_t)n * 256 * H * W;

  for (int cb = 0; cb < 8; ++cb) {
    int ci0 = cb * 32;
    {
      const float* xn = xn0 + (size_t)ci0 * H * W;
      for (int t = tid; t < 1560; t += 256) {
        int q = t & 3;
        int cr = t >> 2;     // 0..389
        int col = cr % 130;  // 0..129
        int row = cr / 130;  // 0..2
        int gr = r + row - 1;
        int gc = col - 1;
        bool ok = (gr >= 0) && (gr < H) && (gc >= 0) && (gc < W);
        uint4 ph = {0, 0, 0, 0};
        uint4 pl = {0, 0, 0, 0};
        if (ok) {
          const float* xp =
              xn + (size_t)(q * 8) * (H * W) + (size_t)gr * W + gc;
          unsigned short vh[8], vl[8];
#pragma unroll
          for (int e = 0; e < 8; ++e) {
            float v = xp[(size_t)e * H * W];
            bf16 hb = __float2bfloat16(v);
            float fh = __bfloat162float(hb);
            bf16 lb = __float2bfloat16(v - fh);
            vh[e] = *reinterpret_cast<unsigned short*>(&hb);
            vl[e] = *reinterpret_cast<unsigned short*>(&lb);
          }
          ph.x = (unsigned)vh[0] | ((unsigned)vh[1] << 16);
          ph.y = (unsigned)vh[2] | ((unsigned)vh[3] << 16);
          ph.z = (unsigned)vh[4] | ((unsigned)vh[5] << 16);
          ph.w = (unsigned)vh[6] | ((unsigned)vh[7] << 16);
          pl.x = (unsigned)vl[0] | ((unsigned)vl[1] << 16);
          pl.y = (unsigned)vl[2] | ((unsigned)vl[3] << 16);
          pl.z = (unsigned)vl[4] | ((unsigned)vl[5] << 16);
          pl.w = (unsigned)vl[6] | ((unsigned)vl[7] << 16);
        }
        int slot = (cr * 4 + (q ^ swz3(col))) * 8;
        *(uint4*)(&Xh[slot]) = ph;
        *(uint4*)(&Xl[slot]) = pl;
      }
    }
    for (int tap = 0; tap < 9; ++tap) {
      for (int t = tid; t < 1024; t += 256) {
        int half = t >> 9;
        int rem = t & 511;
        int q = rem & 3;
        int co = rem >> 2;
        const unsigned short* wsrc =
            (half ? wl : wh) +
            ((size_t)tap * 256 + cog * 128 + co) * 256 + ci0 + q * 8;
        uint4 pk = *(const uint4*)wsrc;
        int slot = (co * 4 + (q ^ swz3(co))) * 8;
        *(uint4*)((half ? Al : Ah) + slot) = pk;
      }
      __syncthreads();
      int ky = tap / 3;
      int kx = tap - ky * 3;
      bf16x8 ahf[4], alf[4], bhf[4], blf[4];
#pragma unroll
      for (int m = 0; m < 4; ++m) {
        int co = wco + m * 16 + l15;
        int slot = (co * 4 + (l4 ^ swz3(co))) * 8;
        ahf[m] = *(const bf16x8*)(&Ah[slot]);
        alf[m] = *(const bf16x8*)(&Al[slot]);
      }
#pragma unroll
      for (int nf = 0; nf < 4; ++nf) {
        int col = wpx + nf * 16 + l15 + kx;  // lds col = px + kx
        int slot = ((ky * 130 + col) * 4 + (l4 ^ swz3(col))) * 8;
        bhf[nf] = *(const bf16x8*)(&Xh[slot]);
        blf[nf] = *(const bf16x8*)(&Xl[slot]);
      }
#pragma unroll
      for (int m = 0; m < 4; ++m)
#pragma unroll
        for (int nf = 0; nf < 4; ++nf) {
          acc[m][nf] = __builtin_amdgcn_mfma_f32_16x16x32_bf16(
              ahf[m], bhf[nf], acc[m][nf], 0, 0, 0);
          acc[m][nf] = __builtin_amdgcn_mfma_f32_16x16x32_bf16(
              ahf[m], blf[nf], acc[m][nf], 0, 0, 0);
          acc[m][nf] = __builtin_amdgcn_mfma_f32_16x16x32_bf16(
              alf[m], bhf[nf], acc[m][nf], 0, 0, 0);
        }
      __syncthreads();
    }
  }
#pragma unroll
  for (int m = 0; m < 4; ++m) {
    int cob = cog * 128 + wco + m * 16 + l4 * 4;
#pragma unroll
    for (int reg = 0; reg < 4; ++reg) {
      float bv = bias[cob + reg];
      float* yr =
          y + (((size_t)(n * 256 + cob + reg) * H) + r) * W + wpx + l15;
#pragma unroll
      for (int nf = 0; nf < 4; ++nf) yr[nf * 16] = acc[m][nf][reg] + bv;
    }
  }
}

// ---------------- ConvTranspose2d k3 s2 p1 op1 via MFMA bf16 ----------------
// Block: input row r x 64 input cols (c0..c0+63), all Co. 4 waves:
// wv_co = wv>>1 (Co/2 each), wv_px = wv&1 (32 px each).
// Each of the 9 taps maps to ONE output parity (py,px)=((ky!=1),(kx!=1)) and
// input shift (row + (ky==0), col + (kx==0)) -- derived from the scalar kernel.
// acc[par][m][nf]; MF = Co/32 (d1: 4, d2: 2). Frag/swizzle conventions
// identical to conv3x3s1_mfma (verified).
template <int MF, typename Tin>
__global__ __launch_bounds__(256) void convt3x3_mfma(
    const Tin* __restrict__ x, const unsigned short* __restrict__ wc,
    const float* __restrict__ bias, bf16* __restrict__ y, int Ci, int Hi,
    int Wi) {
  const int Co = MF * 32;
  int Ho = Hi * 2, Wo = Wi * 2;
  int r = blockIdx.x;        // input row
  int c0 = blockIdx.y * 64;  // input col base
  int n = blockIdx.z;
  int tid = threadIdx.x;
  int wv = tid >> 6, lane = tid & 63;
  int wv_co = wv >> 1, wv_px = wv & 1;
  int l15 = lane & 15, l4 = lane >> 4;

  __shared__ __align__(16) unsigned short Xs[2 * 66 * 32];
  __shared__ __align__(16) unsigned short As[MF * 32 * 32 * 2];  // Co*32

  f32x4 acc[4][MF][2];
#pragma unroll
  for (int par = 0; par < 4; ++par)
#pragma unroll
    for (int m = 0; m < MF; ++m)
#pragma unroll
      for (int nf = 0; nf < 2; ++nf)
        acc[par][m][nf] = (f32x4){0.f, 0.f, 0.f, 0.f};

  const Tin* xb = x + (size_t)n * Ci * Hi * Wi;
  int nchunk = Ci >> 5;
  for (int cb = 0; cb < nchunk; ++cb) {
    int ci0 = cb * 32;
    // ---- stage input: rows r..r+1, cols c0..c0+64, 32 ci (bf16 bits) ----
    for (int t = tid; t < 520; t += 256) {
      int q = t & 3;
      int cr = t >> 2;    // 0..129
      int col = cr % 65;  // 0..64
      int row = cr / 65;  // 0..1
      int gr = r + row;
      int gc = c0 + col;
      uint4 pk = {0, 0, 0, 0};
      if (gr < Hi && gc < Wi) {
        const Tin* xp = xb + ((size_t)(ci0 + q * 8) * Hi + gr) * Wi + gc;
        unsigned short v[8];
#pragma unroll
        for (int e = 0; e < 8; ++e) v[e] = xbits(xp[(size_t)e * Hi * Wi]);
        pk.x = (unsigned)v[0] | ((unsigned)v[1] << 16);
        pk.y = (unsigned)v[2] | ((unsigned)v[3] << 16);
        pk.z = (unsigned)v[4] | ((unsigned)v[5] << 16);
        pk.w = (unsigned)v[6] | ((unsigned)v[7] << 16);
      }
      int slot = ((row * 66 + col) * 4 + (q ^ swz3(col))) * 8;
      *(uint4*)(&Xs[slot]) = pk;
    }
#pragma unroll
    for (int tap = 0; tap < 9; ++tap) {
      const int ky = tap / 3, kx = tap % 3;
      const int par = ((ky != 1) ? 2 : 0) + ((kx != 1) ? 1 : 0);
      const int trow = (ky == 0) ? 1 : 0;
      const int tcol = (kx == 0) ? 1 : 0;
      for (int t = tid; t < Co * 4; t += 256) {
        int q = t & 3;
        int co = t >> 2;
        uint4 pk =
            *(const uint4*)(wc + ((size_t)tap * Co + co) * Ci + ci0 + q * 8);
        int slot = (co * 4 + (q ^ swz3(co))) * 8;
        *(uint4*)(&As[slot]) = pk;
      }
      __syncthreads();
      bf16x8 af[MF], bfr[2];
#pragma unroll
      for (int m = 0; m < MF; ++m) {
        int co = wv_co * (MF * 16) + m * 16 + l15;
        int slot = (co * 4 + (l4 ^ swz3(co))) * 8;
        af[m] = *(const bf16x8*)(&As[slot]);
      }
#pragma unroll
      for (int nf = 0; nf < 2; ++nf) {
        int lc = wv_px * 32 + nf * 16 + l15 + tcol;
        int slot = ((trow * 66 + lc) * 4 + (l4 ^ swz3(lc))) * 8;
        bfr[nf] = *(const bf16x8*)(&Xs[slot]);
      }
#pragma unroll
      for (int m = 0; m < MF; ++m)
#pragma unroll
        for (int nf = 0; nf < 2; ++nf)
          acc[par][m][nf] = __builtin_amdgcn_mfma_f32_16x16x32_bf16(
              af[m], bfr[nf], acc[par][m][nf], 0, 0, 0);
      __syncthreads();  // protect As (next tap) and Xs (next chunk)
    }
  }
  // ---- epilogue: bias + bf16 store; output (2r+py, 2*px_in+px_) ----
#pragma unroll
  for (int par = 0; par < 4; ++par) {
    int py = par >> 1, pxp = par & 1;
    int orow = 2 * r + py;
#pragma unroll
    for (int m = 0; m < MF; ++m) {
#pragma unroll
      for (int reg = 0; reg < 4; ++reg) {
        int co = wv_co * (MF * 16) + m * 16 + l4 * 4 + reg;
        float bv = bias[co];
        bf16* yr = y + ((size_t)(n * Co + co) * Ho + orow) * Wo + pxp;
#pragma unroll
        for (int nf = 0; nf < 2; ++nf) {
          int px_in = c0 + wv_px * 32 + nf * 16 + l15;
          yr[2 * px_in] = f2b(acc[par][m][nf][reg] + bv);
        }
      }
    }
  }
}

// ---------------- e1: 7x7 conv p3, CI=3, LDS-tiled (1 ci slice at a time) ---
__global__ __launch_bounds__(256) void conv7_e1(
    const float* __restrict__ x, const float* __restrict__ w,
    const float* __restrict__ bias, float* __restrict__ stats,
    f16* __restrict__ y) {
  const int H = 512, W = 512;
  __shared__ float Xs[5200];         // [10][520] one ci, zero-padded halo
  __shared__ float wsh[8 * 3 * 49];  // 8 co slab
  __shared__ float sred[4][8], qred[4][8];
  int cog = blockIdx.y;  // 8 groups x 8 co
  int n = blockIdx.z;
  int tid = threadIdx.x;
  int r0 = blockIdx.x * 4;
  int tr = tid >> 6;
  int lane = tid & 63;
  for (int t = tid; t < 1176; t += 256) wsh[t] = w[cog * 1176 + t];
  const float* xb = x + (size_t)n * 3 * H * W;
  float acc[8][8];
#pragma unroll
  for (int j = 0; j < 8; ++j) {
#pragma unroll
    for (int p = 0; p < 8; ++p) acc[j][p] = 0.f;
  }
  for (int ci = 0; ci < 3; ++ci) {
    __syncthreads();  // protect Xs from prev readers; orders wsh on 1st iter
    for (int t = tid; t < 5200; t += 256) {
      int row = t / 520;
      int col = t - row * 520;
      int gr = r0 - 3 + row;
      int gc = col - 3;
      float v = 0.f;
      if (gr >= 0 && gr < H && gc >= 0 && gc < W)
        v = xb[((size_t)ci * H + gr) * W + gc];
      Xs[t] = v;
    }
    __syncthreads();
    for (int i = 0; i < 7; ++i) {
      const float* xr = &Xs[(tr + i) * 520 + lane];
      float v[8][7];
#pragma unroll
      for (int p = 0; p < 8; ++p)
#pragma unroll
        for (int k = 0; k < 7; ++k) v[p][k] = xr[p * 64 + k];
#pragma unroll
      for (int j = 0; j < 8; ++j) {
        const float* wr = &wsh[(j * 3 + ci) * 49 + i * 7];
        float w0 = wr[0], w1 = wr[1], w2 = wr[2], w3 = wr[3], w4 = wr[4],
              w5 = wr[5], w6 = wr[6];
#pragma unroll
        for (int p = 0; p < 8; ++p)
          acc[j][p] += v[p][0] * w0 + v[p][1] * w1 + v[p][2] * w2 +
                       v[p][3] * w3 + v[p][4] * w4 + v[p][5] * w5 +
                       v[p][6] * w6;
      }
    }
  }
  int r = r0 + tr;
#pragma unroll
  for (int j = 0; j < 8; ++j) {
    int co = cog * 8 + j;
    float bv = bias[co];
    f16* yr = y + ((size_t)(n * 64 + co) * H + r) * W + lane;
    float s = 0.f, q = 0.f;
#pragma unroll
    for (int p = 0; p < 8; ++p) {
      float o = acc[j][p] + bv;
      yr[p * 64] = __float2half(o);
      s += o;
      q += o * o;
    }
#pragma unroll
    for (int off = 32; off > 0; off >>= 1) {
      s += __shfl_down(s, off, 64);
      q += __shfl_down(q, off, 64);
    }
    if (lane == 0) {
      sred[tr][j] = s;
      qred[tr][j] = q;
    }
  }
  __syncthreads();
  if (tid < 8) {
    float S = sred[0][tid] + sred[1][tid] + sred[2][tid] + sred[3][tid];
    float Q = qred[0][tid] + qred[1][tid] + qred[2][tid] + qred[3][tid];
    atomicAdd(&stats[n * 64 + cog * 8 + tid], S);
    atomicAdd(&stats[1024 + n * 64 + cog * 8 + tid], Q);
  }
}

// ---------------- head: 7x7 conv via MFMA bf16, Ci=64, Co=3 (M padded 16) ---
__global__ __launch_bounds__(256) void conv7_head_mfma(
    const bf16* __restrict__ xin, const float* __restrict__ w,
    const float* __restrict__ bias, float* __restrict__ y) {
  const int H = 512, W = 512;
  __shared__ __align__(16) unsigned short Xs[10 * 264 * 8];
  __shared__ __align__(16) unsigned short wlds[7 * 16 * 64];
  int n = blockIdx.z;
  int cbase = blockIdx.y * 256;
  int r0 = blockIdx.x * 4;
  int tid = threadIdx.x;
  int wv = tid >> 6;  // wave = output row
  int lane = tid & 63;
  int l15 = lane & 15, l4 = lane >> 4;
  const unsigned short* xb =
      (const unsigned short*)xin + (size_t)n * 64 * H * W;
  f32x4 acc[16];
#pragma unroll
  for (int nf = 0; nf < 16; ++nf) acc[nf] = (f32x4){0.f, 0.f, 0.f, 0.f};
  for (int ch = 0; ch < 8; ++ch) {
    __syncthreads();  // protect Xs/wlds from previous chunk's readers
    for (int t = tid; t < 2640; t += 256) {
      int row = t / 264;
      int col = t - row * 264;
      int gr = r0 - 3 + row;
      int gc = cbase - 3 + col;
      uint4 pk = {0, 0, 0, 0};
      if (gr >= 0 && gr < H && gc >= 0 && gc < W) {
        const unsigned short* xp =
            xb + ((size_t)(ch * 8) * H + gr) * W + gc;
        unsigned short v[8];
#pragma unroll
        for (int e = 0; e < 8; ++e) v[e] = xp[(size_t)e * H * W];
        pk.x = (unsigned)v[0] | ((unsigned)v[1] << 16);
        pk.y = (unsigned)v[2] | ((unsigned)v[3] << 16);
        pk.z = (unsigned)v[4] | ((unsigned)v[5] << 16);
        pk.w = (unsigned)v[6] | ((unsigned)v[7] << 16);
      }
      *(uint4*)(&Xs[t * 8]) = pk;
    }
    for (int t = tid; t < 7168; t += 256) {
      int k64 = t & 63;
      int co = (t >> 6) & 15;
      int ky = t >> 10;
      int kx = k64 >> 3;
      int cie = k64 & 7;
      unsigned short val = 0;
      if (co < 3 && kx < 7)
        val = f2bu(w[((size_t)(co * 64 + ch * 8 + cie) * 7 + ky) * 7 + kx]);
      wlds[t] = val;
    }
    __syncthreads();
#pragma unroll 1
    for (int ky = 0; ky < 7; ++ky) {
      bf16x8 af0 = *(const bf16x8*)(&wlds[(ky * 16 + l15) * 64 + l4 * 8]);
      bf16x8 af1 =
          *(const bf16x8*)(&wlds[(ky * 16 + l15) * 64 + 32 + l4 * 8]);
      int xrow = wv + ky;
#pragma unroll
      for (int nf = 0; nf < 16; ++nf) {
        int col0 = nf * 16 + l15 + l4;  // kf=0: kx = l4
        bf16x8 b0 = *(const bf16x8*)(&Xs[(xrow * 264 + col0) * 8]);
        acc[nf] =
            __builtin_amdgcn_mfma_f32_16x16x32_bf16(af0, b0, acc[nf], 0, 0, 0);
        bf16x8 b1 = *(const bf16x8*)(&Xs[(xrow * 264 + col0 + 4) * 8]);
        acc[nf] =
            __builtin_amdgcn_mfma_f32_16x16x32_bf16(af1, b1, acc[nf], 0, 0, 0);
      }
    }
  }
  if (l4 == 0) {
    int r = r0 + wv;
#pragma unroll
    for (int nf = 0; nf < 16; ++nf) {
#pragma unroll
      for (int reg = 0; reg < 3; ++reg) {
        float o = tanhf(acc[nf][reg] + bias[reg]);
        y[((size_t)(n * 3 + reg) * H + r) * W + cbase + nf * 16 + l15] = o;
      }
    }
  }
}

// ---------------- 3x3 s2 p1 conv, tiled 4 px x 8 co ------------------------
template <typename Tin, typename Tout, bool NORM>
__global__ __launch_bounds__(256) void conv3x3s2_tile(
    const Tin* __restrict__ x, const float* __restrict__ w,
    const float* __restrict__ bias, const float* __restrict__ stats,
    Tout* __restrict__ y, int Ci, int Hi, int Wi) {
  int Ho = Hi >> 1, Wo = Wi >> 1;
  int cog = blockIdx.y;
  int Co = gridDim.y * 8;
  int n = blockIdx.z;
  int CG = Wo >> 2;
  int rpb = 256 / CG;
  int tid = threadIdx.x;
  int r = blockIdx.x * rpb + tid / CG;
  int c0 = (tid % CG) * 4;
  const Tin* xb = x + (size_t)n * Ci * Hi * Wi;
  int ir0 = 2 * r - 1;
  float mr0 = (ir0 >= 0) ? 1.f : 0.f;
  int cr0 = max(ir0, 0);
  int icl = 2 * c0 - 1;
  float mcl = (icl >= 0) ? 1.f : 0.f;
  int ccl = max(icl, 0);
  float acc[8][4];
#pragma unroll
  for (int j = 0; j < 8; ++j) {
    float b = bias[cog * 8 + j];
#pragma unroll
    for (int p = 0; p < 4; ++p) acc[j][p] = b;
  }
  for (int ci = 0; ci < Ci; ++ci) {
    const Tin* xc = xb + (size_t)ci * Hi * Wi;
    float sc = 1.f, sh = 0.f;
    if (NORM) {
      sc = stats[2048 + n * Ci + ci];
      sh = stats[3072 + n * Ci + ci];
    }
    float v[3][9];
#pragma unroll
    for (int i = 0; i < 3; ++i) {
      int rr = (i == 0) ? cr0 : (2 * r - 1 + i);
      float mi = (i == 0) ? mr0 : 1.f;
      const Tin* xr = xc + (size_t)rr * Wi;
      float t[9];
      t[0] = (float)xr[ccl];
      float4 a = ld4(xr + 2 * c0);
      float4 b4 = ld4(xr + 2 * c0 + 4);
      t[1] = a.x;
      t[2] = a.y;
      t[3] = a.z;
      t[4] = a.w;
      t[5] = b4.x;
      t[6] = b4.y;
      t[7] = b4.z;
      t[8] = b4.w;
      if (NORM) {
#pragma unroll
        for (int k = 0; k < 9; ++k) t[k] = fmaxf(fmaf(t[k], sc, sh), 0.f);
      }
      v[i][0] = t[0] * (mcl * mi);
#pragma unroll
      for (int k = 1; k < 9; ++k) v[i][k] = t[k] * mi;
    }
#pragma unroll
    for (int j = 0; j < 8; ++j) {
      const float* wc = w + ((size_t)(cog * 8 + j) * Ci + ci) * 9;
#pragma unroll
      for (int p = 0; p < 4; ++p) {
        acc[j][p] += v[0][2 * p] * wc[0] + v[0][2 * p + 1] * wc[1] +
                     v[0][2 * p + 2] * wc[2] + v[1][2 * p] * wc[3] +
                     v[1][2 * p + 1] * wc[4] + v[1][2 * p + 2] * wc[5] +
                     v[2][2 * p] * wc[6] + v[2][2 * p + 1] * wc[7] +
                     v[2][2 * p + 2] * wc[8];
      }
    }
  }
#pragma unroll
  for (int j = 0; j < 8; ++j) {
    float4 o = {acc[j][0], acc[j][1], acc[j][2], acc[j][3]};
    st4(y + ((size_t)(n * Co + cog * 8 + j) * Ho + r) * Wo + c0, o);
  }
}

// ---------------- 1x1 conv, tiled 4 px x 4 co, fp32 -------------------------
__global__ __launch_bounds__(256) void conv1x1_tile(
    const float* __restrict__ x, const float* __restrict__ w,
    const float* __restrict__ bias, float* __restrict__ y, int Ci, int HW) {
  int cog = blockIdx.y;
  int Co = gridDim.y * 4;
  int n = blockIdx.z;
  int p0 = (blockIdx.x * 256 + threadIdx.x) * 4;
  const float* xb = x + (size_t)n * Ci * HW + p0;
  float acc[4][4];
#pragma unroll
  for (int j = 0; j < 4; ++j) {
    float b = bias[cog * 4 + j];
#pragma unroll
    for (int p = 0; p < 4; ++p) acc[j][p] = b;
  }
  for (int ci = 0; ci < Ci; ++ci) {
    float4 xv = *(const float4*)(xb + (size_t)ci * HW);
#pragma unroll
    for (int j = 0; j < 4; ++j) {
      float wv = w[(size_t)(cog * 4 + j) * Ci + ci];
      acc[j][0] += xv.x * wv;
      acc[j][1] += xv.y * wv;
      acc[j][2] += xv.z * wv;
      acc[j][3] += xv.w * wv;
    }
  }
#pragma unroll
  for (int j = 0; j < 4; ++j) {
    float4 o = {acc[j][0], acc[j][1], acc[j][2], acc[j][3]};
    *(float4*)(y + (size_t)(n * Co + cog * 4 + j) * HW + p0) = o;
  }
}

// ---------------- per-(n,c) sum / sumsq reduction ---------------------------
template <typename Tin>
__global__ __launch_bounds__(256) void reduce_nc_kernel(
    const Tin* __restrict__ x, float* __restrict__ stats, int HW) {
  int b = blockIdx.x;
  const Tin* p = x + (size_t)b * HW;
  float s = 0.f, q = 0.f;
  for (int i = threadIdx.x; i < HW; i += 256) {
    float v = (float)p[i];
    s += v;
    q += v * v;
  }
  __shared__ float ss[256], qq[256];
  ss[threadIdx.x] = s;
  qq[threadIdx.x] = q;
  __syncthreads();
  for (int off = 128; off > 0; off >>= 1) {
    if (threadIdx.x < off) {
      ss[threadIdx.x] += ss[threadIdx.x + off];
      qq[threadIdx.x] += qq[threadIdx.x + off];
    }
    __syncthreads();
  }
  if (threadIdx.x == 0) {
    stats[b] = ss[0];
    stats[1024 + b] = qq[0];
  }
}

// ---------------- AdaLIN coefficients ---------------------------------------
__global__ void adalin_coef_kernel(float* __restrict__ stats,
                                   const float* __restrict__ rho,
                                   const float* __restrict__ gam,
                                   const float* __restrict__ bet, int N, int C,
                                   float invHW) {
  int i = blockIdx.x * blockDim.x + threadIdx.x;
  if (i >= N * C) return;
  int c = i % C;
  const float* sums = stats;
  const float* sqs = stats + 1024;
  float im = sums[i] * invHW;
  float iv = sqs[i] * invHW - im * im;
  float lsum = 0.f, lsq = 0.f;
  for (int n = 0; n < N; ++n) {
    lsum += sums[n * C + c];
    lsq += sqs[n * C + c];
  }
  float lm = lsum * invHW / N;
  float lv = lsq * invHW / N - lm * lm;
  float r = rho[c];
  float mean = r * im + (1.f - r) * lm;
  float var = fmaxf(r * iv + (1.f - r) * lv, 0.f);
  float sc = gam[c] / sqrtf(var + EPSN);
  stats[2048 + i] = sc;
  stats[3072 + i] = bet[c] - mean * sc;
}

// ---------------- InstanceNorm coefficients ---------------------------------
__global__ void inorm_coef_kernel(float* __restrict__ stats, int NC,
                                  float invHW) {
  int i = blockIdx.x * blockDim.x + threadIdx.x;
  if (i >= NC) return;
  float im = stats[i] * invHW;
  float iv = fmaxf(stats[1024 + i] * invHW - im * im, 0.f);
  float sc = 1.f / sqrtf(iv + EPSN);
  stats[2048 + i] = sc;
  stats[3072 + i] = -im * sc;
}

// ---------------- x = (relu?)(x*scale[nc] + shift[nc])  (in-place) ----------
template <typename T>
__global__ __launch_bounds__(256) void scale_shift_kernel(
    T* __restrict__ x, const float* __restrict__ stats, int HW, size_t total,
    int relu) {
  size_t i = (size_t)blockIdx.x * 256 + threadIdx.x;
  if (i >= total) return;
  int nc = (int)(i / (size_t)HW);
  float v = (float)x[i] * stats[2048 + nc] + stats[3072 + nc];
  if (relu) v = fmaxf(v, 0.f);
  stv(x, i, v);
}

// ---------------- dst = relu(dst + a)  (fp32) -------------------------------
__global__ __launch_bounds__(256) void add_relu_kernel(
    float* __restrict__ dst, const float* __restrict__ a, size_t total) {
  size_t i = (size_t)blockIdx.x * 256 + threadIdx.x;
  if (i >= total) return;
  dst[i] = fmaxf(dst[i] + a[i], 0.f);
}

// ---------------- windowed attention (all fp32) -----------------------------
__global__ __launch_bounds__(256) void win_attn_kernel(
    const float* __restrict__ f, const float* __restrict__ g,
    const float* __restrict__ h, float* __restrict__ out) {
  const int H = 128;
  int j = blockIdx.x;
  int i = blockIdx.y;
  int b = blockIdx.z;
  __shared__ float fs[32 * 64];
  __shared__ float gs[32 * 64];
  __shared__ float att[16 * 64];
  int t = threadIdx.x;
  for (int idx = t; idx < 32 * 64; idx += 256) {
    int c = idx >> 6, k = idx & 63;
    int hr = i * 4 + (k >> 3), wc = j * 4 + (k & 7);
    float fv = 0.f, gv = 0.f;
    if (hr < H && wc < H) {
      size_t o = ((size_t)(b * 32 + c) * H + hr) * H + wc;
      fv = f[o];
      gv = g[o];
    }
    fs[idx] = fv;
    gs[idx] = gv;
  }
  __syncthreads();
  for (int idx = t; idx < 1024; idx += 256) {
    int q = idx >> 6, k = idx & 63;
    int qi = (q >> 2) * 8 + (q & 3);
    int hr = i * 4 + (k >> 3), wc = j * 4 + (k & 7);
    float s;
    if (hr < H && wc < H) {
      s = 0.f;
      for (int c = 0; c < 32; ++c) s += fs[c * 64 + qi] * gs[c * 64 + k];
    } else {
      s = -1e30f;
    }
    att[idx] = s;
  }
  __syncthreads();
  if (t < 16) {
    float m = -1e30f;
    for (int k = 0; k < 64; ++k) m = fmaxf(m, att[t * 64 + k]);
    float d = 0.f;
    for (int k = 0; k < 64; ++k) {
      float e = expf(att[t * 64 + k] - m);
      att[t * 64 + k] = e;
      d += e;
    }
    float inv = 1.f / d;
    for (int k = 0; k < 64; ++k) att[t * 64 + k] *= inv;
  }
  __syncthreads();
  int c = t;
  float accs[16];
  for (int q = 0; q < 16; ++q) accs[q] = 0.f;
  const float* hb = h + (size_t)(b * 256 + c) * H * H;
  for (int k = 0; k < 64; ++k) {
    int hr = i * 4 + (k >> 3), wc = j * 4 + (k & 7);
    if (hr >= H || wc >= H) continue;
    float hv = hb[hr * H + wc];
    for (int q = 0; q < 16; ++q) accs[q] += hv * att[q * 64 + k];
  }
  for (int q = 0; q < 16; ++q) {
    int oh = i * 4 + (q >> 2), ow = j * 4 + (q & 3);
    out[((size_t)(b * 256 + c) * H + oh) * H + ow] = accs[q];
  }
}

// ============================================================================
extern "C" void kernel_launch(void* const* d_in, const int* in_sizes, int n_in,
                              void* d_out, int out_size, void* d_ws,
                              size_t ws_size, hipStream_t stream) {
  const float* x = (const float*)d_in[0];
  const float* w_e1 = (const float*)d_in[1];
  const float* b_e1 = (const float*)d_in[2];
  const float* rho1 = (const float*)d_in[3];
  const float* gam1 = (const float*)d_in[4];
  const float* bet1 = (const float*)d_in[5];
  const float* w_e2 = (const float*)d_in[6];
  const float* b_e2 = (const float*)d_in[7];
  const float* rho2 = (const float*)d_in[8];
  const float* gam2 = (const float*)d_in[9];
  const float* bet2 = (const float*)d_in[10];
  const float* w_e3 = (const float*)d_in[11];
  const float* b_e3 = (const float*)d_in[12];
  const float* rho3 = (const float*)d_in[13];
  const float* gam3 = (const float*)d_in[14];
  const float* bet3 = (const float*)d_in[15];
  const float* rw1 = (const float*)d_in[16];
  const float* rb1 = (const float*)d_in[17];
  const float* rw2 = (const float*)d_in[18];
  const float* rb2 = (const float*)d_in[19];
  const float* w_f = (const float*)d_in[20];
  const float* b_f = (const float*)d_in[21];
  const float* w_g = (const float*)d_in[22];
  const float* b_g = (const float*)d_in[23];
  const float* w_h = (const float*)d_in[24];
  const float* b_h = (const float*)d_in[25];
  const float* w_d1 = (const float*)d_in[26];
  const float* b_d1 = (const float*)d_in[27];
  const float* rho4 = (const float*)d_in[28];
  const float* gam4 = (const float*)d_in[29];
  const float* bet4 = (const float*)d_in[30];
  const float* w_d2 = (const float*)d_in[31];
  const float* b_d2 = (const float*)d_in[32];
  const float* rho5 = (const float*)d_in[33];
  const float* gam5 = (const float*)d_in[34];
  const float* bet5 = (const float*)d_in[35];
  const float* w_d3 = (const float*)d_in[36];
  const float* b_d3 = (const float*)d_in[37];

  // ws layout (192 MiB):
  // E1H f16 raw e1 [0,128MiB) (dead after e2)
  // B2H f16 raw e2 [128,192) (dead after e3; later Bb2 bf16 d1 out)
  // Cc fp32 [0,64), D fp32 [64,128), E fp32 [128,192) (residual stage)
  // F1/F2 fp32 [64,80) (attention f/g); A2 bf16 [0,128) (d2 out)
  char* wsb = (char*)d_ws;
  f16* E1H = (f16*)wsb;
  float* Cc = (float*)wsb;
  float* D = (float*)(wsb + 67108864);
  float* E = (float*)(wsb + 134217728);
  float* F1 = (float*)(wsb + 67108864);
  float* F2 = (float*)(wsb + 75497472);
  f16* B2H = (f16*)(wsb + 134217728);
  bf16* Bb2 = (bf16*)(wsb + 134217728);
  bf16* A2 = (bf16*)wsb;

  float* out_img = (float*)d_out;
  float* out_attn = out_img + 3145728;
  // 16 KiB stats scratch at head of img region; fully overwritten by head conv
  float* stats = (float*)d_out;
  // bf16 hi+lo residual weights scratch in the (not yet written) out_attn
  // region; fully consumed before win_attn_kernel writes out_attn.
  unsigned short* wbres = (unsigned short*)((char*)d_out + 12582912);
  // convT bf16 weights [tap][co][ci] in out_img scratch (bytes 1-2.3 MiB);
  // consumed by d1/d2 before conv7_head_mfma overwrites out_img.
  unsigned short* wd1c = (unsigned short*)((char*)d_out + 1048576);
  unsigned short* wd2c = (unsigned short*)((char*)d_out + 2097152);

  dim3 blk(256);

  // ---- weight conversions (once) ----
  convert_w_kernel<<<18432, blk, 0, stream>>>(rw1, rw2, wbres);
  convert_wd_kernel<<<1152, blk, 0, stream>>>(w_d1, wd1c, 256, 128);
  convert_wd_kernel<<<288, blk, 0, stream>>>(w_d2, wd2c, 128, 64);

  // ---- e1: 7x7 conv (LDS-tiled) -> raw f16 + stats ----
  zero_stats_kernel<<<1, 256, 0, stream>>>(stats);
  conv7_e1<<<dim3(128, 8, 4), blk, 0, stream>>>(x, w_e1, b_e1, stats, E1H);
  adalin_coef_kernel<<<1, 256, 0, stream>>>(stats, rho1, gam1, bet1, 4, 64,
                                            1.f / 262144.f);
  // ---- e2: 3x3 s2 conv with fused e1-norm+relu -> raw f16 ----
  conv3x3s2_tile<f16, f16, true><<<dim3(64, 16, 4), blk, 0, stream>>>(
      E1H, w_e2, b_e2, stats, B2H, 64, 512, 512);
  reduce_nc_kernel<f16><<<512, blk, 0, stream>>>(B2H, stats, 65536);
  adalin_coef_kernel<<<2, 256, 0, stream>>>(stats, rho2, gam2, bet2, 4, 128,
                                            1.f / 65536.f);
  // ---- e3: 3x3 s2 conv with fused e2-norm+relu -> fp32, then AdaLIN ----
  conv3x3s2_tile<f16, float, true><<<dim3(16, 32, 4), blk, 0, stream>>>(
      B2H, w_e3, b_e3, stats, Cc, 128, 256, 256);
  reduce_nc_kernel<float><<<1024, blk, 0, stream>>>(Cc, stats, 16384);
  adalin_coef_kernel<<<4, 256, 0, stream>>>(stats, rho3, gam3, bet3, 4, 256,
                                            1.f / 16384.f);
  scale_shift_kernel<float><<<65536, blk, 0, stream>>>(Cc, stats, 16384,
                                                       (size_t)16777216, 1);
  // ---- 4 residual blocks (bf16x3 MFMA convs) ----
  for (int r = 0; r < 4; ++r) {
    const float* rb1p = rb1 + (size_t)r * 256;
    const float* rb2p = rb2 + (size_t)r * 256;
    const unsigned short* w1h = wbres + (size_t)(r * 2) * 589824;
    const unsigned short* w1l = w1h + 4718592;
    const unsigned short* w2h = wbres + (size_t)(r * 2 + 1) * 589824;
    const unsigned short* w2l = w2h + 4718592;
    conv3x3s1_mfma<<<dim3(128, 2, 4), blk, 0, stream>>>(Cc, w1h, w1l, rb1p, D);
    reduce_nc_kernel<float><<<1024, blk, 0, stream>>>(D, stats, 16384);
    inorm_coef_kernel<<<4, 256, 0, stream>>>(stats, 1024, 1.f / 16384.f);
    scale_shift_kernel<float><<<65536, blk, 0, stream>>>(D, stats, 16384,
                                                         (size_t)16777216, 1);
    conv3x3s1_mfma<<<dim3(128, 2, 4), blk, 0, stream>>>(D, w2h, w2l, rb2p, E);
    reduce_nc_kernel<float><<<1024, blk, 0, stream>>>(E, stats, 16384);
    inorm_coef_kernel<<<4, 256, 0, stream>>>(stats, 1024, 1.f / 16384.f);
    scale_shift_kernel<float><<<65536, blk, 0, stream>>>(E, stats, 16384,
                                                         (size_t)16777216, 0);
    add_relu_kernel<<<65536, blk, 0, stream>>>(Cc, E, (size_t)16777216);
  }
  // ---- attention: 1x1 convs f/g/h + windowed attention ----
  conv1x1_tile<<<dim3(16, 8, 4), blk, 0, stream>>>(Cc, w_f, b_f, F1, 256,
                                                   16384);
  conv1x1_tile<<<dim3(16, 8, 4), blk, 0, stream>>>(Cc, w_g, b_g, F2, 256,
                                                   16384);
  conv1x1_tile<<<dim3(16, 64, 4), blk, 0, stream>>>(Cc, w_h, b_h, E, 256,
                                                    16384);
  win_attn_kernel<<<dim3(32, 32, 4), blk, 0, stream>>>(F1, F2, E, out_attn);
  // ---- d1: convT 256->128 via MFMA, AdaLIN, relu (bf16 out) ----
  convt3x3_mfma<4, float><<<dim3(128, 2, 4), blk, 0, stream>>>(
      Cc, wd1c, b_d1, Bb2, 256, 128, 128);
  reduce_nc_kernel<bf16><<<512, blk, 0, stream>>>(Bb2, stats, 65536);
  adalin_coef_kernel<<<2, 256, 0, stream>>>(stats, rho4, gam4, bet4, 4, 128,
                                            1.f / 65536.f);
  scale_shift_kernel<bf16><<<131072, blk, 0, stream>>>(Bb2, stats, 65536,
                                                       (size_t)33554432, 1);
  // ---- d2: convT 128->64 via MFMA, AdaLIN, relu (bf16) ----
  convt3x3_mfma<2, bf16><<<dim3(256, 4, 4), blk, 0, stream>>>(
      Bb2, wd2c, b_d2, A2, 128, 256, 256);
  reduce_nc_kernel<bf16><<<256, blk, 0, stream>>>(A2, stats, 262144);
  adalin_coef_kernel<<<1, 256, 0, stream>>>(stats, rho5, gam5, bet5, 4, 64,
                                            1.f / 262144.f);
  scale_shift_kernel<bf16><<<262144, blk, 0, stream>>>(A2, stats, 262144,
                                                       (size_t)67108864, 1);
  // ---- head: 7x7 conv via MFMA + tanh -> fp32 img ----
  conv7_head_mfma<<<dim3(128, 2, 4), blk, 0, stream>>>(A2, w_d3, b_d3,
                                                       out_img);
}

// Round 12
// 5974.626 us; speedup vs baseline: 1.7763x; 1.1241x over previous
//
#include <hip/hip_runtime.h>
#include <hip/hip_bf16.h>
#include <hip/hip_fp16.h>

#define EPSN 1e-5f

typedef __hip_bfloat16 bf16;
typedef __half f16;
typedef __attribute__((ext_vector_type(8))) short bf16x8;
typedef __attribute__((ext_vector_type(4))) float f32x4;

__device__ __forceinline__ float b2f(bf16 v) { return __bfloat162float(v); }
__device__ __forceinline__ bf16 f2b(float v) { return __float2bfloat16(v); }
__device__ __forceinline__ unsigned short f2bu(float v) {
  bf16 h = __float2bfloat16(v);
  return *reinterpret_cast<unsigned short*>(&h);
}
__device__ __forceinline__ float bu2f(unsigned short u) {
  unsigned int b = ((unsigned int)u) << 16;
  return __uint_as_float(b);
}
__device__ __forceinline__ unsigned short f2hu(float v) {
  f16 h = __float2half(v);
  return *reinterpret_cast<unsigned short*>(&h);
}
__device__ __forceinline__ float hu2f(unsigned short u) {
  f16 h = *reinterpret_cast<f16*>(&u);
  return __half2float(h);
}
__device__ __forceinline__ void stv(bf16* p, size_t i, float v) { p[i] = f2b(v); }
__device__ __forceinline__ void stv(float* p, size_t i, float v) { p[i] = v; }
__device__ __forceinline__ void stv(f16* p, size_t i, float v) {
  p[i] = __float2half(v);
}

// bf16-bits helper for staging (fp32 -> bf16 bits, or bf16 bit-copy)
__device__ __forceinline__ unsigned short xbits(float v) { return f2bu(v); }
__device__ __forceinline__ unsigned short xbits(bf16 v) {
  return *reinterpret_cast<unsigned short*>(&v);
}

// vec4 load/store helpers (fp32/bf16 storage, fp32 compute)
__device__ __forceinline__ float4 ld4(const float* p) { return *(const float4*)p; }
__device__ __forceinline__ float4 ld4(const bf16* p) {
  ushort4 u = *(const ushort4*)p;
  float4 r;
  r.x = bu2f(u.x);
  r.y = bu2f(u.y);
  r.z = bu2f(u.z);
  r.w = bu2f(u.w);
  return r;
}
__device__ __forceinline__ void st4(float* p, float4 v) { *(float4*)p = v; }
__device__ __forceinline__ void st4(bf16* p, float4 v) {
  uint2 o;
  o.x = (unsigned)f2bu(v.x) | ((unsigned)f2bu(v.y) << 16);
  o.y = (unsigned)f2bu(v.z) | ((unsigned)f2bu(v.w) << 16);
  *(uint2*)p = o;
}

// ---------------- zero the stats scratch (atomicAdd target) -----------------
__global__ void zero_stats_kernel(float* __restrict__ stats) {
  for (int k = threadIdx.x; k < 2048; k += 256) stats[k] = 0.f;
}

// ------- weight convert: [Co][Ci][3][3] fp32 -> [tap][co][ci] bf16 hi+lo ----
__global__ __launch_bounds__(256) void convert_w_kernel(
    const float* __restrict__ rw1, const float* __restrict__ rw2,
    unsigned short* __restrict__ wb) {
  int i = blockIdx.x * 256 + threadIdx.x;  // < 8*9*65536 = 4718592
  if (i >= 4718592) return;
  int conv = i / 589824;
  int rem = i % 589824;
  int tap = rem / 65536;
  int cc = rem % 65536;  // co*256+ci
  const float* src = ((conv & 1) ? rw2 : rw1) + (size_t)(conv >> 1) * 589824;
  float v = src[(size_t)cc * 9 + tap];
  bf16 h = __float2bfloat16(v);
  float fh = __bfloat162float(h);
  wb[i] = *reinterpret_cast<unsigned short*>(&h);
  bf16 l = __float2bfloat16(v - fh);
  wb[4718592 + i] = *reinterpret_cast<unsigned short*>(&l);
}

// ------- convT weight convert: [Ci][Co][3][3] fp32 -> [tap][co][ci] bf16 ----
__global__ __launch_bounds__(256) void convert_wd_kernel(
    const float* __restrict__ w, unsigned short* __restrict__ out, int Ci,
    int Co) {
  int i = blockIdx.x * 256 + threadIdx.x;
  int total = 9 * Co * Ci;
  if (i >= total) return;
  int tap = i / (Co * Ci);
  int rem = i % (Co * Ci);
  int co = rem / Ci;
  int ci = rem % Ci;
  out[i] = f2bu(w[((size_t)ci * Co + co) * 9 + tap]);
}

// ------- s2-conv weight convert: [Co][Ci][3][3] fp32 -> [tap][co][ci] hi+lo -
__global__ __launch_bounds__(256) void convert_ws2_kernel(
    const float* __restrict__ w, unsigned short* __restrict__ out, int Ci,
    int Co) {
  int i = blockIdx.x * 256 + threadIdx.x;
  int total = 9 * Co * Ci;
  if (i >= total) return;
  int tap = i / (Co * Ci);
  int rem = i % (Co * Ci);
  int co = rem / Ci;
  int ci = rem % Ci;
  float v = w[((size_t)co * Ci + ci) * 9 + tap];
  bf16 h = __float2bfloat16(v);
  float fh = __bfloat162float(h);
  out[i] = *reinterpret_cast<unsigned short*>(&h);
  bf16 l = __float2bfloat16(v - fh);
  out[total + i] = *reinterpret_cast<unsigned short*>(&l);
}

// ---------------- 3x3 s1 p1 conv via MFMA (bf16x3), Ci=Co=256, H=W=128 ------
__device__ __forceinline__ int swz3(int idx) {
  return (idx & 3) ^ ((idx >> 2) & 1);
}

__global__ __launch_bounds__(256) void conv3x3s1_mfma(
    const float* __restrict__ x, const unsigned short* __restrict__ wh,
    const unsigned short* __restrict__ wl, const float* __restrict__ bias,
    float* __restrict__ y) {
  const int H = 128, W = 128;
  int r = blockIdx.x;    // output row
  int cog = blockIdx.y;  // 0..1 (128 co each)
  int n = blockIdx.z;
  int tid = threadIdx.x;
  int wv = tid >> 6, lane = tid & 63;
  int wco = (wv >> 1) * 64, wpx = (wv & 1) * 64;
  int l15 = lane & 15, l4 = lane >> 4;

  __shared__ __align__(16) unsigned short Xh[3 * 130 * 32];
  __shared__ __align__(16) unsigned short Xl[3 * 130 * 32];
  __shared__ __align__(16) unsigned short Ah[128 * 32];
  __shared__ __align__(16) unsigned short Al[128 * 32];

  f32x4 acc[4][4];
#pragma unroll
  for (int m = 0; m < 4; ++m)
#pragma unroll
    for (int nf = 0; nf < 4; ++nf) acc[m][nf] = (f32x4){0.f, 0.f, 0.f, 0.f};

  const float* xn0 = x + (size_t)n * 256 * H * W;

  for (int cb = 0; cb < 8; ++cb) {
    int ci0 = cb * 32;
    {
      const float* xn = xn0 + (size_t)ci0 * H * W;
      for (int t = tid; t < 1560; t += 256) {
        int q = t & 3;
        int cr = t >> 2;     // 0..389
        int col = cr % 130;  // 0..129
        int row = cr / 130;  // 0..2
        int gr = r + row - 1;
        int gc = col - 1;
        bool ok = (gr >= 0) && (gr < H) && (gc >= 0) && (gc < W);
        uint4 ph = {0, 0, 0, 0};
        uint4 pl = {0, 0, 0, 0};
        if (ok) {
          const float* xp =
              xn + (size_t)(q * 8) * (H * W) + (size_t)gr * W + gc;
          unsigned short vh[8], vl[8];
#pragma unroll
          for (int e = 0; e < 8; ++e) {
            float v = xp[(size_t)e * H * W];
            bf16 hb = __float2bfloat16(v);
            float fh = __bfloat162float(hb);
            bf16 lb = __float2bfloat16(v - fh);
            vh[e] = *reinterpret_cast<unsigned short*>(&hb);
            vl[e] = *reinterpret_cast<unsigned short*>(&lb);
          }
          ph.x = (unsigned)vh[0] | ((unsigned)vh[1] << 16);
          ph.y = (unsigned)vh[2] | ((unsigned)vh[3] << 16);
          ph.z = (unsigned)vh[4] | ((unsigned)vh[5] << 16);
          ph.w = (unsigned)vh[6] | ((unsigned)vh[7] << 16);
          pl.x = (unsigned)vl[0] | ((unsigned)vl[1] << 16);
          pl.y = (unsigned)vl[2] | ((unsigned)vl[3] << 16);
          pl.z = (unsigned)vl[4] | ((unsigned)vl[5] << 16);
          pl.w = (unsigned)vl[6] | ((unsigned)vl[7] << 16);
        }
        int slot = (cr * 4 + (q ^ swz3(col))) * 8;
        *(uint4*)(&Xh[slot]) = ph;
        *(uint4*)(&Xl[slot]) = pl;
      }
    }
    for (int tap = 0; tap < 9; ++tap) {
      for (int t = tid; t < 1024; t += 256) {
        int half = t >> 9;
        int rem = t & 511;
        int q = rem & 3;
        int co = rem >> 2;
        const unsigned short* wsrc =
            (half ? wl : wh) +
            ((size_t)tap * 256 + cog * 128 + co) * 256 + ci0 + q * 8;
        uint4 pk = *(const uint4*)wsrc;
        int slot = (co * 4 + (q ^ swz3(co))) * 8;
        *(uint4*)((half ? Al : Ah) + slot) = pk;
      }
      __syncthreads();
      int ky = tap / 3;
      int kx = tap - ky * 3;
      bf16x8 ahf[4], alf[4], bhf[4], blf[4];
#pragma unroll
      for (int m = 0; m < 4; ++m) {
        int co = wco + m * 16 + l15;
        int slot = (co * 4 + (l4 ^ swz3(co))) * 8;
        ahf[m] = *(const bf16x8*)(&Ah[slot]);
        alf[m] = *(const bf16x8*)(&Al[slot]);
      }
#pragma unroll
      for (int nf = 0; nf < 4; ++nf) {
        int col = wpx + nf * 16 + l15 + kx;  // lds col = px + kx
        int slot = ((ky * 130 + col) * 4 + (l4 ^ swz3(col))) * 8;
        bhf[nf] = *(const bf16x8*)(&Xh[slot]);
        blf[nf] = *(const bf16x8*)(&Xl[slot]);
      }
#pragma unroll
      for (int m = 0; m < 4; ++m)
#pragma unroll
        for (int nf = 0; nf < 4; ++nf) {
          acc[m][nf] = __builtin_amdgcn_mfma_f32_16x16x32_bf16(
              ahf[m], bhf[nf], acc[m][nf], 0, 0, 0);
          acc[m][nf] = __builtin_amdgcn_mfma_f32_16x16x32_bf16(
              ahf[m], blf[nf], acc[m][nf], 0, 0, 0);
          acc[m][nf] = __builtin_amdgcn_mfma_f32_16x16x32_bf16(
              alf[m], bhf[nf], acc[m][nf], 0, 0, 0);
        }
      __syncthreads();
    }
  }
#pragma unroll
  for (int m = 0; m < 4; ++m) {
    int cob = cog * 128 + wco + m * 16 + l4 * 4;
#pragma unroll
    for (int reg = 0; reg < 4; ++reg) {
      float bv = bias[cob + reg];
      float* yr =
          y + (((size_t)(n * 256 + cob + reg) * H) + r) * W + wpx + l15;
#pragma unroll
      for (int nf = 0; nf < 4; ++nf) yr[nf * 16] = acc[m][nf][reg] + bv;
    }
  }
}

// ---------------- 3x3 s2 p1 conv via MFMA (bf16x3), fused input norm --------
// Block: 128 co x 64 out px x 1 out row. Input cols staged by PARITY so all
// tap reads are lane-stride-1: kx=1 -> Xe[px], kx=0 -> Xo[px], kx=2 -> Xo[px+1].
// Input v = relu(x*sc[n,ci]+sh[n,ci]) applied fp32 during staging, hi/lo split.
// Frag/swizzle conventions identical to conv3x3s1_mfma (verified).
template <typename Tout>
__global__ __launch_bounds__(256) void conv3x3s2_mfma(
    const f16* __restrict__ x, const unsigned short* __restrict__ wch,
    const unsigned short* __restrict__ wcl, const float* __restrict__ bias,
    const float* __restrict__ stats, Tout* __restrict__ y, int Ci, int Hi,
    int Wi, int Cotot) {
  int Ho = Hi >> 1, Wo = Wi >> 1;
  int r = blockIdx.x;
  int npx = Wo >> 6;
  int pxg = blockIdx.y % npx;
  int cog = blockIdx.y / npx;
  int n = blockIdx.z;
  int tid = threadIdx.x;
  int wv = tid >> 6, lane = tid & 63;
  int wv_co = wv >> 1, wv_px = wv & 1;
  int l15 = lane & 15, l4 = lane >> 4;
  int pxbase = pxg * 64;

  __shared__ __align__(16) unsigned short Xeh[3 * 64 * 32];
  __shared__ __align__(16) unsigned short Xel[3 * 64 * 32];
  __shared__ __align__(16) unsigned short Xoh[3 * 68 * 32];
  __shared__ __align__(16) unsigned short Xol[3 * 68 * 32];
  __shared__ __align__(16) unsigned short Ah[128 * 32];
  __shared__ __align__(16) unsigned short Al[128 * 32];

  f32x4 acc[4][2];
#pragma unroll
  for (int m = 0; m < 4; ++m)
#pragma unroll
    for (int nf = 0; nf < 2; ++nf) acc[m][nf] = (f32x4){0.f, 0.f, 0.f, 0.f};

  const f16* xb = x + (size_t)n * Ci * Hi * Wi;
  int nchunk = Ci >> 5;
  for (int cb = 0; cb < nchunk; ++cb) {
    int ci0 = cb * 32;
    // ---- stage inputs with fused norm+relu, hi/lo split, parity split ----
    for (int t = tid; t < 1548; t += 256) {
      bool isodd = t >= 768;
      int tt = isodd ? (t - 768) : t;
      int q = tt & 3;
      int cr = tt >> 2;  // even: 0..191 (i*64+e); odd: 0..194 (i*65+j)
      int i, idx;
      if (!isodd) {
        i = cr >> 6;
        idx = cr & 63;
      } else {
        i = cr / 65;
        idx = cr % 65;
      }
      int gr = 2 * r - 1 + i;
      int gc = isodd ? (2 * pxbase + 2 * idx - 1) : (2 * (pxbase + idx));
      uint4 ph = {0, 0, 0, 0};
      uint4 pl4 = {0, 0, 0, 0};
      if (gr >= 0 && gr < Hi && gc >= 0 && gc < Wi) {
        const f16* xp = xb + ((size_t)(ci0 + q * 8) * Hi + gr) * Wi + gc;
        const float* scp = stats + 2048 + n * Ci + ci0 + q * 8;
        const float* shp = stats + 3072 + n * Ci + ci0 + q * 8;
        unsigned short vh[8], vl[8];
#pragma unroll
        for (int e = 0; e < 8; ++e) {
          float raw = (float)xp[(size_t)e * Hi * Wi];
          float v = fmaxf(fmaf(raw, scp[e], shp[e]), 0.f);
          bf16 hb = __float2bfloat16(v);
          float fh = __bfloat162float(hb);
          bf16 lb = __float2bfloat16(v - fh);
          vh[e] = *reinterpret_cast<unsigned short*>(&hb);
          vl[e] = *reinterpret_cast<unsigned short*>(&lb);
        }
        ph.x = (unsigned)vh[0] | ((unsigned)vh[1] << 16);
        ph.y = (unsigned)vh[2] | ((unsigned)vh[3] << 16);
        ph.z = (unsigned)vh[4] | ((unsigned)vh[5] << 16);
        ph.w = (unsigned)vh[6] | ((unsigned)vh[7] << 16);
        pl4.x = (unsigned)vl[0] | ((unsigned)vl[1] << 16);
        pl4.y = (unsigned)vl[2] | ((unsigned)vl[3] << 16);
        pl4.z = (unsigned)vl[4] | ((unsigned)vl[5] << 16);
        pl4.w = (unsigned)vl[6] | ((unsigned)vl[7] << 16);
      }
      int stride = isodd ? 68 : 64;
      int slot = ((i * stride + idx) * 4 + (q ^ swz3(idx))) * 8;
      if (isodd) {
        *(uint4*)(&Xoh[slot]) = ph;
        *(uint4*)(&Xol[slot]) = pl4;
      } else {
        *(uint4*)(&Xeh[slot]) = ph;
        *(uint4*)(&Xel[slot]) = pl4;
      }
    }
#pragma unroll
    for (int tap = 0; tap < 9; ++tap) {
      const int ky = tap / 3, kx = tap % 3;
      for (int t = tid; t < 1024; t += 256) {
        int half = t >> 9;
        int rem = t & 511;
        int q = rem & 3;
        int co = rem >> 2;
        const unsigned short* wsrc =
            (half ? wcl : wch) +
            ((size_t)tap * Cotot + cog * 128 + co) * Ci + ci0 + q * 8;
        uint4 pk = *(const uint4*)wsrc;
        int slot = (co * 4 + (q ^ swz3(co))) * 8;
        *(uint4*)((half ? Al : Ah) + slot) = pk;
      }
      __syncthreads();
      bf16x8 ahf[4], alf[4], bhf[2], blf[2];
#pragma unroll
      for (int m = 0; m < 4; ++m) {
        int co = wv_co * 64 + m * 16 + l15;
        int slot = (co * 4 + (l4 ^ swz3(co))) * 8;
        ahf[m] = *(const bf16x8*)(&Ah[slot]);
        alf[m] = *(const bf16x8*)(&Al[slot]);
      }
#pragma unroll
      for (int nf = 0; nf < 2; ++nf) {
        int pl = wv_px * 32 + nf * 16 + l15;
        if (kx == 1) {
          int slot = ((ky * 64 + pl) * 4 + (l4 ^ swz3(pl))) * 8;
          bhf[nf] = *(const bf16x8*)(&Xeh[slot]);
          blf[nf] = *(const bf16x8*)(&Xel[slot]);
        } else {
          int idx = (kx == 0) ? pl : (pl + 1);
          int slot = ((ky * 68 + idx) * 4 + (l4 ^ swz3(idx))) * 8;
          bhf[nf] = *(const bf16x8*)(&Xoh[slot]);
          blf[nf] = *(const bf16x8*)(&Xol[slot]);
        }
      }
#pragma unroll
      for (int m = 0; m < 4; ++m)
#pragma unroll
        for (int nf = 0; nf < 2; ++nf) {
          acc[m][nf] = __builtin_amdgcn_mfma_f32_16x16x32_bf16(
              ahf[m], bhf[nf], acc[m][nf], 0, 0, 0);
          acc[m][nf] = __builtin_amdgcn_mfma_f32_16x16x32_bf16(
              ahf[m], blf[nf], acc[m][nf], 0, 0, 0);
          acc[m][nf] = __builtin_amdgcn_mfma_f32_16x16x32_bf16(
              alf[m], bhf[nf], acc[m][nf], 0, 0, 0);
        }
      __syncthreads();  // protect Ah/Al (next tap) and X* (next chunk)
    }
  }
  // ---- epilogue: bias + store raw (Tout) ----
#pragma unroll
  for (int m = 0; m < 4; ++m) {
#pragma unroll
    for (int reg = 0; reg < 4; ++reg) {
      int co = cog * 128 + wv_co * 64 + m * 16 + l4 * 4 + reg;
      float bv = bias[co];
#pragma unroll
      for (int nf = 0; nf < 2; ++nf) {
        int px = pxbase + wv_px * 32 + nf * 16 + l15;
        stv(y, ((size_t)(n * Cotot + co) * Ho + r) * Wo + px,
            acc[m][nf][reg] + bv);
      }
    }
  }
}

// ---------------- ConvTranspose2d k3 s2 p1 op1 via MFMA bf16 ----------------
template <int MF, typename Tin>
__global__ __launch_bounds__(256) void convt3x3_mfma(
    const Tin* __restrict__ x, const unsigned short* __restrict__ wc,
    const float* __restrict__ bias, bf16* __restrict__ y, int Ci, int Hi,
    int Wi) {
  const int Co = MF * 32;
  int Ho = Hi * 2, Wo = Wi * 2;
  int r = blockIdx.x;        // input row
  int c0 = blockIdx.y * 64;  // input col base
  int n = blockIdx.z;
  int tid = threadIdx.x;
  int wv = tid >> 6, lane = tid & 63;
  int wv_co = wv >> 1, wv_px = wv & 1;
  int l15 = lane & 15, l4 = lane >> 4;

  __shared__ __align__(16) unsigned short Xs[2 * 66 * 32];
  __shared__ __align__(16) unsigned short As[MF * 32 * 32 * 2];  // Co*32

  f32x4 acc[4][MF][2];
#pragma unroll
  for (int par = 0; par < 4; ++par)
#pragma unroll
    for (int m = 0; m < MF; ++m)
#pragma unroll
      for (int nf = 0; nf < 2; ++nf)
        acc[par][m][nf] = (f32x4){0.f, 0.f, 0.f, 0.f};

  const Tin* xb = x + (size_t)n * Ci * Hi * Wi;
  int nchunk = Ci >> 5;
  for (int cb = 0; cb < nchunk; ++cb) {
    int ci0 = cb * 32;
    for (int t = tid; t < 520; t += 256) {
      int q = t & 3;
      int cr = t >> 2;    // 0..129
      int col = cr % 65;  // 0..64
      int row = cr / 65;  // 0..1
      int gr = r + row;
      int gc = c0 + col;
      uint4 pk = {0, 0, 0, 0};
      if (gr < Hi && gc < Wi) {
        const Tin* xp = xb + ((size_t)(ci0 + q * 8) * Hi + gr) * Wi + gc;
        unsigned short v[8];
#pragma unroll
        for (int e = 0; e < 8; ++e) v[e] = xbits(xp[(size_t)e * Hi * Wi]);
        pk.x = (unsigned)v[0] | ((unsigned)v[1] << 16);
        pk.y = (unsigned)v[2] | ((unsigned)v[3] << 16);
        pk.z = (unsigned)v[4] | ((unsigned)v[5] << 16);
        pk.w = (unsigned)v[6] | ((unsigned)v[7] << 16);
      }
      int slot = ((row * 66 + col) * 4 + (q ^ swz3(col))) * 8;
      *(uint4*)(&Xs[slot]) = pk;
    }
#pragma unroll
    for (int tap = 0; tap < 9; ++tap) {
      const int ky = tap / 3, kx = tap % 3;
      const int par = ((ky != 1) ? 2 : 0) + ((kx != 1) ? 1 : 0);
      const int trow = (ky == 0) ? 1 : 0;
      const int tcol = (kx == 0) ? 1 : 0;
      for (int t = tid; t < Co * 4; t += 256) {
        int q = t & 3;
        int co = t >> 2;
        uint4 pk =
            *(const uint4*)(wc + ((size_t)tap * Co + co) * Ci + ci0 + q * 8);
        int slot = (co * 4 + (q ^ swz3(co))) * 8;
        *(uint4*)(&As[slot]) = pk;
      }
      __syncthreads();
      bf16x8 af[MF], bfr[2];
#pragma unroll
      for (int m = 0; m < MF; ++m) {
        int co = wv_co * (MF * 16) + m * 16 + l15;
        int slot = (co * 4 + (l4 ^ swz3(co))) * 8;
        af[m] = *(const bf16x8*)(&As[slot]);
      }
#pragma unroll
      for (int nf = 0; nf < 2; ++nf) {
        int lc = wv_px * 32 + nf * 16 + l15 + tcol;
        int slot = ((trow * 66 + lc) * 4 + (l4 ^ swz3(lc))) * 8;
        bfr[nf] = *(const bf16x8*)(&Xs[slot]);
      }
#pragma unroll
      for (int m = 0; m < MF; ++m)
#pragma unroll
        for (int nf = 0; nf < 2; ++nf)
          acc[par][m][nf] = __builtin_amdgcn_mfma_f32_16x16x32_bf16(
              af[m], bfr[nf], acc[par][m][nf], 0, 0, 0);
      __syncthreads();
    }
  }
#pragma unroll
  for (int par = 0; par < 4; ++par) {
    int py = par >> 1, pxp = par & 1;
    int orow = 2 * r + py;
#pragma unroll
    for (int m = 0; m < MF; ++m) {
#pragma unroll
      for (int reg = 0; reg < 4; ++reg) {
        int co = wv_co * (MF * 16) + m * 16 + l4 * 4 + reg;
        float bv = bias[co];
        bf16* yr = y + ((size_t)(n * Co + co) * Ho + orow) * Wo + pxp;
#pragma unroll
        for (int nf = 0; nf < 2; ++nf) {
          int px_in = c0 + wv_px * 32 + nf * 16 + l15;
          yr[2 * px_in] = f2b(acc[par][m][nf][reg] + bv);
        }
      }
    }
  }
}

// ---------------- e1: 7x7 conv p3, CI=3, LDS-tiled (1 ci slice at a time) ---
__global__ __launch_bounds__(256) void conv7_e1(
    const float* __restrict__ x, const float* __restrict__ w,
    const float* __restrict__ bias, float* __restrict__ stats,
    f16* __restrict__ y) {
  const int H = 512, W = 512;
  __shared__ float Xs[5200];         // [10][520] one ci, zero-padded halo
  __shared__ float wsh[8 * 3 * 49];  // 8 co slab
  __shared__ float sred[4][8], qred[4][8];
  int cog = blockIdx.y;  // 8 groups x 8 co
  int n = blockIdx.z;
  int tid = threadIdx.x;
  int r0 = blockIdx.x * 4;
  int tr = tid >> 6;
  int lane = tid & 63;
  for (int t = tid; t < 1176; t += 256) wsh[t] = w[cog * 1176 + t];
  const float* xb = x + (size_t)n * 3 * H * W;
  float acc[8][8];
#pragma unroll
  for (int j = 0; j < 8; ++j) {
#pragma unroll
    for (int p = 0; p < 8; ++p) acc[j][p] = 0.f;
  }
  for (int ci = 0; ci < 3; ++ci) {
    __syncthreads();  // protect Xs from prev readers; orders wsh on 1st iter
    for (int t = tid; t < 5200; t += 256) {
      int row = t / 520;
      int col = t - row * 520;
      int gr = r0 - 3 + row;
      int gc = col - 3;
      float v = 0.f;
      if (gr >= 0 && gr < H && gc >= 0 && gc < W)
        v = xb[((size_t)ci * H + gr) * W + gc];
      Xs[t] = v;
    }
    __syncthreads();
    for (int i = 0; i < 7; ++i) {
      const float* xr = &Xs[(tr + i) * 520 + lane];
      float v[8][7];
#pragma unroll
      for (int p = 0; p < 8; ++p)
#pragma unroll
        for (int k = 0; k < 7; ++k) v[p][k] = xr[p * 64 + k];
#pragma unroll
      for (int j = 0; j < 8; ++j) {
        const float* wr = &wsh[(j * 3 + ci) * 49 + i * 7];
        float w0 = wr[0], w1 = wr[1], w2 = wr[2], w3 = wr[3], w4 = wr[4],
              w5 = wr[5], w6 = wr[6];
#pragma unroll
        for (int p = 0; p < 8; ++p)
          acc[j][p] += v[p][0] * w0 + v[p][1] * w1 + v[p][2] * w2 +
                       v[p][3] * w3 + v[p][4] * w4 + v[p][5] * w5 +
                       v[p][6] * w6;
      }
    }
  }
  int r = r0 + tr;
#pragma unroll
  for (int j = 0; j < 8; ++j) {
    int co = cog * 8 + j;
    float bv = bias[co];
    f16* yr = y + ((size_t)(n * 64 + co) * H + r) * W + lane;
    float s = 0.f, q = 0.f;
#pragma unroll
    for (int p = 0; p < 8; ++p) {
      float o = acc[j][p] + bv;
      yr[p * 64] = __float2half(o);
      s += o;
      q += o * o;
    }
#pragma unroll
    for (int off = 32; off > 0; off >>= 1) {
      s += __shfl_down(s, off, 64);
      q += __shfl_down(q, off, 64);
    }
    if (lane == 0) {
      sred[tr][j] = s;
      qred[tr][j] = q;
    }
  }
  __syncthreads();
  if (tid < 8) {
    float S = sred[0][tid] + sred[1][tid] + sred[2][tid] + sred[3][tid];
    float Q = qred[0][tid] + qred[1][tid] + qred[2][tid] + qred[3][tid];
    atomicAdd(&stats[n * 64 + cog * 8 + tid], S);
    atomicAdd(&stats[1024 + n * 64 + cog * 8 + tid], Q);
  }
}

// ---------------- head: 7x7 conv via MFMA bf16, Ci=64, Co=3 (M padded 16) ---
__global__ __launch_bounds__(256) void conv7_head_mfma(
    const bf16* __restrict__ xin, const float* __restrict__ w,
    const float* __restrict__ bias, float* __restrict__ y) {
  const int H = 512, W = 512;
  __shared__ __align__(16) unsigned short Xs[10 * 264 * 8];
  __shared__ __align__(16) unsigned short wlds[7 * 16 * 64];
  int n = blockIdx.z;
  int cbase = blockIdx.y * 256;
  int r0 = blockIdx.x * 4;
  int tid = threadIdx.x;
  int wv = tid >> 6;  // wave = output row
  int lane = tid & 63;
  int l15 = lane & 15, l4 = lane >> 4;
  const unsigned short* xb =
      (const unsigned short*)xin + (size_t)n * 64 * H * W;
  f32x4 acc[16];
#pragma unroll
  for (int nf = 0; nf < 16; ++nf) acc[nf] = (f32x4){0.f, 0.f, 0.f, 0.f};
  for (int ch = 0; ch < 8; ++ch) {
    __syncthreads();  // protect Xs/wlds from previous chunk's readers
    for (int t = tid; t < 2640; t += 256) {
      int row = t / 264;
      int col = t - row * 264;
      int gr = r0 - 3 + row;
      int gc = cbase - 3 + col;
      uint4 pk = {0, 0, 0, 0};
      if (gr >= 0 && gr < H && gc >= 0 && gc < W) {
        const unsigned short* xp =
            xb + ((size_t)(ch * 8) * H + gr) * W + gc;
        unsigned short v[8];
#pragma unroll
        for (int e = 0; e < 8; ++e) v[e] = xp[(size_t)e * H * W];
        pk.x = (unsigned)v[0] | ((unsigned)v[1] << 16);
        pk.y = (unsigned)v[2] | ((unsigned)v[3] << 16);
        pk.z = (unsigned)v[4] | ((unsigned)v[5] << 16);
        pk.w = (unsigned)v[6] | ((unsigned)v[7] << 16);
      }
      *(uint4*)(&Xs[t * 8]) = pk;
    }
    for (int t = tid; t < 7168; t += 256) {
      int k64 = t & 63;
      int co = (t >> 6) & 15;
      int ky = t >> 10;
      int kx = k64 >> 3;
      int cie = k64 & 7;
      unsigned short val = 0;
      if (co < 3 && kx < 7)
        val = f2bu(w[((size_t)(co * 64 + ch * 8 + cie) * 7 + ky) * 7 + kx]);
      wlds[t] = val;
    }
    __syncthreads();
#pragma unroll 1
    for (int ky = 0; ky < 7; ++ky) {
      bf16x8 af0 = *(const bf16x8*)(&wlds[(ky * 16 + l15) * 64 + l4 * 8]);
      bf16x8 af1 =
          *(const bf16x8*)(&wlds[(ky * 16 + l15) * 64 + 32 + l4 * 8]);
      int xrow = wv + ky;
#pragma unroll
      for (int nf = 0; nf < 16; ++nf) {
        int col0 = nf * 16 + l15 + l4;  // kf=0: kx = l4
        bf16x8 b0 = *(const bf16x8*)(&Xs[(xrow * 264 + col0) * 8]);
        acc[nf] =
            __builtin_amdgcn_mfma_f32_16x16x32_bf16(af0, b0, acc[nf], 0, 0, 0);
        bf16x8 b1 = *(const bf16x8*)(&Xs[(xrow * 264 + col0 + 4) * 8]);
        acc[nf] =
            __builtin_amdgcn_mfma_f32_16x16x32_bf16(af1, b1, acc[nf], 0, 0, 0);
      }
    }
  }
  if (l4 == 0) {
    int r = r0 + wv;
#pragma unroll
    for (int nf = 0; nf < 16; ++nf) {
#pragma unroll
      for (int reg = 0; reg < 3; ++reg) {
        float o = tanhf(acc[nf][reg] + bias[reg]);
        y[((size_t)(n * 3 + reg) * H + r) * W + cbase + nf * 16 + l15] = o;
      }
    }
  }
}

// ---------------- 1x1 conv, tiled 4 px x 4 co, fp32 -------------------------
__global__ __launch_bounds__(256) void conv1x1_tile(
    const float* __restrict__ x, const float* __restrict__ w,
    const float* __restrict__ bias, float* __restrict__ y, int Ci, int HW) {
  int cog = blockIdx.y;
  int Co = gridDim.y * 4;
  int n = blockIdx.z;
  int p0 = (blockIdx.x * 256 + threadIdx.x) * 4;
  const float* xb = x + (size_t)n * Ci * HW + p0;
  float acc[4][4];
#pragma unroll
  for (int j = 0; j < 4; ++j) {
    float b = bias[cog * 4 + j];
#pragma unroll
    for (int p = 0; p < 4; ++p) acc[j][p] = b;
  }
  for (int ci = 0; ci < Ci; ++ci) {
    float4 xv = *(const float4*)(xb + (size_t)ci * HW);
#pragma unroll
    for (int j = 0; j < 4; ++j) {
      float wv = w[(size_t)(cog * 4 + j) * Ci + ci];
      acc[j][0] += xv.x * wv;
      acc[j][1] += xv.y * wv;
      acc[j][2] += xv.z * wv;
      acc[j][3] += xv.w * wv;
    }
  }
#pragma unroll
  for (int j = 0; j < 4; ++j) {
    float4 o = {acc[j][0], acc[j][1], acc[j][2], acc[j][3]};
    *(float4*)(y + (size_t)(n * Co + cog * 4 + j) * HW + p0) = o;
  }
}

// ---------------- per-(n,c) sum / sumsq reduction ---------------------------
template <typename Tin>
__global__ __launch_bounds__(256) void reduce_nc_kernel(
    const Tin* __restrict__ x, float* __restrict__ stats, int HW) {
  int b = blockIdx.x;
  const Tin* p = x + (size_t)b * HW;
  float s = 0.f, q = 0.f;
  for (int i = threadIdx.x; i < HW; i += 256) {
    float v = (float)p[i];
    s += v;
    q += v * v;
  }
  __shared__ float ss[256], qq[256];
  ss[threadIdx.x] = s;
  qq[threadIdx.x] = q;
  __syncthreads();
  for (int off = 128; off > 0; off >>= 1) {
    if (threadIdx.x < off) {
      ss[threadIdx.x] += ss[threadIdx.x + off];
      qq[threadIdx.x] += qq[threadIdx.x + off];
    }
    __syncthreads();
  }
  if (threadIdx.x == 0) {
    stats[b] = ss[0];
    stats[1024 + b] = qq[0];
  }
}

// ---------------- AdaLIN coefficients ---------------------------------------
__global__ void adalin_coef_kernel(float* __restrict__ stats,
                                   const float* __restrict__ rho,
                                   const float* __restrict__ gam,
                                   const float* __restrict__ bet, int N, int C,
                                   float invHW) {
  int i = blockIdx.x * blockDim.x + threadIdx.x;
  if (i >= N * C) return;
  int c = i % C;
  const float* sums = stats;
  const float* sqs = stats + 1024;
  float im = sums[i] * invHW;
  float iv = sqs[i] * invHW - im * im;
  float lsum = 0.f, lsq = 0.f;
  for (int n = 0; n < N; ++n) {
    lsum += sums[n * C + c];
    lsq += sqs[n * C + c];
  }
  float lm = lsum * invHW / N;
  float lv = lsq * invHW / N - lm * lm;
  float r = rho[c];
  float mean = r * im + (1.f - r) * lm;
  float var = fmaxf(r * iv + (1.f - r) * lv, 0.f);
  float sc = gam[c] / sqrtf(var + EPSN);
  stats[2048 + i] = sc;
  stats[3072 + i] = bet[c] - mean * sc;
}

// ---------------- InstanceNorm coefficients ---------------------------------
__global__ void inorm_coef_kernel(float* __restrict__ stats, int NC,
                                  float invHW) {
  int i = blockIdx.x * blockDim.x + threadIdx.x;
  if (i >= NC) return;
  float im = stats[i] * invHW;
  float iv = fmaxf(stats[1024 + i] * invHW - im * im, 0.f);
  float sc = 1.f / sqrtf(iv + EPSN);
  stats[2048 + i] = sc;
  stats[3072 + i] = -im * sc;
}

// ---------------- x = (relu?)(x*scale[nc] + shift[nc])  (in-place) ----------
template <typename T>
__global__ __launch_bounds__(256) void scale_shift_kernel(
    T* __restrict__ x, const float* __restrict__ stats, int HW, size_t total,
    int relu) {
  size_t i = (size_t)blockIdx.x * 256 + threadIdx.x;
  if (i >= total) return;
  int nc = (int)(i / (size_t)HW);
  float v = (float)x[i] * stats[2048 + nc] + stats[3072 + nc];
  if (relu) v = fmaxf(v, 0.f);
  stv(x, i, v);
}

// ---------------- dst = relu(dst + a)  (fp32) -------------------------------
__global__ __launch_bounds__(256) void add_relu_kernel(
    float* __restrict__ dst, const float* __restrict__ a, size_t total) {
  size_t i = (size_t)blockIdx.x * 256 + threadIdx.x;
  if (i >= total) return;
  dst[i] = fmaxf(dst[i] + a[i], 0.f);
}

// ---------------- windowed attention (all fp32) -----------------------------
__global__ __launch_bounds__(256) void win_attn_kernel(
    const float* __restrict__ f, const float* __restrict__ g,
    const float* __restrict__ h, float* __restrict__ out) {
  const int H = 128;
  int j = blockIdx.x;
  int i = blockIdx.y;
  int b = blockIdx.z;
  __shared__ float fs[32 * 64];
  __shared__ float gs[32 * 64];
  __shared__ float att[16 * 64];
  int t = threadIdx.x;
  for (int idx = t; idx < 32 * 64; idx += 256) {
    int c = idx >> 6, k = idx & 63;
    int hr = i * 4 + (k >> 3), wc = j * 4 + (k & 7);
    float fv = 0.f, gv = 0.f;
    if (hr < H && wc < H) {
      size_t o = ((size_t)(b * 32 + c) * H + hr) * H + wc;
      fv = f[o];
      gv = g[o];
    }
    fs[idx] = fv;
    gs[idx] = gv;
  }
  __syncthreads();
  for (int idx = t; idx < 1024; idx += 256) {
    int q = idx >> 6, k = idx & 63;
    int qi = (q >> 2) * 8 + (q & 3);
    int hr = i * 4 + (k >> 3), wc = j * 4 + (k & 7);
    float s;
    if (hr < H && wc < H) {
      s = 0.f;
      for (int c = 0; c < 32; ++c) s += fs[c * 64 + qi] * gs[c * 64 + k];
    } else {
      s = -1e30f;
    }
    att[idx] = s;
  }
  __syncthreads();
  if (t < 16) {
    float m = -1e30f;
    for (int k = 0; k < 64; ++k) m = fmaxf(m, att[t * 64 + k]);
    float d = 0.f;
    for (int k = 0; k < 64; ++k) {
      float e = expf(att[t * 64 + k] - m);
      att[t * 64 + k] = e;
      d += e;
    }
    float inv = 1.f / d;
    for (int k = 0; k < 64; ++k) att[t * 64 + k] *= inv;
  }
  __syncthreads();
  int c = t;
  float accs[16];
  for (int q = 0; q < 16; ++q) accs[q] = 0.f;
  const float* hb = h + (size_t)(b * 256 + c) * H * H;
  for (int k = 0; k < 64; ++k) {
    int hr = i * 4 + (k >> 3), wc = j * 4 + (k & 7);
    if (hr >= H || wc >= H) continue;
    float hv = hb[hr * H + wc];
    for (int q = 0; q < 16; ++q) accs[q] += hv * att[q * 64 + k];
  }
  for (int q = 0; q < 16; ++q) {
    int oh = i * 4 + (q >> 2), ow = j * 4 + (q & 3);
    out[((size_t)(b * 256 + c) * H + oh) * H + ow] = accs[q];
  }
}

// ============================================================================
extern "C" void kernel_launch(void* const* d_in, const int* in_sizes, int n_in,
                              void* d_out, int out_size, void* d_ws,
                              size_t ws_size, hipStream_t stream) {
  const float* x = (const float*)d_in[0];
  const float* w_e1 = (const float*)d_in[1];
  const float* b_e1 = (const float*)d_in[2];
  const float* rho1 = (const float*)d_in[3];
  const float* gam1 = (const float*)d_in[4];
  const float* bet1 = (const float*)d_in[5];
  const float* w_e2 = (const float*)d_in[6];
  const float* b_e2 = (const float*)d_in[7];
  const float* rho2 = (const float*)d_in[8];
  const float* gam2 = (const float*)d_in[9];
  const float* bet2 = (const float*)d_in[10];
  const float* w_e3 = (const float*)d_in[11];
  const float* b_e3 = (const float*)d_in[12];
  const float* rho3 = (const float*)d_in[13];
  const float* gam3 = (const float*)d_in[14];
  const float* bet3 = (const float*)d_in[15];
  const float* rw1 = (const float*)d_in[16];
  const float* rb1 = (const float*)d_in[17];
  const float* rw2 = (const float*)d_in[18];
  const float* rb2 = (const float*)d_in[19];
  const float* w_f = (const float*)d_in[20];
  const float* b_f = (const float*)d_in[21];
  const float* w_g = (const float*)d_in[22];
  const float* b_g = (const float*)d_in[23];
  const float* w_h = (const float*)d_in[24];
  const float* b_h = (const float*)d_in[25];
  const float* w_d1 = (const float*)d_in[26];
  const float* b_d1 = (const float*)d_in[27];
  const float* rho4 = (const float*)d_in[28];
  const float* gam4 = (const float*)d_in[29];
  const float* bet4 = (const float*)d_in[30];
  const float* w_d2 = (const float*)d_in[31];
  const float* b_d2 = (const float*)d_in[32];
  const float* rho5 = (const float*)d_in[33];
  const float* gam5 = (const float*)d_in[34];
  const float* bet5 = (const float*)d_in[35];
  const float* w_d3 = (const float*)d_in[36];
  const float* b_d3 = (const float*)d_in[37];

  // ws layout (192 MiB):
  // E1H f16 raw e1 [0,128MiB) (dead after e2)
  // B2H f16 raw e2 [128,192) (dead after e3; later Bb2 bf16 d1 out)
  // Cc fp32 [0,64), D fp32 [64,128), E fp32 [128,192) (residual stage)
  // F1/F2 fp32 [64,80) (attention f/g); A2 bf16 [0,128) (d2 out)
  char* wsb = (char*)d_ws;
  f16* E1H = (f16*)wsb;
  float* Cc = (float*)wsb;
  float* D = (float*)(wsb + 67108864);
  float* E = (float*)(wsb + 134217728);
  float* F1 = (float*)(wsb + 67108864);
  float* F2 = (float*)(wsb + 75497472);
  f16* B2H = (f16*)(wsb + 134217728);
  bf16* Bb2 = (bf16*)(wsb + 134217728);
  bf16* A2 = (bf16*)wsb;

  float* out_img = (float*)d_out;
  float* out_attn = out_img + 3145728;
  // 16 KiB stats scratch at head of img region; fully overwritten by head conv
  float* stats = (float*)d_out;
  // bf16 hi+lo residual weights scratch in the (not yet written) out_attn
  // region; fully consumed before win_attn_kernel writes out_attn.
  unsigned short* wbres = (unsigned short*)((char*)d_out + 12582912);
  // convT + s2-conv bf16 weights in out_img scratch (1-5.2 MiB); consumed
  // before conv7_head_mfma overwrites out_img.
  unsigned short* wd1c = (unsigned short*)((char*)d_out + 1048576);
  unsigned short* wd2c = (unsigned short*)((char*)d_out + 2097152);
  unsigned short* we2c = (unsigned short*)((char*)d_out + 3145728);
  unsigned short* we3c = (unsigned short*)((char*)d_out + 4194304);

  dim3 blk(256);

  // ---- weight conversions (once) ----
  convert_w_kernel<<<18432, blk, 0, stream>>>(rw1, rw2, wbres);
  convert_wd_kernel<<<1152, blk, 0, stream>>>(w_d1, wd1c, 256, 128);
  convert_wd_kernel<<<288, blk, 0, stream>>>(w_d2, wd2c, 128, 64);
  convert_ws2_kernel<<<288, blk, 0, stream>>>(w_e2, we2c, 64, 128);
  convert_ws2_kernel<<<1152, blk, 0, stream>>>(w_e3, we3c, 128, 256);

  // ---- e1: 7x7 conv (LDS-tiled) -> raw f16 + stats ----
  zero_stats_kernel<<<1, 256, 0, stream>>>(stats);
  conv7_e1<<<dim3(128, 8, 4), blk, 0, stream>>>(x, w_e1, b_e1, stats, E1H);
  adalin_coef_kernel<<<1, 256, 0, stream>>>(stats, rho1, gam1, bet1, 4, 64,
                                            1.f / 262144.f);
  // ---- e2: 3x3 s2 MFMA conv with fused e1-norm+relu -> raw f16 ----
  conv3x3s2_mfma<f16><<<dim3(256, 4, 4), blk, 0, stream>>>(
      E1H, we2c, we2c + 73728, b_e2, stats, B2H, 64, 512, 512, 128);
  reduce_nc_kernel<f16><<<512, blk, 0, stream>>>(B2H, stats, 65536);
  adalin_coef_kernel<<<2, 256, 0, stream>>>(stats, rho2, gam2, bet2, 4, 128,
                                            1.f / 65536.f);
  // ---- e3: 3x3 s2 MFMA conv with fused e2-norm+relu -> fp32, then AdaLIN ---
  conv3x3s2_mfma<float><<<dim3(128, 4, 4), blk, 0, stream>>>(
      B2H, we3c, we3c + 294912, b_e3, stats, Cc, 128, 256, 256, 256);
  reduce_nc_kernel<float><<<1024, blk, 0, stream>>>(Cc, stats, 16384);
  adalin_coef_kernel<<<4, 256, 0, stream>>>(stats, rho3, gam3, bet3, 4, 256,
                                            1.f / 16384.f);
  scale_shift_kernel<float><<<65536, blk, 0, stream>>>(Cc, stats, 16384,
                                                       (size_t)16777216, 1);
  // ---- 4 residual blocks (bf16x3 MFMA convs) ----
  for (int r = 0; r < 4; ++r) {
    const float* rb1p = rb1 + (size_t)r * 256;
    const float* rb2p = rb2 + (size_t)r * 256;
    const unsigned short* w1h = wbres + (size_t)(r * 2) * 589824;
    const unsigned short* w1l = w1h + 4718592;
    const unsigned short* w2h = wbres + (size_t)(r * 2 + 1) * 589824;
    const unsigned short* w2l = w2h + 4718592;
    conv3x3s1_mfma<<<dim3(128, 2, 4), blk, 0, stream>>>(Cc, w1h, w1l, rb1p, D);
    reduce_nc_kernel<float><<<1024, blk, 0, stream>>>(D, stats, 16384);
    inorm_coef_kernel<<<4, 256, 0, stream>>>(stats, 1024, 1.f / 16384.f);
    scale_shift_kernel<float><<<65536, blk, 0, stream>>>(D, stats, 16384,
                                                         (size_t)16777216, 1);
    conv3x3s1_mfma<<<dim3(128, 2, 4), blk, 0, stream>>>(D, w2h, w2l, rb2p, E);
    reduce_nc_kernel<float><<<1024, blk, 0, stream>>>(E, stats, 16384);
    inorm_coef_kernel<<<4, 256, 0, stream>>>(stats, 1024, 1.f / 16384.f);
    scale_shift_kernel<float><<<65536, blk, 0, stream>>>(E, stats, 16384,
                                                         (size_t)16777216, 0);
    add_relu_kernel<<<65536, blk, 0, stream>>>(Cc, E, (size_t)16777216);
  }
  // ---- attention: 1x1 convs f/g/h + windowed attention ----
  conv1x1_tile<<<dim3(16, 8, 4), blk, 0, stream>>>(Cc, w_f, b_f, F1, 256,
                                                   16384);
  conv1x1_tile<<<dim3(16, 8, 4), blk, 0, stream>>>(Cc, w_g, b_g, F2, 256,
                                                   16384);
  conv1x1_tile<<<dim3(16, 64, 4), blk, 0, stream>>>(Cc, w_h, b_h, E, 256,
                                                    16384);
  win_attn_kernel<<<dim3(32, 32, 4), blk, 0, stream>>>(F1, F2, E, out_attn);
  // ---- d1: convT 256->128 via MFMA, AdaLIN, relu (bf16 out) ----
  convt3x3_mfma<4, float><<<dim3(128, 2, 4), blk, 0, stream>>>(
      Cc, wd1c, b_d1, Bb2, 256, 128, 128);
  reduce_nc_kernel<bf16><<<512, blk, 0, stream>>>(Bb2, stats, 65536);
  adalin_coef_kernel<<<2, 256, 0, stream>>>(stats, rho4, gam4, bet4, 4, 128,
                                            1.f / 65536.f);
  scale_shift_kernel<bf16><<<131072, blk, 0, stream>>>(Bb2, stats, 65536,
                                                       (size_t)33554432, 1);
  // ---- d2: convT 128->64 via MFMA, AdaLIN, relu (bf16) ----
  convt3x3_mfma<2, bf16><<<dim3(256, 4, 4), blk, 0, stream>>>(
      Bb2, wd2c, b_d2, A2, 128, 256, 256);
  reduce_nc_kernel<bf16><<<256, blk, 0, stream>>>(A2, stats, 262144);
  adalin_coef_kernel<<<1, 256, 0, stream>>>(stats, rho5, gam5, bet5, 4, 64,
                                            1.f / 262144.f);
  scale_shift_kernel<bf16><<<262144, blk, 0, stream>>>(A2, stats, 262144,
                                                       (size_t)67108864, 1);
  // ---- head: 7x7 conv via MFMA + tanh -> fp32 img ----
  conv7_head_mfma<<<dim3(128, 2, 4), blk, 0, stream>>>(A2, w_d3, b_d3,
                                                       out_img);
}

// Round 13
// 5316.719 us; speedup vs baseline: 1.9962x; 1.1237x over previous
//
#include <hip/hip_runtime.h>
#include <hip/hip_bf16.h>
#include <hip/hip_fp16.h>

#define EPSN 1e-5f

typedef __hip_bfloat16 bf16;
typedef __half f16;
typedef __attribute__((ext_vector_type(8))) short bf16x8;
typedef __attribute__((ext_vector_type(4))) float f32x4;

__device__ __forceinline__ float b2f(bf16 v) { return __bfloat162float(v); }
__device__ __forceinline__ bf16 f2b(float v) { return __float2bfloat16(v); }
__device__ __forceinline__ unsigned short f2bu(float v) {
  bf16 h = __float2bfloat16(v);
  return *reinterpret_cast<unsigned short*>(&h);
}
__device__ __forceinline__ float bu2f(unsigned short u) {
  unsigned int b = ((unsigned int)u) << 16;
  return __uint_as_float(b);
}
__device__ __forceinline__ unsigned short f2hu(float v) {
  f16 h = __float2half(v);
  return *reinterpret_cast<unsigned short*>(&h);
}
__device__ __forceinline__ float hu2f(unsigned short u) {
  f16 h = *reinterpret_cast<f16*>(&u);
  return __half2float(h);
}
__device__ __forceinline__ void stv(bf16* p, size_t i, float v) { p[i] = f2b(v); }
__device__ __forceinline__ void stv(float* p, size_t i, float v) { p[i] = v; }
__device__ __forceinline__ void stv(f16* p, size_t i, float v) {
  p[i] = __float2half(v);
}

// vec4 load/store helpers (fp32/bf16 storage, fp32 compute)
__device__ __forceinline__ float4 ld4(const float* p) { return *(const float4*)p; }
__device__ __forceinline__ float4 ld4(const bf16* p) {
  ushort4 u = *(const ushort4*)p;
  float4 r;
  r.x = bu2f(u.x);
  r.y = bu2f(u.y);
  r.z = bu2f(u.z);
  r.w = bu2f(u.w);
  return r;
}
__device__ __forceinline__ void st4(float* p, float4 v) { *(float4*)p = v; }
__device__ __forceinline__ void st4(bf16* p, float4 v) {
  uint2 o;
  o.x = (unsigned)f2bu(v.x) | ((unsigned)f2bu(v.y) << 16);
  o.y = (unsigned)f2bu(v.z) | ((unsigned)f2bu(v.w) << 16);
  *(uint2*)p = o;
}

// ---------------- zero the stats scratch (atomicAdd target) -----------------
__global__ void zero_stats_kernel(float* __restrict__ stats) {
  for (int k = threadIdx.x; k < 2048; k += 256) stats[k] = 0.f;
}

// ---------------- copy stats coefs to a safe scratch (head self-race fix) ---
__global__ void copy_stats_kernel(const float* __restrict__ src,
                                  float* __restrict__ dst) {
  int i = blockIdx.x * 256 + threadIdx.x;
  if (i < 4096) dst[i] = src[i];
}

// ------- weight convert: [Co][Ci][3][3] fp32 -> [tap][co][ci] bf16 hi+lo ----
__global__ __launch_bounds__(256) void convert_w_kernel(
    const float* __restrict__ rw1, const float* __restrict__ rw2,
    unsigned short* __restrict__ wb) {
  int i = blockIdx.x * 256 + threadIdx.x;  // < 8*9*65536 = 4718592
  if (i >= 4718592) return;
  int conv = i / 589824;
  int rem = i % 589824;
  int tap = rem / 65536;
  int cc = rem % 65536;  // co*256+ci
  const float* src = ((conv & 1) ? rw2 : rw1) + (size_t)(conv >> 1) * 589824;
  float v = src[(size_t)cc * 9 + tap];
  bf16 h = __float2bfloat16(v);
  float fh = __bfloat162float(h);
  wb[i] = *reinterpret_cast<unsigned short*>(&h);
  bf16 l = __float2bfloat16(v - fh);
  wb[4718592 + i] = *reinterpret_cast<unsigned short*>(&l);
}

// ------- convT weight convert: [Ci][Co][3][3] fp32 -> [tap][co][ci] bf16 ----
__global__ __launch_bounds__(256) void convert_wd_kernel(
    const float* __restrict__ w, unsigned short* __restrict__ out, int Ci,
    int Co) {
  int i = blockIdx.x * 256 + threadIdx.x;
  int total = 9 * Co * Ci;
  if (i >= total) return;
  int tap = i / (Co * Ci);
  int rem = i % (Co * Ci);
  int co = rem / Ci;
  int ci = rem % Ci;
  out[i] = f2bu(w[((size_t)ci * Co + co) * 9 + tap]);
}

// ------- s2-conv weight convert: [Co][Ci][3][3] fp32 -> [tap][co][ci] hi+lo -
__global__ __launch_bounds__(256) void convert_ws2_kernel(
    const float* __restrict__ w, unsigned short* __restrict__ out, int Ci,
    int Co) {
  int i = blockIdx.x * 256 + threadIdx.x;
  int total = 9 * Co * Ci;
  if (i >= total) return;
  int tap = i / (Co * Ci);
  int rem = i % (Co * Ci);
  int co = rem / Ci;
  int ci = rem % Ci;
  float v = w[((size_t)co * Ci + ci) * 9 + tap];
  bf16 h = __float2bfloat16(v);
  float fh = __bfloat162float(h);
  out[i] = *reinterpret_cast<unsigned short*>(&h);
  bf16 l = __float2bfloat16(v - fh);
  out[total + i] = *reinterpret_cast<unsigned short*>(&l);
}

// ---------------- 3x3 s1 p1 conv via MFMA (bf16x3), Ci=Co=256, H=W=128 ------
// NORM: input v = relu(x*sc[n,ci]+sh[n,ci]) applied fp32 during staging.
__device__ __forceinline__ int swz3(int idx) {
  return (idx & 3) ^ ((idx >> 2) & 1);
}

template <bool NORM>
__global__ __launch_bounds__(256) void conv3x3s1_mfma(
    const float* __restrict__ x, const unsigned short* __restrict__ wh,
    const unsigned short* __restrict__ wl, const float* __restrict__ bias,
    const float* __restrict__ stats, float* __restrict__ y) {
  const int H = 128, W = 128;
  int r = blockIdx.x;    // output row
  int cog = blockIdx.y;  // 0..1 (128 co each)
  int n = blockIdx.z;
  int tid = threadIdx.x;
  int wv = tid >> 6, lane = tid & 63;
  int wco = (wv >> 1) * 64, wpx = (wv & 1) * 64;
  int l15 = lane & 15, l4 = lane >> 4;

  __shared__ __align__(16) unsigned short Xh[3 * 130 * 32];
  __shared__ __align__(16) unsigned short Xl[3 * 130 * 32];
  __shared__ __align__(16) unsigned short Ah[128 * 32];
  __shared__ __align__(16) unsigned short Al[128 * 32];

  f32x4 acc[4][4];
#pragma unroll
  for (int m = 0; m < 4; ++m)
#pragma unroll
    for (int nf = 0; nf < 4; ++nf) acc[m][nf] = (f32x4){0.f, 0.f, 0.f, 0.f};

  const float* xn0 = x + (size_t)n * 256 * H * W;

  for (int cb = 0; cb < 8; ++cb) {
    int ci0 = cb * 32;
    {
      const float* xn = xn0 + (size_t)ci0 * H * W;
      for (int t = tid; t < 1560; t += 256) {
        int q = t & 3;
        int cr = t >> 2;     // 0..389
        int col = cr % 130;  // 0..129
        int row = cr / 130;  // 0..2
        int gr = r + row - 1;
        int gc = col - 1;
        bool ok = (gr >= 0) && (gr < H) && (gc >= 0) && (gc < W);
        uint4 ph = {0, 0, 0, 0};
        uint4 pl = {0, 0, 0, 0};
        if (ok) {
          const float* xp =
              xn + (size_t)(q * 8) * (H * W) + (size_t)gr * W + gc;
          const float* scp = stats + 2048 + n * 256 + ci0 + q * 8;
          const float* shp = stats + 3072 + n * 256 + ci0 + q * 8;
          unsigned short vh[8], vl[8];
#pragma unroll
          for (int e = 0; e < 8; ++e) {
            float v = xp[(size_t)e * H * W];
            if (NORM) v = fmaxf(fmaf(v, scp[e], shp[e]), 0.f);
            bf16 hb = __float2bfloat16(v);
            float fh = __bfloat162float(hb);
            bf16 lb = __float2bfloat16(v - fh);
            vh[e] = *reinterpret_cast<unsigned short*>(&hb);
            vl[e] = *reinterpret_cast<unsigned short*>(&lb);
          }
          ph.x = (unsigned)vh[0] | ((unsigned)vh[1] << 16);
          ph.y = (unsigned)vh[2] | ((unsigned)vh[3] << 16);
          ph.z = (unsigned)vh[4] | ((unsigned)vh[5] << 16);
          ph.w = (unsigned)vh[6] | ((unsigned)vh[7] << 16);
          pl.x = (unsigned)vl[0] | ((unsigned)vl[1] << 16);
          pl.y = (unsigned)vl[2] | ((unsigned)vl[3] << 16);
          pl.z = (unsigned)vl[4] | ((unsigned)vl[5] << 16);
          pl.w = (unsigned)vl[6] | ((unsigned)vl[7] << 16);
        }
        int slot = (cr * 4 + (q ^ swz3(col))) * 8;
        *(uint4*)(&Xh[slot]) = ph;
        *(uint4*)(&Xl[slot]) = pl;
      }
    }
    for (int tap = 0; tap < 9; ++tap) {
      for (int t = tid; t < 1024; t += 256) {
        int half = t >> 9;
        int rem = t & 511;
        int q = rem & 3;
        int co = rem >> 2;
        const unsigned short* wsrc =
            (half ? wl : wh) +
            ((size_t)tap * 256 + cog * 128 + co) * 256 + ci0 + q * 8;
        uint4 pk = *(const uint4*)wsrc;
        int slot = (co * 4 + (q ^ swz3(co))) * 8;
        *(uint4*)((half ? Al : Ah) + slot) = pk;
      }
      __syncthreads();
      int ky = tap / 3;
      int kx = tap - ky * 3;
      bf16x8 ahf[4], alf[4], bhf[4], blf[4];
#pragma unroll
      for (int m = 0; m < 4; ++m) {
        int co = wco + m * 16 + l15;
        int slot = (co * 4 + (l4 ^ swz3(co))) * 8;
        ahf[m] = *(const bf16x8*)(&Ah[slot]);
        alf[m] = *(const bf16x8*)(&Al[slot]);
      }
#pragma unroll
      for (int nf = 0; nf < 4; ++nf) {
        int col = wpx + nf * 16 + l15 + kx;  // lds col = px + kx
        int slot = ((ky * 130 + col) * 4 + (l4 ^ swz3(col))) * 8;
        bhf[nf] = *(const bf16x8*)(&Xh[slot]);
        blf[nf] = *(const bf16x8*)(&Xl[slot]);
      }
#pragma unroll
      for (int m = 0; m < 4; ++m)
#pragma unroll
        for (int nf = 0; nf < 4; ++nf) {
          acc[m][nf] = __builtin_amdgcn_mfma_f32_16x16x32_bf16(
              ahf[m], bhf[nf], acc[m][nf], 0, 0, 0);
          acc[m][nf] = __builtin_amdgcn_mfma_f32_16x16x32_bf16(
              ahf[m], blf[nf], acc[m][nf], 0, 0, 0);
          acc[m][nf] = __builtin_amdgcn_mfma_f32_16x16x32_bf16(
              alf[m], bhf[nf], acc[m][nf], 0, 0, 0);
        }
      __syncthreads();
    }
  }
#pragma unroll
  for (int m = 0; m < 4; ++m) {
    int cob = cog * 128 + wco + m * 16 + l4 * 4;
#pragma unroll
    for (int reg = 0; reg < 4; ++reg) {
      float bv = bias[cob + reg];
      float* yr =
          y + (((size_t)(n * 256 + cob + reg) * H) + r) * W + wpx + l15;
#pragma unroll
      for (int nf = 0; nf < 4; ++nf) yr[nf * 16] = acc[m][nf][reg] + bv;
    }
  }
}

// ---------------- 3x3 s2 p1 conv via MFMA (bf16x3), fused input norm --------
template <typename Tout>
__global__ __launch_bounds__(256) void conv3x3s2_mfma(
    const f16* __restrict__ x, const unsigned short* __restrict__ wch,
    const unsigned short* __restrict__ wcl, const float* __restrict__ bias,
    const float* __restrict__ stats, Tout* __restrict__ y, int Ci, int Hi,
    int Wi, int Cotot) {
  int Ho = Hi >> 1, Wo = Wi >> 1;
  int r = blockIdx.x;
  int npx = Wo >> 6;
  int pxg = blockIdx.y % npx;
  int cog = blockIdx.y / npx;
  int n = blockIdx.z;
  int tid = threadIdx.x;
  int wv = tid >> 6, lane = tid & 63;
  int wv_co = wv >> 1, wv_px = wv & 1;
  int l15 = lane & 15, l4 = lane >> 4;
  int pxbase = pxg * 64;

  __shared__ __align__(16) unsigned short Xeh[3 * 64 * 32];
  __shared__ __align__(16) unsigned short Xel[3 * 64 * 32];
  __shared__ __align__(16) unsigned short Xoh[3 * 68 * 32];
  __shared__ __align__(16) unsigned short Xol[3 * 68 * 32];
  __shared__ __align__(16) unsigned short Ah[128 * 32];
  __shared__ __align__(16) unsigned short Al[128 * 32];

  f32x4 acc[4][2];
#pragma unroll
  for (int m = 0; m < 4; ++m)
#pragma unroll
    for (int nf = 0; nf < 2; ++nf) acc[m][nf] = (f32x4){0.f, 0.f, 0.f, 0.f};

  const f16* xb = x + (size_t)n * Ci * Hi * Wi;
  int nchunk = Ci >> 5;
  for (int cb = 0; cb < nchunk; ++cb) {
    int ci0 = cb * 32;
    for (int t = tid; t < 1548; t += 256) {
      bool isodd = t >= 768;
      int tt = isodd ? (t - 768) : t;
      int q = tt & 3;
      int cr = tt >> 2;
      int i, idx;
      if (!isodd) {
        i = cr >> 6;
        idx = cr & 63;
      } else {
        i = cr / 65;
        idx = cr % 65;
      }
      int gr = 2 * r - 1 + i;
      int gc = isodd ? (2 * pxbase + 2 * idx - 1) : (2 * (pxbase + idx));
      uint4 ph = {0, 0, 0, 0};
      uint4 pl4 = {0, 0, 0, 0};
      if (gr >= 0 && gr < Hi && gc >= 0 && gc < Wi) {
        const f16* xp = xb + ((size_t)(ci0 + q * 8) * Hi + gr) * Wi + gc;
        const float* scp = stats + 2048 + n * Ci + ci0 + q * 8;
        const float* shp = stats + 3072 + n * Ci + ci0 + q * 8;
        unsigned short vh[8], vl[8];
#pragma unroll
        for (int e = 0; e < 8; ++e) {
          float raw = (float)xp[(size_t)e * Hi * Wi];
          float v = fmaxf(fmaf(raw, scp[e], shp[e]), 0.f);
          bf16 hb = __float2bfloat16(v);
          float fh = __bfloat162float(hb);
          bf16 lb = __float2bfloat16(v - fh);
          vh[e] = *reinterpret_cast<unsigned short*>(&hb);
          vl[e] = *reinterpret_cast<unsigned short*>(&lb);
        }
        ph.x = (unsigned)vh[0] | ((unsigned)vh[1] << 16);
        ph.y = (unsigned)vh[2] | ((unsigned)vh[3] << 16);
        ph.z = (unsigned)vh[4] | ((unsigned)vh[5] << 16);
        ph.w = (unsigned)vh[6] | ((unsigned)vh[7] << 16);
        pl4.x = (unsigned)vl[0] | ((unsigned)vl[1] << 16);
        pl4.y = (unsigned)vl[2] | ((unsigned)vl[3] << 16);
        pl4.z = (unsigned)vl[4] | ((unsigned)vl[5] << 16);
        pl4.w = (unsigned)vl[6] | ((unsigned)vl[7] << 16);
      }
      int stride = isodd ? 68 : 64;
      int slot = ((i * stride + idx) * 4 + (q ^ swz3(idx))) * 8;
      if (isodd) {
        *(uint4*)(&Xoh[slot]) = ph;
        *(uint4*)(&Xol[slot]) = pl4;
      } else {
        *(uint4*)(&Xeh[slot]) = ph;
        *(uint4*)(&Xel[slot]) = pl4;
      }
    }
#pragma unroll
    for (int tap = 0; tap < 9; ++tap) {
      const int ky = tap / 3, kx = tap % 3;
      for (int t = tid; t < 1024; t += 256) {
        int half = t >> 9;
        int rem = t & 511;
        int q = rem & 3;
        int co = rem >> 2;
        const unsigned short* wsrc =
            (half ? wcl : wch) +
            ((size_t)tap * Cotot + cog * 128 + co) * Ci + ci0 + q * 8;
        uint4 pk = *(const uint4*)wsrc;
        int slot = (co * 4 + (q ^ swz3(co))) * 8;
        *(uint4*)((half ? Al : Ah) + slot) = pk;
      }
      __syncthreads();
      bf16x8 ahf[4], alf[4], bhf[2], blf[2];
#pragma unroll
      for (int m = 0; m < 4; ++m) {
        int co = wv_co * 64 + m * 16 + l15;
        int slot = (co * 4 + (l4 ^ swz3(co))) * 8;
        ahf[m] = *(const bf16x8*)(&Ah[slot]);
        alf[m] = *(const bf16x8*)(&Al[slot]);
      }
#pragma unroll
      for (int nf = 0; nf < 2; ++nf) {
        int pl = wv_px * 32 + nf * 16 + l15;
        if (kx == 1) {
          int slot = ((ky * 64 + pl) * 4 + (l4 ^ swz3(pl))) * 8;
          bhf[nf] = *(const bf16x8*)(&Xeh[slot]);
          blf[nf] = *(const bf16x8*)(&Xel[slot]);
        } else {
          int idx = (kx == 0) ? pl : (pl + 1);
          int slot = ((ky * 68 + idx) * 4 + (l4 ^ swz3(idx))) * 8;
          bhf[nf] = *(const bf16x8*)(&Xoh[slot]);
          blf[nf] = *(const bf16x8*)(&Xol[slot]);
        }
      }
#pragma unroll
      for (int m = 0; m < 4; ++m)
#pragma unroll
        for (int nf = 0; nf < 2; ++nf) {
          acc[m][nf] = __builtin_amdgcn_mfma_f32_16x16x32_bf16(
              ahf[m], bhf[nf], acc[m][nf], 0, 0, 0);
          acc[m][nf] = __builtin_amdgcn_mfma_f32_16x16x32_bf16(
              ahf[m], blf[nf], acc[m][nf], 0, 0, 0);
          acc[m][nf] = __builtin_amdgcn_mfma_f32_16x16x32_bf16(
              alf[m], bhf[nf], acc[m][nf], 0, 0, 0);
        }
      __syncthreads();
    }
  }
#pragma unroll
  for (int m = 0; m < 4; ++m) {
#pragma unroll
    for (int reg = 0; reg < 4; ++reg) {
      int co = cog * 128 + wv_co * 64 + m * 16 + l4 * 4 + reg;
      float bv = bias[co];
#pragma unroll
      for (int nf = 0; nf < 2; ++nf) {
        int px = pxbase + wv_px * 32 + nf * 16 + l15;
        stv(y, ((size_t)(n * Cotot + co) * Ho + r) * Wo + px,
            acc[m][nf][reg] + bv);
      }
    }
  }
}

// ---------------- ConvTranspose2d k3 s2 p1 op1 via MFMA bf16 ----------------
// NORM: input v = relu(x*sc[n,ci]+sh[n,ci]) applied fp32 during staging.
template <int MF, typename Tin, bool NORM>
__global__ __launch_bounds__(256) void convt3x3_mfma(
    const Tin* __restrict__ x, const unsigned short* __restrict__ wc,
    const float* __restrict__ bias, const float* __restrict__ stats,
    bf16* __restrict__ y, int Ci, int Hi, int Wi) {
  const int Co = MF * 32;
  int Ho = Hi * 2, Wo = Wi * 2;
  int r = blockIdx.x;        // input row
  int c0 = blockIdx.y * 64;  // input col base
  int n = blockIdx.z;
  int tid = threadIdx.x;
  int wv = tid >> 6, lane = tid & 63;
  int wv_co = wv >> 1, wv_px = wv & 1;
  int l15 = lane & 15, l4 = lane >> 4;

  __shared__ __align__(16) unsigned short Xs[2 * 66 * 32];
  __shared__ __align__(16) unsigned short As[MF * 32 * 32 * 2];  // Co*32

  f32x4 acc[4][MF][2];
#pragma unroll
  for (int par = 0; par < 4; ++par)
#pragma unroll
    for (int m = 0; m < MF; ++m)
#pragma unroll
      for (int nf = 0; nf < 2; ++nf)
        acc[par][m][nf] = (f32x4){0.f, 0.f, 0.f, 0.f};

  const Tin* xb = x + (size_t)n * Ci * Hi * Wi;
  int nchunk = Ci >> 5;
  for (int cb = 0; cb < nchunk; ++cb) {
    int ci0 = cb * 32;
    for (int t = tid; t < 520; t += 256) {
      int q = t & 3;
      int cr = t >> 2;    // 0..129
      int col = cr % 65;  // 0..64
      int row = cr / 65;  // 0..1
      int gr = r + row;
      int gc = c0 + col;
      uint4 pk = {0, 0, 0, 0};
      if (gr < Hi && gc < Wi) {
        const Tin* xp = xb + ((size_t)(ci0 + q * 8) * Hi + gr) * Wi + gc;
        const float* scp = stats + 2048 + n * Ci + ci0 + q * 8;
        const float* shp = stats + 3072 + n * Ci + ci0 + q * 8;
        unsigned short v[8];
#pragma unroll
        for (int e = 0; e < 8; ++e) {
          float raw = (float)xp[(size_t)e * Hi * Wi];
          if (NORM) raw = fmaxf(fmaf(raw, scp[e], shp[e]), 0.f);
          v[e] = f2bu(raw);
        }
        pk.x = (unsigned)v[0] | ((unsigned)v[1] << 16);
        pk.y = (unsigned)v[2] | ((unsigned)v[3] << 16);
        pk.z = (unsigned)v[4] | ((unsigned)v[5] << 16);
        pk.w = (unsigned)v[6] | ((unsigned)v[7] << 16);
      }
      int slot = ((row * 66 + col) * 4 + (q ^ swz3(col))) * 8;
      *(uint4*)(&Xs[slot]) = pk;
    }
#pragma unroll
    for (int tap = 0; tap < 9; ++tap) {
      const int ky = tap / 3, kx = tap % 3;
      const int par = ((ky != 1) ? 2 : 0) + ((kx != 1) ? 1 : 0);
      const int trow = (ky == 0) ? 1 : 0;
      const int tcol = (kx == 0) ? 1 : 0;
      for (int t = tid; t < Co * 4; t += 256) {
        int q = t & 3;
        int co = t >> 2;
        uint4 pk =
            *(const uint4*)(wc + ((size_t)tap * Co + co) * Ci + ci0 + q * 8);
        int slot = (co * 4 + (q ^ swz3(co))) * 8;
        *(uint4*)(&As[slot]) = pk;
      }
      __syncthreads();
      bf16x8 af[MF], bfr[2];
#pragma unroll
      for (int m = 0; m < MF; ++m) {
        int co = wv_co * (MF * 16) + m * 16 + l15;
        int slot = (co * 4 + (l4 ^ swz3(co))) * 8;
        af[m] = *(const bf16x8*)(&As[slot]);
      }
#pragma unroll
      for (int nf = 0; nf < 2; ++nf) {
        int lc = wv_px * 32 + nf * 16 + l15 + tcol;
        int slot = ((trow * 66 + lc) * 4 + (l4 ^ swz3(lc))) * 8;
        bfr[nf] = *(const bf16x8*)(&Xs[slot]);
      }
#pragma unroll
      for (int m = 0; m < MF; ++m)
#pragma unroll
        for (int nf = 0; nf < 2; ++nf)
          acc[par][m][nf] = __builtin_amdgcn_mfma_f32_16x16x32_bf16(
              af[m], bfr[nf], acc[par][m][nf], 0, 0, 0);
      __syncthreads();
    }
  }
#pragma unroll
  for (int par = 0; par < 4; ++par) {
    int py = par >> 1, pxp = par & 1;
    int orow = 2 * r + py;
#pragma unroll
    for (int m = 0; m < MF; ++m) {
#pragma unroll
      for (int reg = 0; reg < 4; ++reg) {
        int co = wv_co * (MF * 16) + m * 16 + l4 * 4 + reg;
        float bv = bias[co];
        bf16* yr = y + ((size_t)(n * Co + co) * Ho + orow) * Wo + pxp;
#pragma unroll
        for (int nf = 0; nf < 2; ++nf) {
          int px_in = c0 + wv_px * 32 + nf * 16 + l15;
          yr[2 * px_in] = f2b(acc[par][m][nf][reg] + bv);
        }
      }
    }
  }
}

// ---------------- e1: 7x7 conv p3, CI=3, LDS-tiled (1 ci slice at a time) ---
__global__ __launch_bounds__(256) void conv7_e1(
    const float* __restrict__ x, const float* __restrict__ w,
    const float* __restrict__ bias, float* __restrict__ stats,
    f16* __restrict__ y) {
  const int H = 512, W = 512;
  __shared__ float Xs[5200];         // [10][520] one ci, zero-padded halo
  __shared__ float wsh[8 * 3 * 49];  // 8 co slab
  __shared__ float sred[4][8], qred[4][8];
  int cog = blockIdx.y;  // 8 groups x 8 co
  int n = blockIdx.z;
  int tid = threadIdx.x;
  int r0 = blockIdx.x * 4;
  int tr = tid >> 6;
  int lane = tid & 63;
  for (int t = tid; t < 1176; t += 256) wsh[t] = w[cog * 1176 + t];
  const float* xb = x + (size_t)n * 3 * H * W;
  float acc[8][8];
#pragma unroll
  for (int j = 0; j < 8; ++j) {
#pragma unroll
    for (int p = 0; p < 8; ++p) acc[j][p] = 0.f;
  }
  for (int ci = 0; ci < 3; ++ci) {
    __syncthreads();  // protect Xs from prev readers; orders wsh on 1st iter
    for (int t = tid; t < 5200; t += 256) {
      int row = t / 520;
      int col = t - row * 520;
      int gr = r0 - 3 + row;
      int gc = col - 3;
      float v = 0.f;
      if (gr >= 0 && gr < H && gc >= 0 && gc < W)
        v = xb[((size_t)ci * H + gr) * W + gc];
      Xs[t] = v;
    }
    __syncthreads();
    for (int i = 0; i < 7; ++i) {
      const float* xr = &Xs[(tr + i) * 520 + lane];
      float v[8][7];
#pragma unroll
      for (int p = 0; p < 8; ++p)
#pragma unroll
        for (int k = 0; k < 7; ++k) v[p][k] = xr[p * 64 + k];
#pragma unroll
      for (int j = 0; j < 8; ++j) {
        const float* wr = &wsh[(j * 3 + ci) * 49 + i * 7];
        float w0 = wr[0], w1 = wr[1], w2 = wr[2], w3 = wr[3], w4 = wr[4],
              w5 = wr[5], w6 = wr[6];
#pragma unroll
        for (int p = 0; p < 8; ++p)
          acc[j][p] += v[p][0] * w0 + v[p][1] * w1 + v[p][2] * w2 +
                       v[p][3] * w3 + v[p][4] * w4 + v[p][5] * w5 +
                       v[p][6] * w6;
      }
    }
  }
  int r = r0 + tr;
#pragma unroll
  for (int j = 0; j < 8; ++j) {
    int co = cog * 8 + j;
    float bv = bias[co];
    f16* yr = y + ((size_t)(n * 64 + co) * H + r) * W + lane;
    float s = 0.f, q = 0.f;
#pragma unroll
    for (int p = 0; p < 8; ++p) {
      float o = acc[j][p] + bv;
      yr[p * 64] = __float2half(o);
      s += o;
      q += o * o;
    }
#pragma unroll
    for (int off = 32; off > 0; off >>= 1) {
      s += __shfl_down(s, off, 64);
      q += __shfl_down(q, off, 64);
    }
    if (lane == 0) {
      sred[tr][j] = s;
      qred[tr][j] = q;
    }
  }
  __syncthreads();
  if (tid < 8) {
    float S = sred[0][tid] + sred[1][tid] + sred[2][tid] + sred[3][tid];
    float Q = qred[0][tid] + qred[1][tid] + qred[2][tid] + qred[3][tid];
    atomicAdd(&stats[n * 64 + cog * 8 + tid], S);
    atomicAdd(&stats[1024 + n * 64 + cog * 8 + tid], Q);
  }
}

// ---------------- head: 7x7 conv via MFMA bf16 + fused d2-norm + tanh -------
__global__ __launch_bounds__(256) void conv7_head_mfma(
    const bf16* __restrict__ xin, const float* __restrict__ w,
    const float* __restrict__ bias, const float* __restrict__ stats,
    float* __restrict__ y) {
  const int H = 512, W = 512;
  __shared__ __align__(16) unsigned short Xs[10 * 264 * 8];
  __shared__ __align__(16) unsigned short wlds[7 * 16 * 64];
  int n = blockIdx.z;
  int cbase = blockIdx.y * 256;
  int r0 = blockIdx.x * 4;
  int tid = threadIdx.x;
  int wv = tid >> 6;  // wave = output row
  int lane = tid & 63;
  int l15 = lane & 15, l4 = lane >> 4;
  const unsigned short* xb =
      (const unsigned short*)xin + (size_t)n * 64 * H * W;
  f32x4 acc[16];
#pragma unroll
  for (int nf = 0; nf < 16; ++nf) acc[nf] = (f32x4){0.f, 0.f, 0.f, 0.f};
  for (int ch = 0; ch < 8; ++ch) {
    __syncthreads();  // protect Xs/wlds from previous chunk's readers
    for (int t = tid; t < 2640; t += 256) {
      int row = t / 264;
      int col = t - row * 264;
      int gr = r0 - 3 + row;
      int gc = cbase - 3 + col;
      uint4 pk = {0, 0, 0, 0};
      if (gr >= 0 && gr < H && gc >= 0 && gc < W) {
        const unsigned short* xp =
            xb + ((size_t)(ch * 8) * H + gr) * W + gc;
        const float* scp = stats + 2048 + n * 64 + ch * 8;
        const float* shp = stats + 3072 + n * 64 + ch * 8;
        unsigned short v[8];
#pragma unroll
        for (int e = 0; e < 8; ++e) {
          float raw = bu2f(xp[(size_t)e * H * W]);
          raw = fmaxf(fmaf(raw, scp[e], shp[e]), 0.f);
          v[e] = f2bu(raw);
        }
        pk.x = (unsigned)v[0] | ((unsigned)v[1] << 16);
        pk.y = (unsigned)v[2] | ((unsigned)v[3] << 16);
        pk.z = (unsigned)v[4] | ((unsigned)v[5] << 16);
        pk.w = (unsigned)v[6] | ((unsigned)v[7] << 16);
      }
      *(uint4*)(&Xs[t * 8]) = pk;
    }
    for (int t = tid; t < 7168; t += 256) {
      int k64 = t & 63;
      int co = (t >> 6) & 15;
      int ky = t >> 10;
      int kx = k64 >> 3;
      int cie = k64 & 7;
      unsigned short val = 0;
      if (co < 3 && kx < 7)
        val = f2bu(w[((size_t)(co * 64 + ch * 8 + cie) * 7 + ky) * 7 + kx]);
      wlds[t] = val;
    }
    __syncthreads();
#pragma unroll 1
    for (int ky = 0; ky < 7; ++ky) {
      bf16x8 af0 = *(const bf16x8*)(&wlds[(ky * 16 + l15) * 64 + l4 * 8]);
      bf16x8 af1 =
          *(const bf16x8*)(&wlds[(ky * 16 + l15) * 64 + 32 + l4 * 8]);
      int xrow = wv + ky;
#pragma unroll
      for (int nf = 0; nf < 16; ++nf) {
        int col0 = nf * 16 + l15 + l4;  // kf=0: kx = l4
        bf16x8 b0 = *(const bf16x8*)(&Xs[(xrow * 264 + col0) * 8]);
        acc[nf] =
            __builtin_amdgcn_mfma_f32_16x16x32_bf16(af0, b0, acc[nf], 0, 0, 0);
        bf16x8 b1 = *(const bf16x8*)(&Xs[(xrow * 264 + col0 + 4) * 8]);
        acc[nf] =
            __builtin_amdgcn_mfma_f32_16x16x32_bf16(af1, b1, acc[nf], 0, 0, 0);
      }
    }
  }
  if (l4 == 0) {
    int r = r0 + wv;
#pragma unroll
    for (int nf = 0; nf < 16; ++nf) {
#pragma unroll
      for (int reg = 0; reg < 3; ++reg) {
        float o = tanhf(acc[nf][reg] + bias[reg]);
        y[((size_t)(n * 3 + reg) * H + r) * W + cbase + nf * 16 + l15] = o;
      }
    }
  }
}

// ---------------- 1x1 conv, tiled 4 px x 4 co, fp32 -------------------------
__global__ __launch_bounds__(256) void conv1x1_tile(
    const float* __restrict__ x, const float* __restrict__ w,
    const float* __restrict__ bias, float* __restrict__ y, int Ci, int HW) {
  int cog = blockIdx.y;
  int Co = gridDim.y * 4;
  int n = blockIdx.z;
  int p0 = (blockIdx.x * 256 + threadIdx.x) * 4;
  const float* xb = x + (size_t)n * Ci * HW + p0;
  float acc[4][4];
#pragma unroll
  for (int j = 0; j < 4; ++j) {
    float b = bias[cog * 4 + j];
#pragma unroll
    for (int p = 0; p < 4; ++p) acc[j][p] = b;
  }
  for (int ci = 0; ci < Ci; ++ci) {
    float4 xv = *(const float4*)(xb + (size_t)ci * HW);
#pragma unroll
    for (int j = 0; j < 4; ++j) {
      float wv = w[(size_t)(cog * 4 + j) * Ci + ci];
      acc[j][0] += xv.x * wv;
      acc[j][1] += xv.y * wv;
      acc[j][2] += xv.z * wv;
      acc[j][3] += xv.w * wv;
    }
  }
#pragma unroll
  for (int j = 0; j < 4; ++j) {
    float4 o = {acc[j][0], acc[j][1], acc[j][2], acc[j][3]};
    *(float4*)(y + (size_t)(n * Co + cog * 4 + j) * HW + p0) = o;
  }
}

// ---------------- per-(n,c) sum / sumsq reduction (vectorized) --------------
template <typename Tin>
__global__ __launch_bounds__(256) void reduce_nc_kernel(
    const Tin* __restrict__ x, float* __restrict__ stats, int HW) {
  int b = blockIdx.x;
  const Tin* p = x + (size_t)b * HW;
  float s = 0.f, q = 0.f;
  if constexpr (sizeof(Tin) == 2) {
    const uint4* p8 = reinterpret_cast<const uint4*>(p);
    int n8 = HW >> 3;
    for (int i = threadIdx.x; i < n8; i += 256) {
      uint4 u = p8[i];
      unsigned int wds[4] = {u.x, u.y, u.z, u.w};
#pragma unroll
      for (int j = 0; j < 4; ++j) {
        unsigned short lo = (unsigned short)(wds[j] & 0xffff);
        unsigned short hi = (unsigned short)(wds[j] >> 16);
        Tin a = *reinterpret_cast<Tin*>(&lo);
        Tin c = *reinterpret_cast<Tin*>(&hi);
        float va = (float)a, vc = (float)c;
        s += va + vc;
        q += va * va + vc * vc;
      }
    }
  } else {
    const float4* p4 = reinterpret_cast<const float4*>(p);
    int n4 = HW >> 2;
    for (int i = threadIdx.x; i < n4; i += 256) {
      float4 v = p4[i];
      s += v.x + v.y + v.z + v.w;
      q += v.x * v.x + v.y * v.y + v.z * v.z + v.w * v.w;
    }
  }
  __shared__ float ss[256], qq[256];
  ss[threadIdx.x] = s;
  qq[threadIdx.x] = q;
  __syncthreads();
  for (int off = 128; off > 0; off >>= 1) {
    if (threadIdx.x < off) {
      ss[threadIdx.x] += ss[threadIdx.x + off];
      qq[threadIdx.x] += qq[threadIdx.x + off];
    }
    __syncthreads();
  }
  if (threadIdx.x == 0) {
    stats[b] = ss[0];
    stats[1024 + b] = qq[0];
  }
}

// ---------------- AdaLIN coefficients ---------------------------------------
__global__ void adalin_coef_kernel(float* __restrict__ stats,
                                   const float* __restrict__ rho,
                                   const float* __restrict__ gam,
                                   const float* __restrict__ bet, int N, int C,
                                   float invHW) {
  int i = blockIdx.x * blockDim.x + threadIdx.x;
  if (i >= N * C) return;
  int c = i % C;
  const float* sums = stats;
  const float* sqs = stats + 1024;
  float im = sums[i] * invHW;
  float iv = sqs[i] * invHW - im * im;
  float lsum = 0.f, lsq = 0.f;
  for (int n = 0; n < N; ++n) {
    lsum += sums[n * C + c];
    lsq += sqs[n * C + c];
  }
  float lm = lsum * invHW / N;
  float lv = lsq * invHW / N - lm * lm;
  float r = rho[c];
  float mean = r * im + (1.f - r) * lm;
  float var = fmaxf(r * iv + (1.f - r) * lv, 0.f);
  float sc = gam[c] / sqrtf(var + EPSN);
  stats[2048 + i] = sc;
  stats[3072 + i] = bet[c] - mean * sc;
}

// ---------------- InstanceNorm coefficients ---------------------------------
__global__ void inorm_coef_kernel(float* __restrict__ stats, int NC,
                                  float invHW) {
  int i = blockIdx.x * blockDim.x + threadIdx.x;
  if (i >= NC) return;
  float im = stats[i] * invHW;
  float iv = fmaxf(stats[1024 + i] * invHW - im * im, 0.f);
  float sc = 1.f / sqrtf(iv + EPSN);
  stats[2048 + i] = sc;
  stats[3072 + i] = -im * sc;
}

// ---------------- x = (relu?)(x*scale[nc] + shift[nc])  (in-place) ----------
template <typename T>
__global__ __launch_bounds__(256) void scale_shift_kernel(
    T* __restrict__ x, const float* __restrict__ stats, int HW, size_t total,
    int relu) {
  size_t i = (size_t)blockIdx.x * 256 + threadIdx.x;
  if (i >= total) return;
  int nc = (int)(i / (size_t)HW);
  float v = (float)x[i] * stats[2048 + nc] + stats[3072 + nc];
  if (relu) v = fmaxf(v, 0.f);
  stv(x, i, v);
}

// ---------------- dst = relu(dst + e*sc[nc]+sh[nc])  (fp32) -----------------
__global__ __launch_bounds__(256) void scale_add_relu_kernel(
    float* __restrict__ dst, const float* __restrict__ e,
    const float* __restrict__ stats, int HW, size_t total) {
  size_t i = (size_t)blockIdx.x * 256 + threadIdx.x;
  if (i >= total) return;
  int nc = (int)(i / (size_t)HW);
  float v = fmaf(e[i], stats[2048 + nc], stats[3072 + nc]);
  dst[i] = fmaxf(dst[i] + v, 0.f);
}

// ---------------- windowed attention (all fp32) -----------------------------
__global__ __launch_bounds__(256) void win_attn_kernel(
    const float* __restrict__ f, const float* __restrict__ g,
    const float* __restrict__ h, float* __restrict__ out) {
  const int H = 128;
  int j = blockIdx.x;
  int i = blockIdx.y;
  int b = blockIdx.z;
  __shared__ float fs[32 * 64];
  __shared__ float gs[32 * 64];
  __shared__ float att[16 * 64];
  int t = threadIdx.x;
  for (int idx = t; idx < 32 * 64; idx += 256) {
    int c = idx >> 6, k = idx & 63;
    int hr = i * 4 + (k >> 3), wc = j * 4 + (k & 7);
    float fv = 0.f, gv = 0.f;
    if (hr < H && wc < H) {
      size_t o = ((size_t)(b * 32 + c) * H + hr) * H + wc;
      fv = f[o];
      gv = g[o];
    }
    fs[idx] = fv;
    gs[idx] = gv;
  }
  __syncthreads();
  for (int idx = t; idx < 1024; idx += 256) {
    int q = idx >> 6, k = idx & 63;
    int qi = (q >> 2) * 8 + (q & 3);
    int hr = i * 4 + (k >> 3), wc = j * 4 + (k & 7);
    float s;
    if (hr < H && wc < H) {
      s = 0.f;
      for (int c = 0; c < 32; ++c) s += fs[c * 64 + qi] * gs[c * 64 + k];
    } else {
      s = -1e30f;
    }
    att[idx] = s;
  }
  __syncthreads();
  if (t < 16) {
    float m = -1e30f;
    for (int k = 0; k < 64; ++k) m = fmaxf(m, att[t * 64 + k]);
    float d = 0.f;
    for (int k = 0; k < 64; ++k) {
      float e = expf(att[t * 64 + k] - m);
      att[t * 64 + k] = e;
      d += e;
    }
    float inv = 1.f / d;
    for (int k = 0; k < 64; ++k) att[t * 64 + k] *= inv;
  }
  __syncthreads();
  int c = t;
  float accs[16];
  for (int q = 0; q < 16; ++q) accs[q] = 0.f;
  const float* hb = h + (size_t)(b * 256 + c) * H * H;
  for (int k = 0; k < 64; ++k) {
    int hr = i * 4 + (k >> 3), wc = j * 4 + (k & 7);
    if (hr >= H || wc >= H) continue;
    float hv = hb[hr * H + wc];
    for (int q = 0; q < 16; ++q) accs[q] += hv * att[q * 64 + k];
  }
  for (int q = 0; q < 16; ++q) {
    int oh = i * 4 + (q >> 2), ow = j * 4 + (q & 3);
    out[((size_t)(b * 256 + c) * H + oh) * H + ow] = accs[q];
  }
}

// ============================================================================
extern "C" void kernel_launch(void* const* d_in, const int* in_sizes, int n_in,
                              void* d_out, int out_size, void* d_ws,
                              size_t ws_size, hipStream_t stream) {
  const float* x = (const float*)d_in[0];
  const float* w_e1 = (const float*)d_in[1];
  const float* b_e1 = (const float*)d_in[2];
  const float* rho1 = (const float*)d_in[3];
  const float* gam1 = (const float*)d_in[4];
  const float* bet1 = (const float*)d_in[5];
  const float* w_e2 = (const float*)d_in[6];
  const float* b_e2 = (const float*)d_in[7];
  const float* rho2 = (const float*)d_in[8];
  const float* gam2 = (const float*)d_in[9];
  const float* bet2 = (const float*)d_in[10];
  const float* w_e3 = (const float*)d_in[11];
  const float* b_e3 = (const float*)d_in[12];
  const float* rho3 = (const float*)d_in[13];
  const float* gam3 = (const float*)d_in[14];
  const float* bet3 = (const float*)d_in[15];
  const float* rw1 = (const float*)d_in[16];
  const float* rb1 = (const float*)d_in[17];
  const float* rw2 = (const float*)d_in[18];
  const float* rb2 = (const float*)d_in[19];
  const float* w_f = (const float*)d_in[20];
  const float* b_f = (const float*)d_in[21];
  const float* w_g = (const float*)d_in[22];
  const float* b_g = (const float*)d_in[23];
  const float* w_h = (const float*)d_in[24];
  const float* b_h = (const float*)d_in[25];
  const float* w_d1 = (const float*)d_in[26];
  const float* b_d1 = (const float*)d_in[27];
  const float* rho4 = (const float*)d_in[28];
  const float* gam4 = (const float*)d_in[29];
  const float* bet4 = (const float*)d_in[30];
  const float* w_d2 = (const float*)d_in[31];
  const float* b_d2 = (const float*)d_in[32];
  const float* rho5 = (const float*)d_in[33];
  const float* gam5 = (const float*)d_in[34];
  const float* bet5 = (const float*)d_in[35];
  const float* w_d3 = (const float*)d_in[36];
  const float* b_d3 = (const float*)d_in[37];

  // ws layout (192 MiB):
  // E1H f16 raw e1 [0,128MiB) (dead after e2)
  // B2H f16 raw e2 [128,192) (dead after e3; later Bb2 bf16 d1 out)
  // Cc fp32 [0,64), D fp32 [64,128), E fp32 [128,192) (residual stage)
  // F1/F2 fp32 [64,80) (attention f/g); A2 bf16 [0,128) (d2 out)
  // statcopy fp32 16KB at [128MiB,...) during head (Bb2 dead by then)
  char* wsb = (char*)d_ws;
  f16* E1H = (f16*)wsb;
  float* Cc = (float*)wsb;
  float* D = (float*)(wsb + 67108864);
  float* E = (float*)(wsb + 134217728);
  float* F1 = (float*)(wsb + 67108864);
  float* F2 = (float*)(wsb + 75497472);
  f16* B2H = (f16*)(wsb + 134217728);
  bf16* Bb2 = (bf16*)(wsb + 134217728);
  bf16* A2 = (bf16*)wsb;
  float* statcopy = (float*)(wsb + 134217728);

  float* out_img = (float*)d_out;
  float* out_attn = out_img + 3145728;
  // 16 KiB stats scratch at head of img region; fully overwritten by head conv
  float* stats = (float*)d_out;
  // bf16 hi+lo residual weights scratch in the (not yet written) out_attn
  // region; fully consumed before win_attn_kernel writes out_attn.
  unsigned short* wbres = (unsigned short*)((char*)d_out + 12582912);
  // convT + s2-conv bf16 weights in out_img scratch (1-5.2 MiB); consumed
  // before conv7_head_mfma overwrites out_img.
  unsigned short* wd1c = (unsigned short*)((char*)d_out + 1048576);
  unsigned short* wd2c = (unsigned short*)((char*)d_out + 2097152);
  unsigned short* we2c = (unsigned short*)((char*)d_out + 3145728);
  unsigned short* we3c = (unsigned short*)((char*)d_out + 4194304);

  dim3 blk(256);

  // ---- weight conversions (once) ----
  convert_w_kernel<<<18432, blk, 0, stream>>>(rw1, rw2, wbres);
  convert_wd_kernel<<<1152, blk, 0, stream>>>(w_d1, wd1c, 256, 128);
  convert_wd_kernel<<<288, blk, 0, stream>>>(w_d2, wd2c, 128, 64);
  convert_ws2_kernel<<<288, blk, 0, stream>>>(w_e2, we2c, 64, 128);
  convert_ws2_kernel<<<1152, blk, 0, stream>>>(w_e3, we3c, 128, 256);

  // ---- e1: 7x7 conv (LDS-tiled) -> raw f16 + stats ----
  zero_stats_kernel<<<1, 256, 0, stream>>>(stats);
  conv7_e1<<<dim3(128, 8, 4), blk, 0, stream>>>(x, w_e1, b_e1, stats, E1H);
  adalin_coef_kernel<<<1, 256, 0, stream>>>(stats, rho1, gam1, bet1, 4, 64,
                                            1.f / 262144.f);
  // ---- e2: 3x3 s2 MFMA conv with fused e1-norm+relu -> raw f16 ----
  conv3x3s2_mfma<f16><<<dim3(256, 4, 4), blk, 0, stream>>>(
      E1H, we2c, we2c + 73728, b_e2, stats, B2H, 64, 512, 512, 128);
  reduce_nc_kernel<f16><<<512, blk, 0, stream>>>(B2H, stats, 65536);
  adalin_coef_kernel<<<2, 256, 0, stream>>>(stats, rho2, gam2, bet2, 4, 128,
                                            1.f / 65536.f);
  // ---- e3: 3x3 s2 MFMA conv with fused e2-norm+relu -> fp32, then AdaLIN ---
  conv3x3s2_mfma<float><<<dim3(128, 4, 4), blk, 0, stream>>>(
      B2H, we3c, we3c + 294912, b_e3, stats, Cc, 128, 256, 256, 256);
  reduce_nc_kernel<float><<<1024, blk, 0, stream>>>(Cc, stats, 16384);
  adalin_coef_kernel<<<4, 256, 0, stream>>>(stats, rho3, gam3, bet3, 4, 256,
                                            1.f / 16384.f);
  scale_shift_kernel<float><<<65536, blk, 0, stream>>>(Cc, stats, 16384,
                                                       (size_t)16777216, 1);
  // ---- 4 residual blocks (bf16x3 MFMA convs, fused norms) ----
  for (int r = 0; r < 4; ++r) {
    const float* rb1p = rb1 + (size_t)r * 256;
    const float* rb2p = rb2 + (size_t)r * 256;
    const unsigned short* w1h = wbres + (size_t)(r * 2) * 589824;
    const unsigned short* w1l = w1h + 4718592;
    const unsigned short* w2h = wbres + (size_t)(r * 2 + 1) * 589824;
    const unsigned short* w2l = w2h + 4718592;
    conv3x3s1_mfma<false><<<dim3(128, 2, 4), blk, 0, stream>>>(
        Cc, w1h, w1l, rb1p, nullptr, D);
    reduce_nc_kernel<float><<<1024, blk, 0, stream>>>(D, stats, 16384);
    inorm_coef_kernel<<<4, 256, 0, stream>>>(stats, 1024, 1.f / 16384.f);
    conv3x3s1_mfma<true><<<dim3(128, 2, 4), blk, 0, stream>>>(
        D, w2h, w2l, rb2p, stats, E);
    reduce_nc_kernel<float><<<1024, blk, 0, stream>>>(E, stats, 16384);
    inorm_coef_kernel<<<4, 256, 0, stream>>>(stats, 1024, 1.f / 16384.f);
    scale_add_relu_kernel<<<65536, blk, 0, stream>>>(Cc, E, stats, 16384,
                                                     (size_t)16777216);
  }
  // ---- attention: 1x1 convs f/g/h + windowed attention ----
  conv1x1_tile<<<dim3(16, 8, 4), blk, 0, stream>>>(Cc, w_f, b_f, F1, 256,
                                                   16384);
  conv1x1_tile<<<dim3(16, 8, 4), blk, 0, stream>>>(Cc, w_g, b_g, F2, 256,
                                                   16384);
  conv1x1_tile<<<dim3(16, 64, 4), blk, 0, stream>>>(Cc, w_h, b_h, E, 256,
                                                    16384);
  win_attn_kernel<<<dim3(32, 32, 4), blk, 0, stream>>>(F1, F2, E, out_attn);
  // ---- d1: convT 256->128 via MFMA -> raw bf16, stats ----
  convt3x3_mfma<4, float, false><<<dim3(128, 2, 4), blk, 0, stream>>>(
      Cc, wd1c, b_d1, nullptr, Bb2, 256, 128, 128);
  reduce_nc_kernel<bf16><<<512, blk, 0, stream>>>(Bb2, stats, 65536);
  adalin_coef_kernel<<<2, 256, 0, stream>>>(stats, rho4, gam4, bet4, 4, 128,
                                            1.f / 65536.f);
  // ---- d2: convT 128->64 via MFMA with fused d1-norm+relu -> raw bf16 ----
  convt3x3_mfma<2, bf16, true><<<dim3(256, 4, 4), blk, 0, stream>>>(
      Bb2, wd2c, b_d2, stats, A2, 128, 256, 256);
  reduce_nc_kernel<bf16><<<256, blk, 0, stream>>>(A2, stats, 262144);
  adalin_coef_kernel<<<1, 256, 0, stream>>>(stats, rho5, gam5, bet5, 4, 64,
                                            1.f / 262144.f);
  // ---- head: copy coefs out of out_img (self-race fix), then MFMA conv ----
  copy_stats_kernel<<<16, blk, 0, stream>>>(stats, statcopy);
  conv7_head_mfma<<<dim3(128, 2, 4), blk, 0, stream>>>(A2, w_d3, b_d3,
                                                       statcopy, out_img);
}